// Round 3
// baseline (4925.105 us; speedup 1.0000x reference)
//
#include <hip/hip_runtime.h>
#include <hip/hip_bf16.h>

using bf16 = __hip_bfloat16;

__device__ __forceinline__ float bf2f(bf16 v) { return __bfloat162float(v); }
__device__ __forceinline__ bf16 f2bf(float v) { return __float2bfloat16(v); }

// dtype-adaptive input load / output store (flag: 1 = fp32 buffers, 0 = bf16)
__device__ __forceinline__ float ldin(const void* p, size_t i, int f32) {
    return f32 ? ((const float*)p)[i] : __bfloat162float(((const bf16*)p)[i]);
}
__device__ __forceinline__ void stout(void* p, size_t i, float v, int f32) {
    if (f32) ((float*)p)[i] = v;
    else     ((bf16*)p)[i] = __float2bfloat16(v);
}

// ---------------- sizes ----------------
#define B_   4
#define CC   64      // coarse channels
#define HC   64
#define WC   64
#define JC   4096    // HC*WC
#define CF   24      // fine channels
#define HF   128
#define WF   128
#define JF   16384   // HF*WF
#define OUT0_ELEMS (B_ * 3 * JC)   // 49152

// =====================================================================
// Kernel 0: dtype probe. Reads first 8192 uint16 of feats0_c. True bf16
// N(0,1) data never has |x| >= 2^10 (exp field >= 0x89). fp32 data read
// as uint16 has ~46% of its low-halves in that range. flag=1 -> fp32.
// =====================================================================
__global__ void dtype_probe_kernel(const unsigned short* __restrict__ x,
                                   int* __restrict__ flag)
{
    __shared__ int cnt;
    if (threadIdx.x == 0) cnt = 0;
    __syncthreads();
    int c = 0;
    for (int i = threadIdx.x; i < 8192; i += 256) {
        const unsigned e = (x[i] >> 7) & 0xFF;
        if (e >= 0x89) ++c;   // |bf16(bits)| >= 1024 (incl. inf/nan)
    }
    atomicAdd(&cnt, c);
    __syncthreads();
    if (threadIdx.x == 0) *flag = (cnt > 64) ? 1 : 0;
}

// =====================================================================
// Kernel 1: fused correlation + softmax + position expectation
// grid: (HC, B), block: 256.  thread = (query w = tid&63, key-slice = tid>>6)
// =====================================================================
__global__ __launch_bounds__(256) void corr_warp_kernel(
    const void* __restrict__ f0, const void* __restrict__ f1,
    float* __restrict__ cm0, const int* __restrict__ dflag)
{
    const int f32 = *dflag;
    __shared__ float tile[4][64][64];          // 64 KB, reused as reduce buf
    const int h = blockIdx.x;
    const int b = blockIdx.y;
    const int tid = threadIdx.x;
    const int q = tid & 63;          // query column (w)
    const int slice = tid >> 6;      // key slice: 1024 keys each

    // load query vector f0[b, :, h, q] into registers
    float q0[64];
    const size_t f0base = (size_t)b * CC * JC + h * WC + q;
#pragma unroll
    for (int c = 0; c < 64; ++c) q0[c] = ldin(f0, f0base + (size_t)c * JC, f32);

    float m = -1e30f, l = 0.f, ax = 0.f, ay = 0.f;

    const size_t f1base = (size_t)b * CC * JC + (size_t)q * JC;
    for (int t = 0; t < 16; ++t) {
        const int j0 = slice * 1024 + t * 64;
        __syncthreads();   // previous tile fully consumed
        // lane q loads channel q of 64 consecutive keys, stores transposed
        for (int jj = 0; jj < 64; ++jj)
            tile[slice][jj][q] = ldin(f1, f1base + j0 + jj, f32);
        __syncthreads();

        for (int jj = 0; jj < 64; ++jj) {
            const float* kv = tile[slice][jj];   // broadcast reads across wave
            float s = 0.f;
#pragma unroll
            for (int c = 0; c < 64; c += 4) {
                const float4 v = *(const float4*)(kv + c);
                s += q0[c] * v.x + q0[c + 1] * v.y + q0[c + 2] * v.z + q0[c + 3] * v.w;
            }
            s *= 0.125f;   // 1/sqrt(64)
            const int j = j0 + jj;
            const float gx = (float)((j & 63) * 2 + 1) * (1.f / 64.f) - 1.f;
            const float gy = (float)((j >> 6) * 2 + 1) * (1.f / 64.f) - 1.f;
            const float mn = fmaxf(m, s);
            const float alpha = __expf(m - mn);
            const float p = __expf(s - mn);
            l = l * alpha + p;
            ax = ax * alpha + p * gx;
            ay = ay * alpha + p * gy;
            m = mn;
        }
    }

    // combine 4 slices per query via LDS (reuse tile memory)
    __syncthreads();
    float* red = (float*)tile;                 // [slice][q][4]
    float* my = red + ((slice * 64) + q) * 4;
    my[0] = m; my[1] = l; my[2] = ax; my[3] = ay;
    __syncthreads();
    if (slice == 0) {
        float M = -1e30f;
        for (int s2 = 0; s2 < 4; ++s2) M = fmaxf(M, red[((s2 * 64) + q) * 4 + 0]);
        float L = 0.f, AX = 0.f, AY = 0.f;
        for (int s2 = 0; s2 < 4; ++s2) {
            const float* r = red + ((s2 * 64) + q) * 4;
            const float e = __expf(r[0] - M);
            L += r[1] * e; AX += r[2] * e; AY += r[3] * e;
        }
        const float inv = 1.f / L;
        const size_t base = ((size_t)b * 3) * JC + h * WC + q;
        cm0[base]            = AX * inv;
        cm0[base + JC]       = AY * inv;
        cm0[base + 2 * JC]   = 0.f;
    }
}

// =====================================================================
// Kernel 2: coarse concat:  A[0:64]=feats0_c, A[64:128]=grid_sample(feats1_c),
//           A[128:130]=warp.   grid: 64 blocks x 256
// =====================================================================
__global__ __launch_bounds__(256) void coarse_concat_kernel(
    const void* __restrict__ f0c, const void* __restrict__ f1c,
    const float* __restrict__ cm0, float* __restrict__ A,
    const int* __restrict__ dflag)
{
    const int f32 = *dflag;
    const int idx = blockIdx.x * 256 + threadIdx.x;   // B*JC
    const int b = idx >> 12, hw = idx & (JC - 1);
    const size_t ib = (size_t)b * CC * JC;

    for (int c = 0; c < CC; ++c)
        A[((size_t)(b * 130 + c)) * JC + hw] = ldin(f0c, ib + (size_t)c * JC + hw, f32);

    const float gx = cm0[((size_t)b * 3 + 0) * JC + hw];
    const float gy = cm0[((size_t)b * 3 + 1) * JC + hw];
    const float x = (gx + 1.f) * 32.f - 0.5f;
    const float y = (gy + 1.f) * 32.f - 0.5f;
    const float x0f = floorf(x), y0f = floorf(y);
    const float wx = x - x0f, wy = y - y0f;
    const int x0 = (int)x0f, y0 = (int)y0f;
    const int x1 = x0 + 1, y1 = y0 + 1;
    const float vx0 = (x0 >= 0 && x0 < WC) ? 1.f : 0.f;
    const float vx1 = (x1 >= 0 && x1 < WC) ? 1.f : 0.f;
    const float vy0 = (y0 >= 0 && y0 < HC) ? 1.f : 0.f;
    const float vy1 = (y1 >= 0 && y1 < HC) ? 1.f : 0.f;
    const int cx0 = min(max(x0, 0), WC - 1), cx1 = min(max(x1, 0), WC - 1);
    const int cy0 = min(max(y0, 0), HC - 1), cy1 = min(max(y1, 0), HC - 1);
    const float w00 = (1.f - wx) * (1.f - wy) * vx0 * vy0;
    const float w01 = wx * (1.f - wy) * vx1 * vy0;
    const float w10 = (1.f - wx) * wy * vx0 * vy1;
    const float w11 = wx * wy * vx1 * vy1;
    const int i00 = cy0 * WC + cx0, i01 = cy0 * WC + cx1;
    const int i10 = cy1 * WC + cx0, i11 = cy1 * WC + cx1;

    for (int c = 0; c < CC; ++c) {
        const size_t pb = ib + (size_t)c * JC;
        const float v = w00 * ldin(f1c, pb + i00, f32) + w01 * ldin(f1c, pb + i01, f32)
                      + w10 * ldin(f1c, pb + i10, f32) + w11 * ldin(f1c, pb + i11, f32);
        A[((size_t)(b * 130 + 64 + c)) * JC + hw] = v;
    }
    A[((size_t)(b * 130 + 128)) * JC + hw] = gx;
    A[((size_t)(b * 130 + 129)) * JC + hw] = gy;
}

// =====================================================================
// Kernel 3: 3x3 SAME conv, optional fused relu(bn(x)) applied on LOAD.
// grid: (tiles, B, Cout/32), block 256 (16x16 pixel tile, 32 outch/block)
// =====================================================================
template <bool BN>
__global__ __launch_bounds__(256) void conv3x3_kernel(
    const float* __restrict__ src, const void* __restrict__ w,
    const float2* __restrict__ stats, float* __restrict__ dst,
    int Cin, int Cout, int H, int W, int tilesPerRow,
    const int* __restrict__ dflag)
{
    const int f32 = *dflag;
    __shared__ float it[18][18];
    __shared__ __align__(16) float wt[32][12];
    __shared__ float2 st[256];

    const int tile = blockIdx.x;
    const int b = blockIdx.y;
    const int cog = blockIdx.z;
    const int ty = (tile / tilesPerRow) * 16;
    const int tx = (tile % tilesPerRow) * 16;
    const int tid = threadIdx.x;
    const int lx = tid & 15, ly = tid >> 4;

    if (BN) for (int c = tid; c < Cin; c += 256) st[c] = stats[c];

    float acc[32];
#pragma unroll
    for (int i = 0; i < 32; ++i) acc[i] = 0.f;
    __syncthreads();

    for (int ci = 0; ci < Cin; ++ci) {
        const float* sp = src + ((size_t)(b * Cin + ci)) * H * W;
        float2 s;
        if (BN) s = st[ci];
        for (int p = tid; p < 324; p += 256) {
            const int iy = p / 18, ix = p - iy * 18;
            const int gy = ty + iy - 1, gx = tx + ix - 1;
            float v = 0.f;
            if (gy >= 0 && gy < H && gx >= 0 && gx < W) {
                v = sp[gy * W + gx];
                if (BN) v = fmaxf((v - s.x) * s.y, 0.f);
            }
            it[iy][ix] = v;
        }
        // 288 weight entries, 256 threads -> strided loop (R1 bug fixed)
        for (int p = tid; p < 288; p += 256) {
            const int co = p / 9, k = p - co * 9;
            wt[co][k] = ldin(w, (((size_t)(cog * 32 + co)) * Cin + ci) * 9 + k, f32);
        }
        __syncthreads();

        float in[9];
#pragma unroll
        for (int dy = 0; dy < 3; ++dy)
#pragma unroll
            for (int dx = 0; dx < 3; ++dx)
                in[dy * 3 + dx] = it[ly + dy][lx + dx];

#pragma unroll
        for (int co = 0; co < 32; ++co) {
            const float4 w0 = *(const float4*)&wt[co][0];
            const float4 w1 = *(const float4*)&wt[co][4];
            const float w8 = wt[co][8];
            acc[co] += in[0] * w0.x + in[1] * w0.y + in[2] * w0.z + in[3] * w0.w
                     + in[4] * w1.x + in[5] * w1.y + in[6] * w1.z + in[7] * w1.w
                     + in[8] * w8;
        }
        __syncthreads();
    }

    const size_t obase = ((size_t)(b * Cout + cog * 32)) * H * W
                       + (size_t)(ty + ly) * W + (tx + lx);
#pragma unroll
    for (int co = 0; co < 32; ++co)
        dst[obase + (size_t)co * H * W] = acc[co];
}

// =====================================================================
// Kernel 4: per-channel batch-norm stats (mean, rsqrt(var+eps))
// grid: C blocks, block 256
// =====================================================================
__global__ __launch_bounds__(256) void stats_kernel(
    const float* __restrict__ x, float2* __restrict__ stats, int C, int HW)
{
    __shared__ double sd[256], sq[256];
    const int c = blockIdx.x;
    const int tid = threadIdx.x;
    double s = 0.0, s2 = 0.0;
    for (int b = 0; b < B_; ++b) {
        const float* p = x + ((size_t)(b * C + c)) * HW;
        for (int i = tid; i < HW; i += 256) {
            const double v = (double)p[i];
            s += v; s2 += v * v;
        }
    }
    sd[tid] = s; sq[tid] = s2;
    __syncthreads();
    for (int o = 128; o > 0; o >>= 1) {
        if (tid < o) { sd[tid] += sd[tid + o]; sq[tid] += sq[tid + o]; }
        __syncthreads();
    }
    if (tid == 0) {
        const double n = (double)B_ * HW;
        const double mean = sd[0] / n;
        const double var = sq[0] / n - mean * mean;
        stats[c] = make_float2((float)mean, (float)(1.0 / sqrt(var + 1e-5)));
    }
}

// =====================================================================
// Kernel 5: coarse head: 1x1 conv (256->3) on relu(bn(A)) + bias + cm0
// writes fp32 cmatch (for upsample) and dtype-adaptive output 0.
// grid 64 x 256
// =====================================================================
__global__ __launch_bounds__(256) void coarse_head_kernel(
    const float* __restrict__ A, const float2* __restrict__ stats,
    const void* __restrict__ w5, const void* __restrict__ b5,
    const float* __restrict__ cm0, float* __restrict__ cmatch,
    void* __restrict__ out, const int* __restrict__ dflag)
{
    const int f32 = *dflag;
    __shared__ float wl[3][256];
    __shared__ float bl[3];
    __shared__ float2 st[256];
    const int tid = threadIdx.x;
    for (int i = tid; i < 768; i += 256) wl[i >> 8][i & 255] = ldin(w5, i, f32);
    if (tid < 3) bl[tid] = ldin(b5, tid, f32);
    st[tid] = stats[tid];
    __syncthreads();

    const int idx = blockIdx.x * 256 + tid;
    const int b = idx >> 12, hw = idx & (JC - 1);
    float a0 = bl[0], a1 = bl[1], a2 = bl[2];
    const float* p = A + (size_t)b * 256 * JC + hw;
    for (int c = 0; c < 256; ++c) {
        const float v = fmaxf((p[(size_t)c * JC] - st[c].x) * st[c].y, 0.f);
        a0 += v * wl[0][c]; a1 += v * wl[1][c]; a2 += v * wl[2][c];
    }
    const size_t base = (size_t)b * 3 * JC + hw;
    const float c0 = cm0[base] + a0;
    const float c1 = cm0[base + JC] + a1;
    const float c2 = cm0[base + 2 * JC] + a2;
    cmatch[base] = c0; cmatch[base + JC] = c1; cmatch[base + 2 * JC] = c2;
    stout(out, base, c0, f32);
    stout(out, base + JC, c1, f32);
    stout(out, base + 2 * JC, c2, f32);
}

// =====================================================================
// Kernel 6: bilinear 2x upsample (jax.image.resize semantics = half-pixel,
// edge clamp == weight renorm at borders for 2x).  grid 768 x 256
// =====================================================================
__global__ __launch_bounds__(256) void upsample_kernel(
    const float* __restrict__ cm, float* __restrict__ up)
{
    const int idx = blockIdx.x * 256 + threadIdx.x;   // B*3*JF
    const int ox = idx & 127, oy = (idx >> 7) & 127, bc = idx >> 14;
    const float sx = ox * 0.5f - 0.25f;
    const float sy = oy * 0.5f - 0.25f;
    const int x0 = (int)floorf(sx), y0 = (int)floorf(sy);
    const float fx = sx - x0, fy = sy - y0;
    const int cx0 = max(x0, 0), cx1 = min(x0 + 1, WC - 1);
    const int cy0 = max(y0, 0), cy1 = min(y0 + 1, HC - 1);
    const float* p = cm + (size_t)bc * JC;
    const float v = (1.f - fy) * ((1.f - fx) * p[cy0 * WC + cx0] + fx * p[cy0 * WC + cx1])
                  + fy * ((1.f - fx) * p[cy1 * WC + cx0] + fx * p[cy1 * WC + cx1]);
    up[idx] = v;
}

// =====================================================================
// Kernel 7: fine concat: A[0:24]=feats0_f, A[24:48]=grid_sample(feats1_f, up),
// A[48:50]=up[:, :2].  grid 256 x 256
// =====================================================================
__global__ __launch_bounds__(256) void fine_concat_kernel(
    const void* __restrict__ f0f, const void* __restrict__ f1f,
    const float* __restrict__ up, float* __restrict__ A,
    const int* __restrict__ dflag)
{
    const int f32 = *dflag;
    const int idx = blockIdx.x * 256 + threadIdx.x;   // B*JF
    const int b = idx >> 14, hw = idx & (JF - 1);
    const size_t ib = (size_t)b * CF * JF;

    for (int c = 0; c < CF; ++c)
        A[((size_t)(b * 50 + c)) * JF + hw] = ldin(f0f, ib + (size_t)c * JF + hw, f32);

    const size_t ub = (size_t)b * 3 * JF + hw;
    const float gx = up[ub], gy = up[ub + JF];
    const float x = (gx + 1.f) * 64.f - 0.5f;
    const float y = (gy + 1.f) * 64.f - 0.5f;
    const float x0f = floorf(x), y0f = floorf(y);
    const float wx = x - x0f, wy = y - y0f;
    const int x0 = (int)x0f, y0 = (int)y0f;
    const int x1 = x0 + 1, y1 = y0 + 1;
    const float vx0 = (x0 >= 0 && x0 < WF) ? 1.f : 0.f;
    const float vx1 = (x1 >= 0 && x1 < WF) ? 1.f : 0.f;
    const float vy0 = (y0 >= 0 && y0 < HF) ? 1.f : 0.f;
    const float vy1 = (y1 >= 0 && y1 < HF) ? 1.f : 0.f;
    const int cx0 = min(max(x0, 0), WF - 1), cx1 = min(max(x1, 0), WF - 1);
    const int cy0 = min(max(y0, 0), HF - 1), cy1 = min(max(y1, 0), HF - 1);
    const float w00 = (1.f - wx) * (1.f - wy) * vx0 * vy0;
    const float w01 = wx * (1.f - wy) * vx1 * vy0;
    const float w10 = (1.f - wx) * wy * vx0 * vy1;
    const float w11 = wx * wy * vx1 * vy1;
    const int i00 = cy0 * WF + cx0, i01 = cy0 * WF + cx1;
    const int i10 = cy1 * WF + cx0, i11 = cy1 * WF + cx1;

    for (int c = 0; c < CF; ++c) {
        const size_t pb = ib + (size_t)c * JF;
        const float v = w00 * ldin(f1f, pb + i00, f32) + w01 * ldin(f1f, pb + i01, f32)
                      + w10 * ldin(f1f, pb + i10, f32) + w11 * ldin(f1f, pb + i11, f32);
        A[((size_t)(b * 50 + 24 + c)) * JF + hw] = v;
    }
    A[((size_t)(b * 50 + 48)) * JF + hw] = gx;
    A[((size_t)(b * 50 + 49)) * JF + hw] = gy;
}

// =====================================================================
// Kernel 8: fine head: 1x1 conv (64->3) on relu(bn(A)) + bias + up -> out1
// grid 256 x 256
// =====================================================================
__global__ __launch_bounds__(256) void fine_head_kernel(
    const float* __restrict__ A, const float2* __restrict__ stats,
    const void* __restrict__ w5, const void* __restrict__ b5,
    const float* __restrict__ up, void* __restrict__ out,
    const int* __restrict__ dflag)
{
    const int f32 = *dflag;
    __shared__ float wl[3][64];
    __shared__ float bl[3];
    __shared__ float2 st[64];
    const int tid = threadIdx.x;
    if (tid < 192) wl[tid >> 6][tid & 63] = ldin(w5, tid, f32);
    if (tid < 3) bl[tid] = ldin(b5, tid, f32);
    if (tid < 64) st[tid] = stats[tid];
    __syncthreads();

    const int idx = blockIdx.x * 256 + tid;
    const int b = idx >> 14, hw = idx & (JF - 1);
    float a0 = bl[0], a1 = bl[1], a2 = bl[2];
    const float* p = A + (size_t)b * 64 * JF + hw;
    for (int c = 0; c < 64; ++c) {
        const float v = fmaxf((p[(size_t)c * JF] - st[c].x) * st[c].y, 0.f);
        a0 += v * wl[0][c]; a1 += v * wl[1][c]; a2 += v * wl[2][c];
    }
    const size_t base = (size_t)b * 3 * JF + hw;
    stout(out, OUT0_ELEMS + base,          up[base] + a0, f32);
    stout(out, OUT0_ELEMS + base + JF,     up[base + JF] + a1, f32);
    stout(out, OUT0_ELEMS + base + 2 * JF, up[base + 2 * JF] + a2, f32);
}

// =====================================================================
extern "C" void kernel_launch(void* const* d_in, const int* in_sizes, int n_in,
                              void* d_out, int out_size, void* d_ws, size_t ws_size,
                              hipStream_t stream)
{
    const void* f0c = d_in[0];
    const void* f1c = d_in[1];
    const void* f0f = d_in[2];
    const void* f1f = d_in[3];
    const void* cw1 = d_in[4];
    const void* cw2 = d_in[5];
    const void* cw3 = d_in[6];
    const void* cw4 = d_in[7];
    const void* cw5 = d_in[8];
    const void* cb5 = d_in[9];
    const void* fw1 = d_in[10];
    const void* fw2 = d_in[11];
    const void* fw3 = d_in[12];
    const void* fw4 = d_in[13];
    const void* fw5 = d_in[14];
    const void* fb5 = d_in[15];

    // workspace layout (floats)
    float* A      = (float*)d_ws;               // 4*256*4096 = 4194304
    float* Bb     = A + (size_t)4194304;        // 4194304
    float* cm0    = Bb + (size_t)4194304;       // 49152
    float* cmatch = cm0 + 49152;                // 49152
    float* up     = cmatch + 49152;             // 196608
    float2* st    = (float2*)(up + 196608);     // 256 float2
    int*   dflag  = (int*)(st + 256);           // 1 int

    // 0. dtype probe (must run first)
    dtype_probe_kernel<<<1, 256, 0, stream>>>((const unsigned short*)f0c, dflag);

    // 1. correlation + softmax + warp
    corr_warp_kernel<<<dim3(HC, B_), 256, 0, stream>>>(f0c, f1c, cm0, dflag);

    // 2. coarse concat (130 ch)
    coarse_concat_kernel<<<dim3(B_ * JC / 256), 256, 0, stream>>>(f0c, f1c, cm0, A, dflag);

    // 3. coarse conv stack
    const dim3 cgrid(16, B_, 8);   // (64/16)^2 tiles, 8 groups of 32 outch
    conv3x3_kernel<false><<<cgrid, 256, 0, stream>>>(A, cw1, nullptr, Bb, 130, 256, HC, WC, 4, dflag);
    stats_kernel<<<256, 256, 0, stream>>>(Bb, st, 256, JC);
    conv3x3_kernel<true><<<cgrid, 256, 0, stream>>>(Bb, cw2, st, A, 256, 256, HC, WC, 4, dflag);
    stats_kernel<<<256, 256, 0, stream>>>(A, st, 256, JC);
    conv3x3_kernel<true><<<cgrid, 256, 0, stream>>>(A, cw3, st, Bb, 256, 256, HC, WC, 4, dflag);
    stats_kernel<<<256, 256, 0, stream>>>(Bb, st, 256, JC);
    conv3x3_kernel<true><<<cgrid, 256, 0, stream>>>(Bb, cw4, st, A, 256, 256, HC, WC, 4, dflag);
    stats_kernel<<<256, 256, 0, stream>>>(A, st, 256, JC);

    // 4. coarse head (writes output 0)
    coarse_head_kernel<<<dim3(B_ * JC / 256), 256, 0, stream>>>(A, st, cw5, cb5, cm0, cmatch, d_out, dflag);

    // 5. upsample to fine resolution
    upsample_kernel<<<dim3(B_ * 3 * JF / 256), 256, 0, stream>>>(cmatch, up);

    // 6. fine concat (50 ch)
    fine_concat_kernel<<<dim3(B_ * JF / 256), 256, 0, stream>>>(f0f, f1f, up, A, dflag);

    // 7. fine conv stack
    const dim3 fgrid(64, B_, 2);   // (128/16)^2 tiles, 2 groups of 32 outch
    conv3x3_kernel<false><<<fgrid, 256, 0, stream>>>(A, fw1, nullptr, Bb, 50, 64, HF, WF, 8, dflag);
    stats_kernel<<<64, 256, 0, stream>>>(Bb, st, 64, JF);
    conv3x3_kernel<true><<<fgrid, 256, 0, stream>>>(Bb, fw2, st, A, 64, 64, HF, WF, 8, dflag);
    stats_kernel<<<64, 256, 0, stream>>>(A, st, 64, JF);
    conv3x3_kernel<true><<<fgrid, 256, 0, stream>>>(A, fw3, st, Bb, 64, 64, HF, WF, 8, dflag);
    stats_kernel<<<64, 256, 0, stream>>>(Bb, st, 64, JF);
    conv3x3_kernel<true><<<fgrid, 256, 0, stream>>>(Bb, fw4, st, A, 64, 64, HF, WF, 8, dflag);
    stats_kernel<<<64, 256, 0, stream>>>(A, st, 64, JF);

    // 8. fine head (writes output 1)
    fine_head_kernel<<<dim3(B_ * JF / 256), 256, 0, stream>>>(A, st, fw5, fb5, up, d_out, dflag);
}

// Round 5
// 2113.390 us; speedup vs baseline: 2.3304x; 2.3304x over previous
//
#include <hip/hip_runtime.h>
#include <hip/hip_bf16.h>

using bf16 = __hip_bfloat16;
typedef unsigned short ushort_t;
typedef __attribute__((ext_vector_type(8))) short v8s;
typedef __attribute__((ext_vector_type(4))) float v4f;

__device__ __forceinline__ float bfbits2f(unsigned u) {
    return __uint_as_float(u << 16);
}
__device__ __forceinline__ ushort_t f2bfbits(float f) {
    unsigned x = __float_as_uint(f);
    return (ushort_t)((x + 0x7fffu + ((x >> 16) & 1u)) >> 16);
}
// dtype-adaptive input load / output store (flag: 1 = fp32 buffers, 0 = bf16)
__device__ __forceinline__ float ldin(const void* p, size_t i, int f32) {
    return f32 ? ((const float*)p)[i] : bfbits2f(((const ushort_t*)p)[i]);
}
__device__ __forceinline__ void stout(void* p, size_t i, float v, int f32) {
    if (f32) ((float*)p)[i] = v;
    else     ((ushort_t*)p)[i] = f2bfbits(v);
}

// ---------------- sizes ----------------
#define B_   4
#define CC   64
#define HC   64
#define WC   64
#define JC   4096
#define CF   24
#define HF   128
#define WF   128
#define JF   16384
#define OUT0_ELEMS (B_ * 3 * JC)

// =====================================================================
// Kernel 0: dtype probe. flag=1 -> fp32 inputs (R3: confirmed fp32).
// =====================================================================
__global__ void dtype_probe_kernel(const ushort_t* __restrict__ x,
                                   int* __restrict__ flag)
{
    __shared__ int cnt;
    if (threadIdx.x == 0) cnt = 0;
    __syncthreads();
    int c = 0;
    for (int i = threadIdx.x; i < 8192; i += 256) {
        const unsigned e = (x[i] >> 7) & 0xFF;
        if (e >= 0x89) ++c;
    }
    atomicAdd(&cnt, c);
    __syncthreads();
    if (threadIdx.x == 0) *flag = (cnt > 64) ? 1 : 0;
}

// =====================================================================
// Fine weight repack: w[co][ci][3][3] -> wp[k][co][ci_pad] bf16
// =====================================================================
__global__ void repack_w_kernel(const void* __restrict__ w, ushort_t* __restrict__ wp,
                                int CO, int CIreal, int CIP, const int* __restrict__ dflag)
{
    const int f32 = *dflag;
    const int idx = blockIdx.x * 256 + threadIdx.x;
    const int total = 9 * CO * CIP;
    if (idx >= total) return;
    const int k = idx / (CO * CIP);
    const int rem = idx - k * (CO * CIP);
    const int co = rem / CIP;
    const int cip = rem - co * CIP;
    float v = 0.f;
    if (cip < CIreal) v = ldin(w, ((size_t)co * CIreal + cip) * 9 + k, f32);
    wp[((size_t)k * CO + co) * CIP + cip] = f2bfbits(v);
}

// =====================================================================
// Kernel 1: fused correlation + softmax + position expectation (fp32)
// =====================================================================
__global__ __launch_bounds__(256) void corr_warp_kernel(
    const void* __restrict__ f0, const void* __restrict__ f1,
    float* __restrict__ cm0, const int* __restrict__ dflag)
{
    const int f32 = *dflag;
    __shared__ float tile[4][64][64];
    const int h = blockIdx.x;
    const int b = blockIdx.y;
    const int tid = threadIdx.x;
    const int q = tid & 63;
    const int slice = tid >> 6;

    float q0[64];
    const size_t f0base = (size_t)b * CC * JC + h * WC + q;
#pragma unroll
    for (int c = 0; c < 64; ++c) q0[c] = ldin(f0, f0base + (size_t)c * JC, f32);

    float m = -1e30f, l = 0.f, ax = 0.f, ay = 0.f;
    const size_t f1base = (size_t)b * CC * JC + (size_t)q * JC;
    for (int t = 0; t < 16; ++t) {
        const int j0 = slice * 1024 + t * 64;
        __syncthreads();
        for (int jj = 0; jj < 64; ++jj)
            tile[slice][jj][q] = ldin(f1, f1base + j0 + jj, f32);
        __syncthreads();

        for (int jj = 0; jj < 64; ++jj) {
            const float* kv = tile[slice][jj];
            float s = 0.f;
#pragma unroll
            for (int c = 0; c < 64; c += 4) {
                const float4 v = *(const float4*)(kv + c);
                s += q0[c] * v.x + q0[c + 1] * v.y + q0[c + 2] * v.z + q0[c + 3] * v.w;
            }
            s *= 0.125f;
            const int j = j0 + jj;
            const float gx = (float)((j & 63) * 2 + 1) * (1.f / 64.f) - 1.f;
            const float gy = (float)((j >> 6) * 2 + 1) * (1.f / 64.f) - 1.f;
            const float mn = fmaxf(m, s);
            const float alpha = __expf(m - mn);
            const float p = __expf(s - mn);
            l = l * alpha + p;
            ax = ax * alpha + p * gx;
            ay = ay * alpha + p * gy;
            m = mn;
        }
    }

    __syncthreads();
    float* red = (float*)tile;
    float* my = red + ((slice * 64) + q) * 4;
    my[0] = m; my[1] = l; my[2] = ax; my[3] = ay;
    __syncthreads();
    if (slice == 0) {
        float M = -1e30f;
        for (int s2 = 0; s2 < 4; ++s2) M = fmaxf(M, red[((s2 * 64) + q) * 4 + 0]);
        float L = 0.f, AX = 0.f, AY = 0.f;
        for (int s2 = 0; s2 < 4; ++s2) {
            const float* r = red + ((s2 * 64) + q) * 4;
            const float e = __expf(r[0] - M);
            L += r[1] * e; AX += r[2] * e; AY += r[3] * e;
        }
        const float inv = 1.f / L;
        const size_t base = ((size_t)b * 3) * JC + h * WC + q;
        cm0[base]          = AX * inv;
        cm0[base + JC]     = AY * inv;
        cm0[base + 2 * JC] = 0.f;
    }
}

// =====================================================================
// Kernel 2: coarse concat -> fp32 NHWC [b][y][x][160] (130 real + 30 zero)
// =====================================================================
__global__ __launch_bounds__(256) void coarse_concat_f32(
    const void* __restrict__ f0c, const void* __restrict__ f1c,
    const float* __restrict__ cm0, float* __restrict__ A,
    const int* __restrict__ dflag)
{
    const int f32 = *dflag;
    const int idx = blockIdx.x * 256 + threadIdx.x;   // B*JC
    const int b = idx >> 12, hw = idx & (JC - 1);
    const size_t ib = (size_t)b * CC * JC;
    float* o = A + (size_t)idx * 160;

    for (int c = 0; c < CC; ++c)
        o[c] = ldin(f0c, ib + (size_t)c * JC + hw, f32);

    const float gx = cm0[((size_t)b * 3 + 0) * JC + hw];
    const float gy = cm0[((size_t)b * 3 + 1) * JC + hw];
    const float x = (gx + 1.f) * 32.f - 0.5f;
    const float y = (gy + 1.f) * 32.f - 0.5f;
    const float x0f = floorf(x), y0f = floorf(y);
    const float wx = x - x0f, wy = y - y0f;
    const int x0 = (int)x0f, y0 = (int)y0f;
    const int x1 = x0 + 1, y1 = y0 + 1;
    const float vx0 = (x0 >= 0 && x0 < WC) ? 1.f : 0.f;
    const float vx1 = (x1 >= 0 && x1 < WC) ? 1.f : 0.f;
    const float vy0 = (y0 >= 0 && y0 < HC) ? 1.f : 0.f;
    const float vy1 = (y1 >= 0 && y1 < HC) ? 1.f : 0.f;
    const int cx0 = min(max(x0, 0), WC - 1), cx1 = min(max(x1, 0), WC - 1);
    const int cy0 = min(max(y0, 0), HC - 1), cy1 = min(max(y1, 0), HC - 1);
    const float w00 = (1.f - wx) * (1.f - wy) * vx0 * vy0;
    const float w01 = wx * (1.f - wy) * vx1 * vy0;
    const float w10 = (1.f - wx) * wy * vx0 * vy1;
    const float w11 = wx * wy * vx1 * vy1;
    const int i00 = cy0 * WC + cx0, i01 = cy0 * WC + cx1;
    const int i10 = cy1 * WC + cx0, i11 = cy1 * WC + cx1;

    for (int c = 0; c < CC; ++c) {
        const size_t pb = ib + (size_t)c * JC;
        o[64 + c] = w00 * ldin(f1c, pb + i00, f32) + w01 * ldin(f1c, pb + i01, f32)
                  + w10 * ldin(f1c, pb + i10, f32) + w11 * ldin(f1c, pb + i11, f32);
    }
    o[128] = gx;
    o[129] = gy;
    for (int c = 130; c < 160; ++c) o[c] = 0.f;
}

// =====================================================================
// Kernel 3a: COARSE 3x3 conv, SPLIT-bf16 MFMA (hi/lo planes, 3 MFMA/pair):
// fp32 NHWC in/out, near-fp32 precision (rel ~2^-17). Weights staged
// straight from the original [CO][CIreal][3][3] tensor (L2-resident).
// Dynamic LDS: actH/actL 18x18x40, wH/wL 9x32x40, st 256 -> 99,968 B.
// =====================================================================
template <bool BN>
__global__ __launch_bounds__(256) void conv3x3_split(
    const float* __restrict__ in,    // fp32 NHWC [B][H][W][CI]
    const void* __restrict__ w,      // original [CO][CIreal][3][3]
    const float2* __restrict__ stats,
    float* __restrict__ out,         // fp32 NHWC [B][H][W][CO]
    int CI, int CIreal, int CO, int H, int W, int tilesX,
    const int* __restrict__ dflag)
{
    extern __shared__ char smem[];
    ushort_t* actH = (ushort_t*)smem;          // 12960
    ushort_t* actL = actH + 12960;             // 12960
    ushort_t* wHs  = actL + 12960;             // 11520
    ushort_t* wLs  = wHs + 11520;              // 11520
    float2*   st   = (float2*)(wLs + 11520);   // 256

    const int f32 = *dflag;
    const int tid = threadIdx.x;
    const int tile = blockIdx.x;
    const int b = blockIdx.y;
    const int cog = blockIdx.z;
    const int ty = (tile / tilesX) * 16;
    const int tx = (tile % tilesX) * 16;
    const int wv = tid >> 6;
    const int ln = tid & 63;
    const int lm = ln & 15;
    const int q8 = (ln >> 4) * 8;

    if (BN) for (int c = tid; c < CI; c += 256) st[c] = stats[c];

    v4f acc[4][2];
#pragma unroll
    for (int i = 0; i < 4; ++i)
#pragma unroll
        for (int j = 0; j < 2; ++j) acc[i][j] = (v4f)(0.f);

    const int nChunks = CI >> 5;
    for (int ch = 0; ch < nChunks; ++ch) {
        const int ci0 = ch << 5;
        __syncthreads();
        // ---- stage activations: 18x18 px x 32 ci as float4 items, split ----
        for (int p = tid; p < 2592; p += 256) {
            const int yy = p / 144;
            const int rem = p - yy * 144;
            const int xx = rem >> 3;
            const int cs = (rem & 7) << 2;
            const int gy = ty + yy - 1, gx = tx + xx - 1;
            float4 v = make_float4(0.f, 0.f, 0.f, 0.f);
            if (gy >= 0 && gy < H && gx >= 0 && gx < W) {
                v = *(const float4*)(in + (((size_t)(b * H + gy)) * W + gx) * CI + ci0 + cs);
                if (BN) {
                    const float2 s0 = st[ci0 + cs + 0];
                    const float2 s1 = st[ci0 + cs + 1];
                    const float2 s2 = st[ci0 + cs + 2];
                    const float2 s3 = st[ci0 + cs + 3];
                    v.x = fmaxf((v.x - s0.x) * s0.y, 0.f);
                    v.y = fmaxf((v.y - s1.x) * s1.y, 0.f);
                    v.z = fmaxf((v.z - s2.x) * s2.y, 0.f);
                    v.w = fmaxf((v.w - s3.x) * s3.y, 0.f);
                }
            }
            const float vv[4] = {v.x, v.y, v.z, v.w};
            unsigned hh[4], ll[4];
#pragma unroll
            for (int e = 0; e < 4; ++e) {
                const ushort_t h = f2bfbits(vv[e]);
                hh[e] = h;
                ll[e] = f2bfbits(vv[e] - bfbits2f(h));
            }
            const int off = (yy * 18 + xx) * 40 + cs;
            *(uint2*)&actH[off] = make_uint2(hh[0] | (hh[1] << 16), hh[2] | (hh[3] << 16));
            *(uint2*)&actL[off] = make_uint2(ll[0] | (ll[1] << 16), ll[2] | (ll[3] << 16));
        }
        // ---- stage weights from original layout: 9 x 32co x 32ci scalars ----
        for (int p = tid; p < 9216; p += 256) {
            const int k = p >> 10;
            const int co = (p & 1023) >> 5;
            const int ci = p & 31;
            const int cig = ci0 + ci;
            float v = 0.f;
            if (cig < CIreal)
                v = ldin(w, ((size_t)(cog * 32 + co) * CIreal + cig) * 9 + k, f32);
            const ushort_t h = f2bfbits(v);
            wHs[(k * 32 + co) * 40 + ci] = h;
            wLs[(k * 32 + co) * 40 + ci] = f2bfbits(v - bfbits2f(h));
        }
        __syncthreads();

#pragma unroll
        for (int k = 0; k < 9; ++k) {
            const int dy = k / 3, dx = k - 3 * (k / 3);
            const v8s bh0 = *(const v8s*)&wHs[(k * 32 + lm) * 40 + q8];
            const v8s bl0 = *(const v8s*)&wLs[(k * 32 + lm) * 40 + q8];
            const v8s bh1 = *(const v8s*)&wHs[(k * 32 + 16 + lm) * 40 + q8];
            const v8s bl1 = *(const v8s*)&wLs[(k * 32 + 16 + lm) * 40 + q8];
#pragma unroll
            for (int mt = 0; mt < 4; ++mt) {
                const int r = wv * 4 + mt;
                const int aoff = ((r + dy) * 18 + lm + dx) * 40 + q8;
                const v8s ah = *(const v8s*)&actH[aoff];
                const v8s al = *(const v8s*)&actL[aoff];
                acc[mt][0] = __builtin_amdgcn_mfma_f32_16x16x32_bf16(ah, bl0, acc[mt][0], 0, 0, 0);
                acc[mt][0] = __builtin_amdgcn_mfma_f32_16x16x32_bf16(al, bh0, acc[mt][0], 0, 0, 0);
                acc[mt][0] = __builtin_amdgcn_mfma_f32_16x16x32_bf16(ah, bh0, acc[mt][0], 0, 0, 0);
                acc[mt][1] = __builtin_amdgcn_mfma_f32_16x16x32_bf16(ah, bl1, acc[mt][1], 0, 0, 0);
                acc[mt][1] = __builtin_amdgcn_mfma_f32_16x16x32_bf16(al, bh1, acc[mt][1], 0, 0, 0);
                acc[mt][1] = __builtin_amdgcn_mfma_f32_16x16x32_bf16(ah, bh1, acc[mt][1], 0, 0, 0);
            }
        }
    }

    // D layout: col(n=co) = ln&15, row(m=x) = (ln>>4)*4 + i
#pragma unroll
    for (int mt = 0; mt < 4; ++mt) {
        const int y = ty + wv * 4 + mt;
#pragma unroll
        for (int nt = 0; nt < 2; ++nt) {
            const int co = cog * 32 + nt * 16 + lm;
#pragma unroll
            for (int i = 0; i < 4; ++i) {
                const int x = tx + ((ln >> 4) << 2) + i;
                out[(((size_t)(b * H + y)) * W + x) * CO + co] = acc[mt][nt][i];
            }
        }
    }
}

// =====================================================================
// Kernel 3b: FINE 3x3 conv, single-bf16 MFMA (R4 engine, coarse-validated)
// =====================================================================
template <bool BN>
__global__ __launch_bounds__(256) void conv3x3_mfma(
    const ushort_t* __restrict__ in,
    const ushort_t* __restrict__ wp,   // [9][CO][CI] bf16
    const float2* __restrict__ stats,
    ushort_t* __restrict__ out,
    int CI, int CO, int H, int W, int tilesX)
{
    __shared__ ushort_t act[18 * 18 * 40];
    __shared__ ushort_t wbuf[9 * 32 * 40];
    __shared__ float2 st[256];

    const int tid = threadIdx.x;
    const int tile = blockIdx.x;
    const int b = blockIdx.y;
    const int cog = blockIdx.z;
    const int ty = (tile / tilesX) * 16;
    const int tx = (tile % tilesX) * 16;
    const int wv = tid >> 6;
    const int ln = tid & 63;
    const int lm = ln & 15;
    const int q8 = (ln >> 4) * 8;

    if (BN) for (int c = tid; c < CI; c += 256) st[c] = stats[c];

    v4f acc[4][2];
#pragma unroll
    for (int i = 0; i < 4; ++i)
#pragma unroll
        for (int j = 0; j < 2; ++j) acc[i][j] = (v4f)(0.f);

    const int nChunks = CI >> 5;
    for (int ch = 0; ch < nChunks; ++ch) {
        const int ci0 = ch << 5;
        __syncthreads();
        for (int p = tid; p < 1296; p += 256) {
            const int yy = p / 72;
            const int rem = p - yy * 72;
            const int xx = rem >> 2;
            const int cs = (rem & 3) << 3;
            const int gy = ty + yy - 1, gx = tx + xx - 1;
            uint4 val = make_uint4(0u, 0u, 0u, 0u);
            if (gy >= 0 && gy < H && gx >= 0 && gx < W) {
                const ushort_t* gp = in + (((size_t)(b * H + gy)) * W + gx) * CI + ci0 + cs;
                val = *(const uint4*)gp;
                if (BN) {
                    unsigned u[4] = {val.x, val.y, val.z, val.w};
                    unsigned o[4];
#pragma unroll
                    for (int e = 0; e < 4; ++e) {
                        float lo = bfbits2f(u[e] & 0xffffu);
                        float hi = bfbits2f(u[e] >> 16);
                        const float2 s0 = st[ci0 + cs + 2 * e];
                        const float2 s1 = st[ci0 + cs + 2 * e + 1];
                        lo = fmaxf((lo - s0.x) * s0.y, 0.f);
                        hi = fmaxf((hi - s1.x) * s1.y, 0.f);
                        o[e] = (unsigned)f2bfbits(lo) | ((unsigned)f2bfbits(hi) << 16);
                    }
                    val = make_uint4(o[0], o[1], o[2], o[3]);
                }
            }
            *(uint4*)&act[(yy * 18 + xx) * 40 + cs] = val;
        }
        for (int p = tid; p < 1152; p += 256) {
            const int k = p / 128;
            const int rem = p - k * 128;
            const int co = rem >> 2;
            const int cs = (rem & 3) << 3;
            const ushort_t* gp = wp + ((size_t)k * CO + cog * 32 + co) * CI + ci0 + cs;
            *(uint4*)&wbuf[(k * 32 + co) * 40 + cs] = *(const uint4*)gp;
        }
        __syncthreads();

#pragma unroll
        for (int k = 0; k < 9; ++k) {
            const int dy = k / 3, dx = k - 3 * (k / 3);
            const v8s bf0 = *(const v8s*)&wbuf[(k * 32 + lm) * 40 + q8];
            const v8s bf1 = *(const v8s*)&wbuf[(k * 32 + 16 + lm) * 40 + q8];
#pragma unroll
            for (int mt = 0; mt < 4; ++mt) {
                const int r = wv * 4 + mt;
                const v8s af = *(const v8s*)&act[((r + dy) * 18 + lm + dx) * 40 + q8];
                acc[mt][0] = __builtin_amdgcn_mfma_f32_16x16x32_bf16(af, bf0, acc[mt][0], 0, 0, 0);
                acc[mt][1] = __builtin_amdgcn_mfma_f32_16x16x32_bf16(af, bf1, acc[mt][1], 0, 0, 0);
            }
        }
    }

#pragma unroll
    for (int mt = 0; mt < 4; ++mt) {
        const int y = ty + wv * 4 + mt;
#pragma unroll
        for (int nt = 0; nt < 2; ++nt) {
            const int co = cog * 32 + nt * 16 + lm;
#pragma unroll
            for (int i = 0; i < 4; ++i) {
                const int x = tx + ((ln >> 4) << 2) + i;
                out[(((size_t)(b * H + y)) * W + x) * CO + co] = f2bfbits(acc[mt][nt][i]);
            }
        }
    }
}

// =====================================================================
// Stats: two-stage deterministic over NHWC tensor (fp32 or bf16 source)
// =====================================================================
template <bool F32IN>
__global__ __launch_bounds__(256) void stats_stage1(
    const void* __restrict__ x, float* __restrict__ partial, int C, int PXblk)
{
    __shared__ float ls[256], lq[256];
    const int tid = threadIdx.x, blk = blockIdx.x;
    const int SUB = 256 / C;
    const int ci = (SUB == 1) ? tid : (tid & (C - 1));
    const int sub = (SUB == 1) ? 0 : (tid / C);
    float s = 0.f, s2 = 0.f;
    for (int j = sub; j < PXblk; j += SUB) {
        const size_t e = ((size_t)blk * PXblk + j) * C + ci;
        const float v = F32IN ? ((const float*)x)[e] : bfbits2f(((const ushort_t*)x)[e]);
        s += v; s2 += v * v;
    }
    if (SUB > 1) {
        ls[tid] = s; lq[tid] = s2;
        __syncthreads();
        if (tid < C) {
            for (int k2 = 1; k2 < SUB; ++k2) { s += ls[tid + k2 * C]; s2 += lq[tid + k2 * C]; }
        }
    }
    if (tid < C) {
        partial[((size_t)blk * C + tid) * 2]     = s;
        partial[((size_t)blk * C + tid) * 2 + 1] = s2;
    }
}

__global__ void stats_stage2(const float* __restrict__ partial, float2* __restrict__ st,
                             int C, float inv_n)
{
    const int ci = threadIdx.x;
    if (ci >= C) return;
    float s = 0.f, s2 = 0.f;
    for (int b = 0; b < 64; ++b) {
        s  += partial[((size_t)b * C + ci) * 2];
        s2 += partial[((size_t)b * C + ci) * 2 + 1];
    }
    const float mean = s * inv_n;
    const float var = s2 * inv_n - mean * mean;
    st[ci] = make_float2(mean, 1.0f / sqrtf(var + 1e-5f));
}

// =====================================================================
// Kernel 5: coarse head (fp32 NHWC): 1x1 conv 256->3 on relu(bn(A)) + bias
// + cm0; writes cmatch IN PLACE over cm0 (per-thread read-then-write) + out0.
// =====================================================================
__global__ __launch_bounds__(256) void coarse_head_kernel(
    const float* __restrict__ A, const float2* __restrict__ stats,
    const void* __restrict__ w5, const void* __restrict__ b5,
    float* __restrict__ cm0, void* __restrict__ out,
    const int* __restrict__ dflag)
{
    const int f32 = *dflag;
    __shared__ float wl[3][256];
    __shared__ float bl[3];
    __shared__ float2 st[256];
    const int tid = threadIdx.x;
    for (int i = tid; i < 768; i += 256) wl[i >> 8][i & 255] = ldin(w5, i, f32);
    if (tid < 3) bl[tid] = ldin(b5, tid, f32);
    st[tid] = stats[tid];
    __syncthreads();

    const int idx = blockIdx.x * 256 + tid;
    const int b = idx >> 12, hw = idx & (JC - 1);
    float a0 = bl[0], a1 = bl[1], a2 = bl[2];
    const float* p = A + (size_t)idx * 256;
    for (int c = 0; c < 256; c += 4) {
        const float4 raw = *(const float4*)(p + c);
        const float rv[4] = {raw.x, raw.y, raw.z, raw.w};
#pragma unroll
        for (int e = 0; e < 4; ++e) {
            const int cc = c + e;
            const float v = fmaxf((rv[e] - st[cc].x) * st[cc].y, 0.f);
            a0 += v * wl[0][cc]; a1 += v * wl[1][cc]; a2 += v * wl[2][cc];
        }
    }
    const size_t base = (size_t)b * 3 * JC + hw;
    const float c0 = cm0[base] + a0;
    const float c1 = cm0[base + JC] + a1;
    const float c2 = cm0[base + 2 * JC] + a2;
    cm0[base] = c0; cm0[base + JC] = c1; cm0[base + 2 * JC] = c2;
    stout(out, base, c0, f32);
    stout(out, base + JC, c1, f32);
    stout(out, base + 2 * JC, c2, f32);
}

// =====================================================================
// Kernel 6: bilinear 2x upsample (half-pixel, edge clamp)
// =====================================================================
__global__ __launch_bounds__(256) void upsample_kernel(
    const float* __restrict__ cm, float* __restrict__ up)
{
    const int idx = blockIdx.x * 256 + threadIdx.x;
    const int ox = idx & 127, oy = (idx >> 7) & 127, bc = idx >> 14;
    const float sx = ox * 0.5f - 0.25f;
    const float sy = oy * 0.5f - 0.25f;
    const int x0 = (int)floorf(sx), y0 = (int)floorf(sy);
    const float fx = sx - x0, fy = sy - y0;
    const int cx0 = max(x0, 0), cx1 = min(x0 + 1, WC - 1);
    const int cy0 = max(y0, 0), cy1 = min(y0 + 1, HC - 1);
    const float* p = cm + (size_t)bc * JC;
    const float v = (1.f - fy) * ((1.f - fx) * p[cy0 * WC + cx0] + fx * p[cy0 * WC + cx1])
                  + fy * ((1.f - fx) * p[cy1 * WC + cx0] + fx * p[cy1 * WC + cx1]);
    up[idx] = v;
}

// =====================================================================
// Kernel 7: fine concat -> NHWC bf16 [b][y][x][64] (50 real + 14 zero)
// =====================================================================
__global__ __launch_bounds__(256) void fine_concat_nhwc(
    const void* __restrict__ f0f, const void* __restrict__ f1f,
    const float* __restrict__ up, ushort_t* __restrict__ A,
    const int* __restrict__ dflag)
{
    const int f32 = *dflag;
    const int idx = blockIdx.x * 256 + threadIdx.x;   // B*JF
    const int b = idx >> 14, hw = idx & (JF - 1);
    const size_t ib = (size_t)b * CF * JF;
    ushort_t* o = A + (size_t)idx * 64;

    for (int c = 0; c < CF; ++c)
        o[c] = f2bfbits(ldin(f0f, ib + (size_t)c * JF + hw, f32));

    const size_t ub = (size_t)b * 3 * JF + hw;
    const float gx = up[ub], gy = up[ub + JF];
    const float x = (gx + 1.f) * 64.f - 0.5f;
    const float y = (gy + 1.f) * 64.f - 0.5f;
    const float x0f = floorf(x), y0f = floorf(y);
    const float wx = x - x0f, wy = y - y0f;
    const int x0 = (int)x0f, y0 = (int)y0f;
    const int x1 = x0 + 1, y1 = y0 + 1;
    const float vx0 = (x0 >= 0 && x0 < WF) ? 1.f : 0.f;
    const float vx1 = (x1 >= 0 && x1 < WF) ? 1.f : 0.f;
    const float vy0 = (y0 >= 0 && y0 < HF) ? 1.f : 0.f;
    const float vy1 = (y1 >= 0 && y1 < HF) ? 1.f : 0.f;
    const int cx0 = min(max(x0, 0), WF - 1), cx1 = min(max(x1, 0), WF - 1);
    const int cy0 = min(max(y0, 0), HF - 1), cy1 = min(max(y1, 0), HF - 1);
    const float w00 = (1.f - wx) * (1.f - wy) * vx0 * vy0;
    const float w01 = wx * (1.f - wy) * vx1 * vy0;
    const float w10 = (1.f - wx) * wy * vx0 * vy1;
    const float w11 = wx * wy * vx1 * vy1;
    const int i00 = cy0 * WF + cx0, i01 = cy0 * WF + cx1;
    const int i10 = cy1 * WF + cx0, i11 = cy1 * WF + cx1;

    for (int c = 0; c < CF; ++c) {
        const size_t pb = ib + (size_t)c * JF;
        const float v = w00 * ldin(f1f, pb + i00, f32) + w01 * ldin(f1f, pb + i01, f32)
                      + w10 * ldin(f1f, pb + i10, f32) + w11 * ldin(f1f, pb + i11, f32);
        o[24 + c] = f2bfbits(v);
    }
    o[48] = f2bfbits(gx);
    o[49] = f2bfbits(gy);
    for (int c = 50; c < 64; ++c) o[c] = 0;
}

// =====================================================================
// Kernel 8: fine head (NHWC bf16): 1x1 conv 64->3 + bias + up -> out1
// =====================================================================
__global__ __launch_bounds__(256) void fine_head_kernel(
    const ushort_t* __restrict__ A, const float2* __restrict__ stats,
    const void* __restrict__ w5, const void* __restrict__ b5,
    const float* __restrict__ up, void* __restrict__ out,
    const int* __restrict__ dflag)
{
    const int f32 = *dflag;
    __shared__ float wl[3][64];
    __shared__ float bl[3];
    __shared__ float2 st[64];
    const int tid = threadIdx.x;
    if (tid < 192) wl[tid >> 6][tid & 63] = ldin(w5, tid, f32);
    if (tid < 3) bl[tid] = ldin(b5, tid, f32);
    if (tid < 64) st[tid] = stats[tid];
    __syncthreads();

    const int idx = blockIdx.x * 256 + tid;
    const int b = idx >> 14, hw = idx & (JF - 1);
    float a0 = bl[0], a1 = bl[1], a2 = bl[2];
    const ushort_t* p = A + (size_t)idx * 64;
    for (int c = 0; c < 64; c += 8) {
        const uint4 raw = *(const uint4*)(p + c);
        const unsigned u[4] = {raw.x, raw.y, raw.z, raw.w};
#pragma unroll
        for (int e = 0; e < 4; ++e) {
            const int c0 = c + 2 * e, c1 = c0 + 1;
            float lo = bfbits2f(u[e] & 0xffffu);
            float hi = bfbits2f(u[e] >> 16);
            lo = fmaxf((lo - st[c0].x) * st[c0].y, 0.f);
            hi = fmaxf((hi - st[c1].x) * st[c1].y, 0.f);
            a0 += lo * wl[0][c0] + hi * wl[0][c1];
            a1 += lo * wl[1][c0] + hi * wl[1][c1];
            a2 += lo * wl[2][c0] + hi * wl[2][c1];
        }
    }
    const size_t base = (size_t)b * 3 * JF + hw;
    stout(out, OUT0_ELEMS + base,          up[base] + a0, f32);
    stout(out, OUT0_ELEMS + base + JF,     up[base + JF] + a1, f32);
    stout(out, OUT0_ELEMS + base + 2 * JF, up[base + 2 * JF] + a2, f32);
}

// =====================================================================
extern "C" void kernel_launch(void* const* d_in, const int* in_sizes, int n_in,
                              void* d_out, int out_size, void* d_ws, size_t ws_size,
                              hipStream_t stream)
{
    const void* f0c = d_in[0];
    const void* f1c = d_in[1];
    const void* f0f = d_in[2];
    const void* f1f = d_in[3];
    const void* cw1 = d_in[4];
    const void* cw2 = d_in[5];
    const void* cw3 = d_in[6];
    const void* cw4 = d_in[7];
    const void* cw5 = d_in[8];
    const void* cb5 = d_in[9];
    const void* fw1 = d_in[10];
    const void* fw2 = d_in[11];
    const void* fw3 = d_in[12];
    const void* fw4 = d_in[13];
    const void* fw5 = d_in[14];
    const void* fb5 = d_in[15];

    // ---- workspace layout (byte offsets; total ~33.4 MiB) ----
    char* wsb = (char*)d_ws;
    float* bufA    = (float*)wsb;                       // 16,777,216 B (fp32 coarse / aliased fine F2)
    float* bufB    = (float*)(wsb + 16777216);          // 16,777,216 B (fp32 coarse / aliased fine F1)
    float* cm0     = (float*)(wsb + 33554432);          // 196,608 B (becomes cmatch in head)
    float* up      = (float*)(wsb + 33751040);          // 786,432 B
    float* partial = (float*)(wsb + 34537472);          // 131,072 B
    float2* st_g   = (float2*)(wsb + 34668544);         // 2,048 B
    int* dflag     = (int*)(wsb + 34670592);            // 4 B (+pad)
    ushort_t* fwp  = (ushort_t*)(wsb + 34670656);       // 4*36864*2 = 294,912 B
    ushort_t* fw1p = fwp;
    ushort_t* fw2p = fwp + 36864;
    ushort_t* fw3p = fwp + 73728;
    ushort_t* fw4p = fwp + 110592;

    ushort_t* fF1 = (ushort_t*)bufB;   // fine ping
    ushort_t* fF2 = (ushort_t*)bufA;   // fine pong

    // 0. dtype probe
    dtype_probe_kernel<<<1, 256, 0, stream>>>((const ushort_t*)f0c, dflag);

    // fine weight repacks (bf16 [k][co][ci_pad])
    repack_w_kernel<<<(9 * 64 * 64 + 255) / 256, 256, 0, stream>>>(fw1, fw1p, 64, 50, 64, dflag);
    repack_w_kernel<<<(9 * 64 * 64 + 255) / 256, 256, 0, stream>>>(fw2, fw2p, 64, 64, 64, dflag);
    repack_w_kernel<<<(9 * 64 * 64 + 255) / 256, 256, 0, stream>>>(fw3, fw3p, 64, 64, 64, dflag);
    repack_w_kernel<<<(9 * 64 * 64 + 255) / 256, 256, 0, stream>>>(fw4, fw4p, 64, 64, 64, dflag);

    // 1. correlation + softmax + warp
    corr_warp_kernel<<<dim3(HC, B_), 256, 0, stream>>>(f0c, f1c, cm0, dflag);

    // 2. coarse concat -> bufA (fp32 NHWC 160)
    coarse_concat_f32<<<dim3(B_ * JC / 256), 256, 0, stream>>>(f0c, f1c, cm0, bufA, dflag);

    // 3. coarse conv stack: split-bf16 MFMA, fp32 activations
    const dim3 cgrid(16, B_, 8);
    const size_t SLDS = 99968;
    conv3x3_split<false><<<cgrid, 256, SLDS, stream>>>(bufA, cw1, nullptr, bufB, 160, 130, 256, HC, WC, 4, dflag);
    stats_stage1<true><<<64, 256, 0, stream>>>(bufB, partial, 256, 256);
    stats_stage2<<<1, 256, 0, stream>>>(partial, st_g, 256, 1.f / 16384.f);
    conv3x3_split<true><<<cgrid, 256, SLDS, stream>>>(bufB, cw2, st_g, bufA, 256, 256, 256, HC, WC, 4, dflag);
    stats_stage1<true><<<64, 256, 0, stream>>>(bufA, partial, 256, 256);
    stats_stage2<<<1, 256, 0, stream>>>(partial, st_g, 256, 1.f / 16384.f);
    conv3x3_split<true><<<cgrid, 256, SLDS, stream>>>(bufA, cw3, st_g, bufB, 256, 256, 256, HC, WC, 4, dflag);
    stats_stage1<true><<<64, 256, 0, stream>>>(bufB, partial, 256, 256);
    stats_stage2<<<1, 256, 0, stream>>>(partial, st_g, 256, 1.f / 16384.f);
    conv3x3_split<true><<<cgrid, 256, SLDS, stream>>>(bufB, cw4, st_g, bufA, 256, 256, 256, HC, WC, 4, dflag);
    stats_stage1<true><<<64, 256, 0, stream>>>(bufA, partial, 256, 256);
    stats_stage2<<<1, 256, 0, stream>>>(partial, st_g, 256, 1.f / 16384.f);

    // 4. coarse head -> out0, cmatch (in place over cm0)
    coarse_head_kernel<<<dim3(B_ * JC / 256), 256, 0, stream>>>(bufA, st_g, cw5, cb5, cm0, d_out, dflag);

    // 5. upsample (cm0 now holds cmatch)
    upsample_kernel<<<dim3(B_ * 3 * JF / 256), 256, 0, stream>>>(cm0, up);

    // 6. fine concat -> fF1 (bufB region; coarse data there is dead)
    fine_concat_nhwc<<<dim3(B_ * JF / 256), 256, 0, stream>>>(f0f, f1f, up, fF1, dflag);

    // 7. fine conv stack (bf16 MFMA)
    const dim3 fgrid(64, B_, 2);
    conv3x3_mfma<false><<<fgrid, 256, 0, stream>>>(fF1, fw1p, nullptr, fF2, 64, 64, HF, WF, 8);
    stats_stage1<false><<<64, 256, 0, stream>>>(fF2, partial, 64, 1024);
    stats_stage2<<<1, 256, 0, stream>>>(partial, st_g, 64, 1.f / 65536.f);
    conv3x3_mfma<true><<<fgrid, 256, 0, stream>>>(fF2, fw2p, st_g, fF1, 64, 64, HF, WF, 8);
    stats_stage1<false><<<64, 256, 0, stream>>>(fF1, partial, 64, 1024);
    stats_stage2<<<1, 256, 0, stream>>>(partial, st_g, 64, 1.f / 65536.f);
    conv3x3_mfma<true><<<fgrid, 256, 0, stream>>>(fF1, fw3p, st_g, fF2, 64, 64, HF, WF, 8);
    stats_stage1<false><<<64, 256, 0, stream>>>(fF2, partial, 64, 1024);
    stats_stage2<<<1, 256, 0, stream>>>(partial, st_g, 64, 1.f / 65536.f);
    conv3x3_mfma<true><<<fgrid, 256, 0, stream>>>(fF2, fw4p, st_g, fF1, 64, 64, HF, WF, 8);
    stats_stage1<false><<<64, 256, 0, stream>>>(fF1, partial, 64, 1024);
    stats_stage2<<<1, 256, 0, stream>>>(partial, st_g, 64, 1.f / 65536.f);

    // 8. fine head -> out1
    fine_head_kernel<<<dim3(B_ * JF / 256), 256, 0, stream>>>(fF1, st_g, fw5, fb5, up, d_out, dflag);
}

// Round 6
// 1826.755 us; speedup vs baseline: 2.6961x; 1.1569x over previous
//
#include <hip/hip_runtime.h>
#include <hip/hip_bf16.h>

using bf16 = __hip_bfloat16;
typedef unsigned short ushort_t;
typedef __attribute__((ext_vector_type(8))) short v8s;
typedef __attribute__((ext_vector_type(4))) float v4f;

__device__ __forceinline__ float bfbits2f(unsigned u) {
    return __uint_as_float(u << 16);
}
__device__ __forceinline__ ushort_t f2bfbits(float f) {
    unsigned x = __float_as_uint(f);
    return (ushort_t)((x + 0x7fffu + ((x >> 16) & 1u)) >> 16);
}
// dtype-adaptive input load / output store (flag: 1 = fp32 buffers, 0 = bf16)
__device__ __forceinline__ float ldin(const void* p, size_t i, int f32) {
    return f32 ? ((const float*)p)[i] : bfbits2f(((const ushort_t*)p)[i]);
}
__device__ __forceinline__ void stout(void* p, size_t i, float v, int f32) {
    if (f32) ((float*)p)[i] = v;
    else     ((ushort_t*)p)[i] = f2bfbits(v);
}

// ---------------- sizes ----------------
#define B_   4
#define CC   64
#define HC   64
#define WC   64
#define JC   4096
#define CF   24
#define HF   128
#define WF   128
#define JF   16384
#define OUT0_ELEMS (B_ * 3 * JC)

// =====================================================================
// Kernel 0: dtype probe. flag=1 -> fp32 inputs (R3: confirmed fp32).
// =====================================================================
__global__ void dtype_probe_kernel(const ushort_t* __restrict__ x,
                                   int* __restrict__ flag)
{
    __shared__ int cnt;
    if (threadIdx.x == 0) cnt = 0;
    __syncthreads();
    int c = 0;
    for (int i = threadIdx.x; i < 8192; i += 256) {
        const unsigned e = (x[i] >> 7) & 0xFF;
        if (e >= 0x89) ++c;
    }
    atomicAdd(&cnt, c);
    __syncthreads();
    if (threadIdx.x == 0) *flag = (cnt > 64) ? 1 : 0;
}

// =====================================================================
// Fine weight repack: w[co][ci][3][3] -> wp[k][co][ci_pad] bf16
// =====================================================================
__global__ void repack_w_kernel(const void* __restrict__ w, ushort_t* __restrict__ wp,
                                int CO, int CIreal, int CIP, const int* __restrict__ dflag)
{
    const int f32 = *dflag;
    const int idx = blockIdx.x * 256 + threadIdx.x;
    const int total = 9 * CO * CIP;
    if (idx >= total) return;
    const int k = idx / (CO * CIP);
    const int rem = idx - k * (CO * CIP);
    const int co = rem / CIP;
    const int cip = rem - co * CIP;
    float v = 0.f;
    if (cip < CIreal) v = ldin(w, ((size_t)co * CIreal + cip) * 9 + k, f32);
    wp[((size_t)k * CO + co) * CIP + cip] = f2bfbits(v);
}

// =====================================================================
// Kernel 1a: split-transpose feats: [b][64ch][4096px] -> [b][4096px][64ch]
// hi/lo bf16 planes. grid: B*64 blocks (64 px each), 256 thr.
// =====================================================================
__global__ __launch_bounds__(256) void split_transpose_kernel(
    const void* __restrict__ src, ushort_t* __restrict__ hi,
    ushort_t* __restrict__ lo, const int* __restrict__ dflag)
{
    const int f32 = *dflag;
    __shared__ float t[64][65];   // +1 pad: stride 65 -> conflict-free
    const int blk = blockIdx.x;
    const int b = blk >> 6;
    const int px0 = (blk & 63) * 64;
    const int tid = threadIdx.x;
    const int px = tid & 63;
    for (int i = 0; i < 16; ++i) {
        const int c = (tid >> 6) + 4 * i;
        t[px][c] = ldin(src, ((size_t)b * 64 + c) * 4096 + px0 + px, f32);
    }
    __syncthreads();
    for (int it = 0; it < 2; ++it) {
        const int p = tid + it * 256;
        const int opx = p >> 3, chk = (p & 7) * 8;
        unsigned hh[4], ll[4];
#pragma unroll
        for (int e = 0; e < 4; ++e) {
            const float v0 = t[opx][chk + 2 * e];
            const float v1 = t[opx][chk + 2 * e + 1];
            const ushort_t h0 = f2bfbits(v0);
            const ushort_t h1 = f2bfbits(v1);
            hh[e] = (unsigned)h0 | ((unsigned)h1 << 16);
            ll[e] = (unsigned)f2bfbits(v0 - bfbits2f(h0))
                  | ((unsigned)f2bfbits(v1 - bfbits2f(h1)) << 16);
        }
        const size_t obase = ((size_t)b * 4096 + px0 + opx) * 64 + chk;
        *(uint4*)&hi[obase] = make_uint4(hh[0], hh[1], hh[2], hh[3]);
        *(uint4*)&lo[obase] = make_uint4(ll[0], ll[1], ll[2], ll[3]);
    }
}

// =====================================================================
// Kernel 1b: correlation + softmax + expectation via split-bf16 MFMA.
// grid (HC, B), 256 thr / 4 waves. Per block: 64 queries (row h of f0)
// x 4096 keys x 64 ch. Unnormalized softmax (no running max: |s|<=~10,
// fp32 exp safe). Wave wv handles keys {chunk + wv*32 .. +31}.
// =====================================================================
#define KCH 128
__global__ __launch_bounds__(256) void corr_mfma_kernel(
    const ushort_t* __restrict__ qhi, const ushort_t* __restrict__ qlo,
    const ushort_t* __restrict__ khi, const ushort_t* __restrict__ klo,
    float* __restrict__ cm0)
{
    __shared__ ushort_t kbh[KCH * 72];   // 18432 B (72 pad: 2-way = free)
    __shared__ ushort_t kbl[KCH * 72];   // 18432 B
    __shared__ float red[4][64][3];      // 3072 B
    const int h = blockIdx.x, b = blockIdx.y;
    const int tid = threadIdx.x;
    const int wv = tid >> 6, ln = tid & 63;
    const int lm = ln & 15, quad = ln >> 4, q8 = quad * 8;

    // Q fragments in registers: [mt][kchunk][plane]
    v8s qf[4][2][2];
#pragma unroll
    for (int mt = 0; mt < 4; ++mt)
#pragma unroll
        for (int kc = 0; kc < 2; ++kc) {
            const size_t qoff = ((size_t)b * 4096 + h * 64 + mt * 16 + lm) * 64 + kc * 32 + q8;
            qf[mt][kc][0] = *(const v8s*)&qhi[qoff];
            qf[mt][kc][1] = *(const v8s*)&qlo[qoff];
        }

    float P[4][4][3];   // [mt][reg][l, sum p*gx, sum p*gy]
#pragma unroll
    for (int mt = 0; mt < 4; ++mt)
#pragma unroll
        for (int i = 0; i < 4; ++i)
            P[mt][i][0] = P[mt][i][1] = P[mt][i][2] = 0.f;

    const size_t kbase = (size_t)b * 4096 * 64;
    for (int c = 0; c < 4096 / KCH; ++c) {
        const int j0 = c * KCH;
        __syncthreads();
        // stage K chunk: 2 planes x 128 keys x 8 ch-chunks (uint4 = 8 bf16)
        for (int p = tid; p < 2048; p += 256) {
            const int pl = p >> 10;
            const int r = p & 1023;
            const int key = r >> 3, chk = (r & 7) * 8;
            const ushort_t* gsrc = pl ? klo : khi;
            const uint4 v = *(const uint4*)&gsrc[kbase + (size_t)(j0 + key) * 64 + chk];
            ushort_t* dst = pl ? kbl : kbh;
            *(uint4*)&dst[key * 72 + chk] = v;
        }
        __syncthreads();

#pragma unroll
        for (int nt = 0; nt < 2; ++nt) {
            const int kb = wv * 32 + nt * 16;
            const int j = j0 + kb + lm;
            const float gx = (float)((j & 63) * 2 + 1) * (1.f / 64.f) - 1.f;
            const float gy = (float)((j >> 6) * 2 + 1) * (1.f / 64.f) - 1.f;
            const v8s bh0 = *(const v8s*)&kbh[(kb + lm) * 72 + q8];
            const v8s bh1 = *(const v8s*)&kbh[(kb + lm) * 72 + 32 + q8];
            const v8s bl0 = *(const v8s*)&kbl[(kb + lm) * 72 + q8];
            const v8s bl1 = *(const v8s*)&kbl[(kb + lm) * 72 + 32 + q8];
#pragma unroll
            for (int mt = 0; mt < 4; ++mt) {
                v4f acc = (v4f)(0.f);
                acc = __builtin_amdgcn_mfma_f32_16x16x32_bf16(qf[mt][0][0], bl0, acc, 0, 0, 0);
                acc = __builtin_amdgcn_mfma_f32_16x16x32_bf16(qf[mt][0][1], bh0, acc, 0, 0, 0);
                acc = __builtin_amdgcn_mfma_f32_16x16x32_bf16(qf[mt][0][0], bh0, acc, 0, 0, 0);
                acc = __builtin_amdgcn_mfma_f32_16x16x32_bf16(qf[mt][1][0], bl1, acc, 0, 0, 0);
                acc = __builtin_amdgcn_mfma_f32_16x16x32_bf16(qf[mt][1][1], bh1, acc, 0, 0, 0);
                acc = __builtin_amdgcn_mfma_f32_16x16x32_bf16(qf[mt][1][0], bh1, acc, 0, 0, 0);
#pragma unroll
                for (int i = 0; i < 4; ++i) {
                    const float p_ = __expf(acc[i] * 0.125f);
                    P[mt][i][0] += p_;
                    P[mt][i][1] += p_ * gx;
                    P[mt][i][2] += p_ * gy;
                }
            }
        }
    }

    // butterfly reduce across the 16 key-lanes (lm bits 0..3)
#pragma unroll
    for (int mt = 0; mt < 4; ++mt)
#pragma unroll
        for (int i = 0; i < 4; ++i)
#pragma unroll
            for (int d = 0; d < 3; ++d) {
                float v = P[mt][i][d];
                v += __shfl_xor(v, 1);
                v += __shfl_xor(v, 2);
                v += __shfl_xor(v, 4);
                v += __shfl_xor(v, 8);
                P[mt][i][d] = v;
            }
    if (lm == 0) {
#pragma unroll
        for (int mt = 0; mt < 4; ++mt)
#pragma unroll
            for (int i = 0; i < 4; ++i) {
                const int q = mt * 16 + quad * 4 + i;
                red[wv][q][0] = P[mt][i][0];
                red[wv][q][1] = P[mt][i][1];
                red[wv][q][2] = P[mt][i][2];
            }
    }
    __syncthreads();
    if (tid < 64) {
        const int q = tid;
        float l = 0.f, ax = 0.f, ay = 0.f;
        for (int w = 0; w < 4; ++w) {
            l += red[w][q][0]; ax += red[w][q][1]; ay += red[w][q][2];
        }
        const float inv = 1.f / l;
        const size_t base = (size_t)b * 3 * JC + h * 64 + q;
        cm0[base]          = ax * inv;
        cm0[base + JC]     = ay * inv;
        cm0[base + 2 * JC] = 0.f;
    }
}

// =====================================================================
// Kernel 2: coarse concat -> fp32 NHWC [b][y][x][160] (130 real + 30 zero)
// =====================================================================
__global__ __launch_bounds__(256) void coarse_concat_f32(
    const void* __restrict__ f0c, const void* __restrict__ f1c,
    const float* __restrict__ cm0, float* __restrict__ A,
    const int* __restrict__ dflag)
{
    const int f32 = *dflag;
    const int idx = blockIdx.x * 256 + threadIdx.x;   // B*JC
    const int b = idx >> 12, hw = idx & (JC - 1);
    const size_t ib = (size_t)b * CC * JC;
    float* o = A + (size_t)idx * 160;

    for (int c = 0; c < CC; ++c)
        o[c] = ldin(f0c, ib + (size_t)c * JC + hw, f32);

    const float gx = cm0[((size_t)b * 3 + 0) * JC + hw];
    const float gy = cm0[((size_t)b * 3 + 1) * JC + hw];
    const float x = (gx + 1.f) * 32.f - 0.5f;
    const float y = (gy + 1.f) * 32.f - 0.5f;
    const float x0f = floorf(x), y0f = floorf(y);
    const float wx = x - x0f, wy = y - y0f;
    const int x0 = (int)x0f, y0 = (int)y0f;
    const int x1 = x0 + 1, y1 = y0 + 1;
    const float vx0 = (x0 >= 0 && x0 < WC) ? 1.f : 0.f;
    const float vx1 = (x1 >= 0 && x1 < WC) ? 1.f : 0.f;
    const float vy0 = (y0 >= 0 && y0 < HC) ? 1.f : 0.f;
    const float vy1 = (y1 >= 0 && y1 < HC) ? 1.f : 0.f;
    const int cx0 = min(max(x0, 0), WC - 1), cx1 = min(max(x1, 0), WC - 1);
    const int cy0 = min(max(y0, 0), HC - 1), cy1 = min(max(y1, 0), HC - 1);
    const float w00 = (1.f - wx) * (1.f - wy) * vx0 * vy0;
    const float w01 = wx * (1.f - wy) * vx1 * vy0;
    const float w10 = (1.f - wx) * wy * vx0 * vy1;
    const float w11 = wx * wy * vx1 * vy1;
    const int i00 = cy0 * WC + cx0, i01 = cy0 * WC + cx1;
    const int i10 = cy1 * WC + cx0, i11 = cy1 * WC + cx1;

    for (int c = 0; c < CC; ++c) {
        const size_t pb = ib + (size_t)c * JC;
        o[64 + c] = w00 * ldin(f1c, pb + i00, f32) + w01 * ldin(f1c, pb + i01, f32)
                  + w10 * ldin(f1c, pb + i10, f32) + w11 * ldin(f1c, pb + i11, f32);
    }
    o[128] = gx;
    o[129] = gy;
    for (int c = 130; c < 160; ++c) o[c] = 0.f;
}

// =====================================================================
// Kernel 3a: COARSE 3x3 conv, SPLIT-bf16 MFMA (hi/lo planes, 3 MFMA/pair)
// =====================================================================
template <bool BN>
__global__ __launch_bounds__(256) void conv3x3_split(
    const float* __restrict__ in,    // fp32 NHWC [B][H][W][CI]
    const void* __restrict__ w,      // original [CO][CIreal][3][3]
    const float2* __restrict__ stats,
    float* __restrict__ out,         // fp32 NHWC [B][H][W][CO]
    int CI, int CIreal, int CO, int H, int W, int tilesX,
    const int* __restrict__ dflag)
{
    extern __shared__ char smem[];
    ushort_t* actH = (ushort_t*)smem;          // 12960
    ushort_t* actL = actH + 12960;             // 12960
    ushort_t* wHs  = actL + 12960;             // 11520
    ushort_t* wLs  = wHs + 11520;              // 11520
    float2*   st   = (float2*)(wLs + 11520);   // 256

    const int f32 = *dflag;
    const int tid = threadIdx.x;
    const int tile = blockIdx.x;
    const int b = blockIdx.y;
    const int cog = blockIdx.z;
    const int ty = (tile / tilesX) * 16;
    const int tx = (tile % tilesX) * 16;
    const int wv = tid >> 6;
    const int ln = tid & 63;
    const int lm = ln & 15;
    const int q8 = (ln >> 4) * 8;

    if (BN) for (int c = tid; c < CI; c += 256) st[c] = stats[c];

    v4f acc[4][2];
#pragma unroll
    for (int i = 0; i < 4; ++i)
#pragma unroll
        for (int j = 0; j < 2; ++j) acc[i][j] = (v4f)(0.f);

    const int nChunks = CI >> 5;
    for (int ch = 0; ch < nChunks; ++ch) {
        const int ci0 = ch << 5;
        __syncthreads();
        for (int p = tid; p < 2592; p += 256) {
            const int yy = p / 144;
            const int rem = p - yy * 144;
            const int xx = rem >> 3;
            const int cs = (rem & 7) << 2;
            const int gy = ty + yy - 1, gx = tx + xx - 1;
            float4 v = make_float4(0.f, 0.f, 0.f, 0.f);
            if (gy >= 0 && gy < H && gx >= 0 && gx < W) {
                v = *(const float4*)(in + (((size_t)(b * H + gy)) * W + gx) * CI + ci0 + cs);
                if (BN) {
                    const float2 s0 = st[ci0 + cs + 0];
                    const float2 s1 = st[ci0 + cs + 1];
                    const float2 s2 = st[ci0 + cs + 2];
                    const float2 s3 = st[ci0 + cs + 3];
                    v.x = fmaxf((v.x - s0.x) * s0.y, 0.f);
                    v.y = fmaxf((v.y - s1.x) * s1.y, 0.f);
                    v.z = fmaxf((v.z - s2.x) * s2.y, 0.f);
                    v.w = fmaxf((v.w - s3.x) * s3.y, 0.f);
                }
            }
            const float vv[4] = {v.x, v.y, v.z, v.w};
            unsigned hh[4], ll[4];
#pragma unroll
            for (int e = 0; e < 4; ++e) {
                const ushort_t h = f2bfbits(vv[e]);
                hh[e] = h;
                ll[e] = f2bfbits(vv[e] - bfbits2f(h));
            }
            const int off = (yy * 18 + xx) * 40 + cs;
            *(uint2*)&actH[off] = make_uint2(hh[0] | (hh[1] << 16), hh[2] | (hh[3] << 16));
            *(uint2*)&actL[off] = make_uint2(ll[0] | (ll[1] << 16), ll[2] | (ll[3] << 16));
        }
        for (int p = tid; p < 9216; p += 256) {
            const int k = p >> 10;
            const int co = (p & 1023) >> 5;
            const int ci = p & 31;
            const int cig = ci0 + ci;
            float v = 0.f;
            if (cig < CIreal)
                v = ldin(w, ((size_t)(cog * 32 + co) * CIreal + cig) * 9 + k, f32);
            const ushort_t h = f2bfbits(v);
            wHs[(k * 32 + co) * 40 + ci] = h;
            wLs[(k * 32 + co) * 40 + ci] = f2bfbits(v - bfbits2f(h));
        }
        __syncthreads();

#pragma unroll
        for (int k = 0; k < 9; ++k) {
            const int dy = k / 3, dx = k - 3 * (k / 3);
            const v8s bh0 = *(const v8s*)&wHs[(k * 32 + lm) * 40 + q8];
            const v8s bl0 = *(const v8s*)&wLs[(k * 32 + lm) * 40 + q8];
            const v8s bh1 = *(const v8s*)&wHs[(k * 32 + 16 + lm) * 40 + q8];
            const v8s bl1 = *(const v8s*)&wLs[(k * 32 + 16 + lm) * 40 + q8];
#pragma unroll
            for (int mt = 0; mt < 4; ++mt) {
                const int r = wv * 4 + mt;
                const int aoff = ((r + dy) * 18 + lm + dx) * 40 + q8;
                const v8s ah = *(const v8s*)&actH[aoff];
                const v8s al = *(const v8s*)&actL[aoff];
                acc[mt][0] = __builtin_amdgcn_mfma_f32_16x16x32_bf16(ah, bl0, acc[mt][0], 0, 0, 0);
                acc[mt][0] = __builtin_amdgcn_mfma_f32_16x16x32_bf16(al, bh0, acc[mt][0], 0, 0, 0);
                acc[mt][0] = __builtin_amdgcn_mfma_f32_16x16x32_bf16(ah, bh0, acc[mt][0], 0, 0, 0);
                acc[mt][1] = __builtin_amdgcn_mfma_f32_16x16x32_bf16(ah, bl1, acc[mt][1], 0, 0, 0);
                acc[mt][1] = __builtin_amdgcn_mfma_f32_16x16x32_bf16(al, bh1, acc[mt][1], 0, 0, 0);
                acc[mt][1] = __builtin_amdgcn_mfma_f32_16x16x32_bf16(ah, bh1, acc[mt][1], 0, 0, 0);
            }
        }
    }

#pragma unroll
    for (int mt = 0; mt < 4; ++mt) {
        const int y = ty + wv * 4 + mt;
#pragma unroll
        for (int nt = 0; nt < 2; ++nt) {
            const int co = cog * 32 + nt * 16 + lm;
#pragma unroll
            for (int i = 0; i < 4; ++i) {
                const int x = tx + ((ln >> 4) << 2) + i;
                out[(((size_t)(b * H + y)) * W + x) * CO + co] = acc[mt][nt][i];
            }
        }
    }
}

// =====================================================================
// Kernel 3b: FINE 3x3 conv, single-bf16 MFMA
// =====================================================================
template <bool BN>
__global__ __launch_bounds__(256) void conv3x3_mfma(
    const ushort_t* __restrict__ in,
    const ushort_t* __restrict__ wp,   // [9][CO][CI] bf16
    const float2* __restrict__ stats,
    ushort_t* __restrict__ out,
    int CI, int CO, int H, int W, int tilesX)
{
    __shared__ ushort_t act[18 * 18 * 40];
    __shared__ ushort_t wbuf[9 * 32 * 40];
    __shared__ float2 st[256];

    const int tid = threadIdx.x;
    const int tile = blockIdx.x;
    const int b = blockIdx.y;
    const int cog = blockIdx.z;
    const int ty = (tile / tilesX) * 16;
    const int tx = (tile % tilesX) * 16;
    const int wv = tid >> 6;
    const int ln = tid & 63;
    const int lm = ln & 15;
    const int q8 = (ln >> 4) * 8;

    if (BN) for (int c = tid; c < CI; c += 256) st[c] = stats[c];

    v4f acc[4][2];
#pragma unroll
    for (int i = 0; i < 4; ++i)
#pragma unroll
        for (int j = 0; j < 2; ++j) acc[i][j] = (v4f)(0.f);

    const int nChunks = CI >> 5;
    for (int ch = 0; ch < nChunks; ++ch) {
        const int ci0 = ch << 5;
        __syncthreads();
        for (int p = tid; p < 1296; p += 256) {
            const int yy = p / 72;
            const int rem = p - yy * 72;
            const int xx = rem >> 2;
            const int cs = (rem & 3) << 3;
            const int gy = ty + yy - 1, gx = tx + xx - 1;
            uint4 val = make_uint4(0u, 0u, 0u, 0u);
            if (gy >= 0 && gy < H && gx >= 0 && gx < W) {
                const ushort_t* gp = in + (((size_t)(b * H + gy)) * W + gx) * CI + ci0 + cs;
                val = *(const uint4*)gp;
                if (BN) {
                    unsigned u[4] = {val.x, val.y, val.z, val.w};
                    unsigned o[4];
#pragma unroll
                    for (int e = 0; e < 4; ++e) {
                        float lo = bfbits2f(u[e] & 0xffffu);
                        float hi = bfbits2f(u[e] >> 16);
                        const float2 s0 = st[ci0 + cs + 2 * e];
                        const float2 s1 = st[ci0 + cs + 2 * e + 1];
                        lo = fmaxf((lo - s0.x) * s0.y, 0.f);
                        hi = fmaxf((hi - s1.x) * s1.y, 0.f);
                        o[e] = (unsigned)f2bfbits(lo) | ((unsigned)f2bfbits(hi) << 16);
                    }
                    val = make_uint4(o[0], o[1], o[2], o[3]);
                }
            }
            *(uint4*)&act[(yy * 18 + xx) * 40 + cs] = val;
        }
        for (int p = tid; p < 1152; p += 256) {
            const int k = p / 128;
            const int rem = p - k * 128;
            const int co = rem >> 2;
            const int cs = (rem & 3) << 3;
            const ushort_t* gp = wp + ((size_t)k * CO + cog * 32 + co) * CI + ci0 + cs;
            *(uint4*)&wbuf[(k * 32 + co) * 40 + cs] = *(const uint4*)gp;
        }
        __syncthreads();

#pragma unroll
        for (int k = 0; k < 9; ++k) {
            const int dy = k / 3, dx = k - 3 * (k / 3);
            const v8s bf0 = *(const v8s*)&wbuf[(k * 32 + lm) * 40 + q8];
            const v8s bf1 = *(const v8s*)&wbuf[(k * 32 + 16 + lm) * 40 + q8];
#pragma unroll
            for (int mt = 0; mt < 4; ++mt) {
                const int r = wv * 4 + mt;
                const v8s af = *(const v8s*)&act[((r + dy) * 18 + lm + dx) * 40 + q8];
                acc[mt][0] = __builtin_amdgcn_mfma_f32_16x16x32_bf16(af, bf0, acc[mt][0], 0, 0, 0);
                acc[mt][1] = __builtin_amdgcn_mfma_f32_16x16x32_bf16(af, bf1, acc[mt][1], 0, 0, 0);
            }
        }
    }

#pragma unroll
    for (int mt = 0; mt < 4; ++mt) {
        const int y = ty + wv * 4 + mt;
#pragma unroll
        for (int nt = 0; nt < 2; ++nt) {
            const int co = cog * 32 + nt * 16 + lm;
#pragma unroll
            for (int i = 0; i < 4; ++i) {
                const int x = tx + ((ln >> 4) << 2) + i;
                out[(((size_t)(b * H + y)) * W + x) * CO + co] = f2bfbits(acc[mt][nt][i]);
            }
        }
    }
}

// =====================================================================
// Stats: two-stage deterministic over NHWC tensor (fp32 or bf16 source)
// =====================================================================
template <bool F32IN>
__global__ __launch_bounds__(256) void stats_stage1(
    const void* __restrict__ x, float* __restrict__ partial, int C, int PXblk)
{
    __shared__ float ls[256], lq[256];
    const int tid = threadIdx.x, blk = blockIdx.x;
    const int SUB = 256 / C;
    const int ci = (SUB == 1) ? tid : (tid & (C - 1));
    const int sub = (SUB == 1) ? 0 : (tid / C);
    float s = 0.f, s2 = 0.f;
    for (int j = sub; j < PXblk; j += SUB) {
        const size_t e = ((size_t)blk * PXblk + j) * C + ci;
        const float v = F32IN ? ((const float*)x)[e] : bfbits2f(((const ushort_t*)x)[e]);
        s += v; s2 += v * v;
    }
    if (SUB > 1) {
        ls[tid] = s; lq[tid] = s2;
        __syncthreads();
        if (tid < C) {
            for (int k2 = 1; k2 < SUB; ++k2) { s += ls[tid + k2 * C]; s2 += lq[tid + k2 * C]; }
        }
    }
    if (tid < C) {
        partial[((size_t)blk * C + tid) * 2]     = s;
        partial[((size_t)blk * C + tid) * 2 + 1] = s2;
    }
}

__global__ void stats_stage2(const float* __restrict__ partial, float2* __restrict__ st,
                             int C, float inv_n)
{
    const int ci = threadIdx.x;
    if (ci >= C) return;
    float s = 0.f, s2 = 0.f;
    for (int b = 0; b < 64; ++b) {
        s  += partial[((size_t)b * C + ci) * 2];
        s2 += partial[((size_t)b * C + ci) * 2 + 1];
    }
    const float mean = s * inv_n;
    const float var = s2 * inv_n - mean * mean;
    st[ci] = make_float2(mean, 1.0f / sqrtf(var + 1e-5f));
}

// =====================================================================
// Kernel 5: coarse head (fp32 NHWC): 1x1 conv 256->3 + bias + cm0;
// writes cmatch in place over cm0, and output 0.
// =====================================================================
__global__ __launch_bounds__(256) void coarse_head_kernel(
    const float* __restrict__ A, const float2* __restrict__ stats,
    const void* __restrict__ w5, const void* __restrict__ b5,
    float* __restrict__ cm0, void* __restrict__ out,
    const int* __restrict__ dflag)
{
    const int f32 = *dflag;
    __shared__ float wl[3][256];
    __shared__ float bl[3];
    __shared__ float2 st[256];
    const int tid = threadIdx.x;
    for (int i = tid; i < 768; i += 256) wl[i >> 8][i & 255] = ldin(w5, i, f32);
    if (tid < 3) bl[tid] = ldin(b5, tid, f32);
    st[tid] = stats[tid];
    __syncthreads();

    const int idx = blockIdx.x * 256 + tid;
    const int b = idx >> 12, hw = idx & (JC - 1);
    float a0 = bl[0], a1 = bl[1], a2 = bl[2];
    const float* p = A + (size_t)idx * 256;
    for (int c = 0; c < 256; c += 4) {
        const float4 raw = *(const float4*)(p + c);
        const float rv[4] = {raw.x, raw.y, raw.z, raw.w};
#pragma unroll
        for (int e = 0; e < 4; ++e) {
            const int cc = c + e;
            const float v = fmaxf((rv[e] - st[cc].x) * st[cc].y, 0.f);
            a0 += v * wl[0][cc]; a1 += v * wl[1][cc]; a2 += v * wl[2][cc];
        }
    }
    const size_t base = (size_t)b * 3 * JC + hw;
    const float c0 = cm0[base] + a0;
    const float c1 = cm0[base + JC] + a1;
    const float c2 = cm0[base + 2 * JC] + a2;
    cm0[base] = c0; cm0[base + JC] = c1; cm0[base + 2 * JC] = c2;
    stout(out, base, c0, f32);
    stout(out, base + JC, c1, f32);
    stout(out, base + 2 * JC, c2, f32);
}

// =====================================================================
// Kernel 6: bilinear 2x upsample (half-pixel, edge clamp)
// =====================================================================
__global__ __launch_bounds__(256) void upsample_kernel(
    const float* __restrict__ cm, float* __restrict__ up)
{
    const int idx = blockIdx.x * 256 + threadIdx.x;
    const int ox = idx & 127, oy = (idx >> 7) & 127, bc = idx >> 14;
    const float sx = ox * 0.5f - 0.25f;
    const float sy = oy * 0.5f - 0.25f;
    const int x0 = (int)floorf(sx), y0 = (int)floorf(sy);
    const float fx = sx - x0, fy = sy - y0;
    const int cx0 = max(x0, 0), cx1 = min(x0 + 1, WC - 1);
    const int cy0 = max(y0, 0), cy1 = min(y0 + 1, HC - 1);
    const float* p = cm + (size_t)bc * JC;
    const float v = (1.f - fy) * ((1.f - fx) * p[cy0 * WC + cx0] + fx * p[cy0 * WC + cx1])
                  + fy * ((1.f - fx) * p[cy1 * WC + cx0] + fx * p[cy1 * WC + cx1]);
    up[idx] = v;
}

// =====================================================================
// Kernel 7: fine concat -> NHWC bf16 [b][y][x][64] (50 real + 14 zero)
// =====================================================================
__global__ __launch_bounds__(256) void fine_concat_nhwc(
    const void* __restrict__ f0f, const void* __restrict__ f1f,
    const float* __restrict__ up, ushort_t* __restrict__ A,
    const int* __restrict__ dflag)
{
    const int f32 = *dflag;
    const int idx = blockIdx.x * 256 + threadIdx.x;   // B*JF
    const int b = idx >> 14, hw = idx & (JF - 1);
    const size_t ib = (size_t)b * CF * JF;
    ushort_t* o = A + (size_t)idx * 64;

    for (int c = 0; c < CF; ++c)
        o[c] = f2bfbits(ldin(f0f, ib + (size_t)c * JF + hw, f32));

    const size_t ub = (size_t)b * 3 * JF + hw;
    const float gx = up[ub], gy = up[ub + JF];
    const float x = (gx + 1.f) * 64.f - 0.5f;
    const float y = (gy + 1.f) * 64.f - 0.5f;
    const float x0f = floorf(x), y0f = floorf(y);
    const float wx = x - x0f, wy = y - y0f;
    const int x0 = (int)x0f, y0 = (int)y0f;
    const int x1 = x0 + 1, y1 = y0 + 1;
    const float vx0 = (x0 >= 0 && x0 < WF) ? 1.f : 0.f;
    const float vx1 = (x1 >= 0 && x1 < WF) ? 1.f : 0.f;
    const float vy0 = (y0 >= 0 && y0 < HF) ? 1.f : 0.f;
    const float vy1 = (y1 >= 0 && y1 < HF) ? 1.f : 0.f;
    const int cx0 = min(max(x0, 0), WF - 1), cx1 = min(max(x1, 0), WF - 1);
    const int cy0 = min(max(y0, 0), HF - 1), cy1 = min(max(y1, 0), HF - 1);
    const float w00 = (1.f - wx) * (1.f - wy) * vx0 * vy0;
    const float w01 = wx * (1.f - wy) * vx1 * vy0;
    const float w10 = (1.f - wx) * wy * vx0 * vy1;
    const float w11 = wx * wy * vx1 * vy1;
    const int i00 = cy0 * WF + cx0, i01 = cy0 * WF + cx1;
    const int i10 = cy1 * WF + cx0, i11 = cy1 * WF + cx1;

    for (int c = 0; c < CF; ++c) {
        const size_t pb = ib + (size_t)c * JF;
        const float v = w00 * ldin(f1f, pb + i00, f32) + w01 * ldin(f1f, pb + i01, f32)
                      + w10 * ldin(f1f, pb + i10, f32) + w11 * ldin(f1f, pb + i11, f32);
        o[24 + c] = f2bfbits(v);
    }
    o[48] = f2bfbits(gx);
    o[49] = f2bfbits(gy);
    for (int c = 50; c < 64; ++c) o[c] = 0;
}

// =====================================================================
// Kernel 8: fine head (NHWC bf16): 1x1 conv 64->3 + bias + up -> out1
// =====================================================================
__global__ __launch_bounds__(256) void fine_head_kernel(
    const ushort_t* __restrict__ A, const float2* __restrict__ stats,
    const void* __restrict__ w5, const void* __restrict__ b5,
    const float* __restrict__ up, void* __restrict__ out,
    const int* __restrict__ dflag)
{
    const int f32 = *dflag;
    __shared__ float wl[3][64];
    __shared__ float bl[3];
    __shared__ float2 st[64];
    const int tid = threadIdx.x;
    if (tid < 192) wl[tid >> 6][tid & 63] = ldin(w5, tid, f32);
    if (tid < 3) bl[tid] = ldin(b5, tid, f32);
    if (tid < 64) st[tid] = stats[tid];
    __syncthreads();

    const int idx = blockIdx.x * 256 + tid;
    const int b = idx >> 14, hw = idx & (JF - 1);
    float a0 = bl[0], a1 = bl[1], a2 = bl[2];
    const ushort_t* p = A + (size_t)idx * 64;
    for (int c = 0; c < 64; c += 8) {
        const uint4 raw = *(const uint4*)(p + c);
        const unsigned u[4] = {raw.x, raw.y, raw.z, raw.w};
#pragma unroll
        for (int e = 0; e < 4; ++e) {
            const int c0 = c + 2 * e, c1 = c0 + 1;
            float lo = bfbits2f(u[e] & 0xffffu);
            float hi = bfbits2f(u[e] >> 16);
            lo = fmaxf((lo - st[c0].x) * st[c0].y, 0.f);
            hi = fmaxf((hi - st[c1].x) * st[c1].y, 0.f);
            a0 += lo * wl[0][c0] + hi * wl[0][c1];
            a1 += lo * wl[1][c0] + hi * wl[1][c1];
            a2 += lo * wl[2][c0] + hi * wl[2][c1];
        }
    }
    const size_t base = (size_t)b * 3 * JF + hw;
    stout(out, OUT0_ELEMS + base,          up[base] + a0, f32);
    stout(out, OUT0_ELEMS + base + JF,     up[base + JF] + a1, f32);
    stout(out, OUT0_ELEMS + base + 2 * JF, up[base + 2 * JF] + a2, f32);
}

// =====================================================================
extern "C" void kernel_launch(void* const* d_in, const int* in_sizes, int n_in,
                              void* d_out, int out_size, void* d_ws, size_t ws_size,
                              hipStream_t stream)
{
    const void* f0c = d_in[0];
    const void* f1c = d_in[1];
    const void* f0f = d_in[2];
    const void* f1f = d_in[3];
    const void* cw1 = d_in[4];
    const void* cw2 = d_in[5];
    const void* cw3 = d_in[6];
    const void* cw4 = d_in[7];
    const void* cw5 = d_in[8];
    const void* cb5 = d_in[9];
    const void* fw1 = d_in[10];
    const void* fw2 = d_in[11];
    const void* fw3 = d_in[12];
    const void* fw4 = d_in[13];
    const void* fw5 = d_in[14];
    const void* fb5 = d_in[15];

    // ---- workspace layout (byte offsets; total ~35 MiB) ----
    char* wsb = (char*)d_ws;
    float* bufA    = (float*)wsb;                       // 16 MiB
    float* bufB    = (float*)(wsb + 16777216);          // 16 MiB
    float* cm0     = (float*)(wsb + 33554432);          // 196,608 B
    float* up      = (float*)(wsb + 33751040);          // 786,432 B
    float* partial = (float*)(wsb + 34537472);          // 131,072 B
    float2* st_g   = (float2*)(wsb + 34668544);         // 2,048 B
    int* dflag     = (int*)(wsb + 34670592);            // 4 B (+pad)
    ushort_t* fwp  = (ushort_t*)(wsb + 34670656);       // 294,912 B
    ushort_t* fw1p = fwp;
    ushort_t* fw2p = fwp + 36864;
    ushort_t* fw3p = fwp + 73728;
    ushort_t* fw4p = fwp + 110592;

    // transposed split Q/K planes live inside bufA (dead before concat)
    ushort_t* qhi = (ushort_t*)bufA;          // 1,048,576 ushorts each
    ushort_t* qlo = qhi + 1048576;
    ushort_t* khi = qlo + 1048576;
    ushort_t* klo = khi + 1048576;

    ushort_t* fF1 = (ushort_t*)bufB;   // fine ping
    ushort_t* fF2 = (ushort_t*)bufA;   // fine pong

    // 0. dtype probe
    dtype_probe_kernel<<<1, 256, 0, stream>>>((const ushort_t*)f0c, dflag);

    // fine weight repacks (bf16 [k][co][ci_pad])
    repack_w_kernel<<<(9 * 64 * 64 + 255) / 256, 256, 0, stream>>>(fw1, fw1p, 64, 50, 64, dflag);
    repack_w_kernel<<<(9 * 64 * 64 + 255) / 256, 256, 0, stream>>>(fw2, fw2p, 64, 64, 64, dflag);
    repack_w_kernel<<<(9 * 64 * 64 + 255) / 256, 256, 0, stream>>>(fw3, fw3p, 64, 64, 64, dflag);
    repack_w_kernel<<<(9 * 64 * 64 + 255) / 256, 256, 0, stream>>>(fw4, fw4p, 64, 64, 64, dflag);

    // 1. correlation: split-transpose Q/K then MFMA flash softmax-expectation
    split_transpose_kernel<<<dim3(B_ * 64), 256, 0, stream>>>(f0c, qhi, qlo, dflag);
    split_transpose_kernel<<<dim3(B_ * 64), 256, 0, stream>>>(f1c, khi, klo, dflag);
    corr_mfma_kernel<<<dim3(HC, B_), 256, 0, stream>>>(qhi, qlo, khi, klo, cm0);

    // 2. coarse concat -> bufA (fp32 NHWC 160); overwrites q/k planes (dead)
    coarse_concat_f32<<<dim3(B_ * JC / 256), 256, 0, stream>>>(f0c, f1c, cm0, bufA, dflag);

    // 3. coarse conv stack: split-bf16 MFMA, fp32 activations
    const dim3 cgrid(16, B_, 8);
    const size_t SLDS = 99968;
    conv3x3_split<false><<<cgrid, 256, SLDS, stream>>>(bufA, cw1, nullptr, bufB, 160, 130, 256, HC, WC, 4, dflag);
    stats_stage1<true><<<64, 256, 0, stream>>>(bufB, partial, 256, 256);
    stats_stage2<<<1, 256, 0, stream>>>(partial, st_g, 256, 1.f / 16384.f);
    conv3x3_split<true><<<cgrid, 256, SLDS, stream>>>(bufB, cw2, st_g, bufA, 256, 256, 256, HC, WC, 4, dflag);
    stats_stage1<true><<<64, 256, 0, stream>>>(bufA, partial, 256, 256);
    stats_stage2<<<1, 256, 0, stream>>>(partial, st_g, 256, 1.f / 16384.f);
    conv3x3_split<true><<<cgrid, 256, SLDS, stream>>>(bufA, cw3, st_g, bufB, 256, 256, 256, HC, WC, 4, dflag);
    stats_stage1<true><<<64, 256, 0, stream>>>(bufB, partial, 256, 256);
    stats_stage2<<<1, 256, 0, stream>>>(partial, st_g, 256, 1.f / 16384.f);
    conv3x3_split<true><<<cgrid, 256, SLDS, stream>>>(bufB, cw4, st_g, bufA, 256, 256, 256, HC, WC, 4, dflag);
    stats_stage1<true><<<64, 256, 0, stream>>>(bufA, partial, 256, 256);
    stats_stage2<<<1, 256, 0, stream>>>(partial, st_g, 256, 1.f / 16384.f);

    // 4. coarse head -> out0, cmatch (in place over cm0)
    coarse_head_kernel<<<dim3(B_ * JC / 256), 256, 0, stream>>>(bufA, st_g, cw5, cb5, cm0, d_out, dflag);

    // 5. upsample (cm0 now holds cmatch)
    upsample_kernel<<<dim3(B_ * 3 * JF / 256), 256, 0, stream>>>(cm0, up);

    // 6. fine concat -> fF1 (bufB region; coarse data there is dead)
    fine_concat_nhwc<<<dim3(B_ * JF / 256), 256, 0, stream>>>(f0f, f1f, up, fF1, dflag);

    // 7. fine conv stack (bf16 MFMA)
    const dim3 fgrid(64, B_, 2);
    conv3x3_mfma<false><<<fgrid, 256, 0, stream>>>(fF1, fw1p, nullptr, fF2, 64, 64, HF, WF, 8);
    stats_stage1<false><<<64, 256, 0, stream>>>(fF2, partial, 64, 1024);
    stats_stage2<<<1, 256, 0, stream>>>(partial, st_g, 64, 1.f / 65536.f);
    conv3x3_mfma<true><<<fgrid, 256, 0, stream>>>(fF2, fw2p, st_g, fF1, 64, 64, HF, WF, 8);
    stats_stage1<false><<<64, 256, 0, stream>>>(fF1, partial, 64, 1024);
    stats_stage2<<<1, 256, 0, stream>>>(partial, st_g, 64, 1.f / 65536.f);
    conv3x3_mfma<true><<<fgrid, 256, 0, stream>>>(fF1, fw3p, st_g, fF2, 64, 64, HF, WF, 8);
    stats_stage1<false><<<64, 256, 0, stream>>>(fF2, partial, 64, 1024);
    stats_stage2<<<1, 256, 0, stream>>>(partial, st_g, 64, 1.f / 65536.f);
    conv3x3_mfma<true><<<fgrid, 256, 0, stream>>>(fF2, fw4p, st_g, fF1, 64, 64, HF, WF, 8);
    stats_stage1<false><<<64, 256, 0, stream>>>(fF1, partial, 64, 1024);
    stats_stage2<<<1, 256, 0, stream>>>(partial, st_g, 64, 1.f / 65536.f);

    // 8. fine head -> out1
    fine_head_kernel<<<dim3(B_ * JF / 256), 256, 0, stream>>>(fF1, st_g, fw5, fb5, up, d_out, dflag);
}

// Round 7
// 1321.808 us; speedup vs baseline: 3.7260x; 1.3820x over previous
//
#include <hip/hip_runtime.h>
#include <hip/hip_bf16.h>

using bf16 = __hip_bfloat16;
typedef unsigned short ushort_t;
typedef __attribute__((ext_vector_type(8))) short v8s;
typedef __attribute__((ext_vector_type(4))) float v4f;

__device__ __forceinline__ float bfbits2f(unsigned u) {
    return __uint_as_float(u << 16);
}
__device__ __forceinline__ ushort_t f2bfbits(float f) {
    unsigned x = __float_as_uint(f);
    return (ushort_t)((x + 0x7fffu + ((x >> 16) & 1u)) >> 16);
}
// dtype-adaptive input load / output store (flag: 1 = fp32 buffers, 0 = bf16)
__device__ __forceinline__ float ldin(const void* p, size_t i, int f32) {
    return f32 ? ((const float*)p)[i] : bfbits2f(((const ushort_t*)p)[i]);
}
__device__ __forceinline__ void stout(void* p, size_t i, float v, int f32) {
    if (f32) ((float*)p)[i] = v;
    else     ((ushort_t*)p)[i] = f2bfbits(v);
}

// ---------------- sizes ----------------
#define B_   4
#define CC   64
#define HC   64
#define WC   64
#define JC   4096
#define CF   24
#define HF   128
#define WF   128
#define JF   16384
#define OUT0_ELEMS (B_ * 3 * JC)

// =====================================================================
// Kernel 0: dtype probe. flag=1 -> fp32 inputs (R3: confirmed fp32).
// =====================================================================
__global__ void dtype_probe_kernel(const ushort_t* __restrict__ x,
                                   int* __restrict__ flag)
{
    __shared__ int cnt;
    if (threadIdx.x == 0) cnt = 0;
    __syncthreads();
    int c = 0;
    for (int i = threadIdx.x; i < 8192; i += 256) {
        const unsigned e = (x[i] >> 7) & 0xFF;
        if (e >= 0x89) ++c;
    }
    atomicAdd(&cnt, c);
    __syncthreads();
    if (threadIdx.x == 0) *flag = (cnt > 64) ? 1 : 0;
}

// =====================================================================
// Fine weight repack: w[co][ci][3][3] -> wp[k][co][ci_pad] bf16
// =====================================================================
__global__ void repack_w_kernel(const void* __restrict__ w, ushort_t* __restrict__ wp,
                                int CO, int CIreal, int CIP, const int* __restrict__ dflag)
{
    const int f32 = *dflag;
    const int idx = blockIdx.x * 256 + threadIdx.x;
    const int total = 9 * CO * CIP;
    if (idx >= total) return;
    const int k = idx / (CO * CIP);
    const int rem = idx - k * (CO * CIP);
    const int co = rem / CIP;
    const int cip = rem - co * CIP;
    float v = 0.f;
    if (cip < CIreal) v = ldin(w, ((size_t)co * CIreal + cip) * 9 + k, f32);
    wp[((size_t)k * CO + co) * CIP + cip] = f2bfbits(v);
}

// =====================================================================
// Coarse weight repack into MFMA FRAGMENT order, split hi/lo:
// wfrag index = ((((cog*9+k)*2+nt)*2+pl)*nch + ch)*64 + ln, 8 ushorts each.
// Lane ln (lm=ln&15, quad=ln>>4) holds w[co=cog*32+nt*16+lm][ci=ch*32+quad*8+e]
// =====================================================================
__global__ void repack_wfrag_kernel(const void* __restrict__ w, ushort_t* __restrict__ wfrag,
                                    int CIreal, int nch, const int* __restrict__ dflag)
{
    const int f32 = *dflag;
    const int idx = blockIdx.x * 256 + threadIdx.x;
    const int total = 8 * 9 * 2 * 2 * nch * 64;
    if (idx >= total) return;
    const int ln = idx & 63;
    int t = idx >> 6;
    const int ch = t % nch; t /= nch;
    const int pl = t & 1; t >>= 1;
    const int nt = t & 1; t >>= 1;
    const int k = t % 9;
    const int cog = t / 9;
    const int co = cog * 32 + nt * 16 + (ln & 15);
    const int cib = ch * 32 + (ln >> 4) * 8;
    ushort_t vals[8];
#pragma unroll
    for (int e = 0; e < 8; ++e) {
        const int ci = cib + e;
        float v = 0.f;
        if (ci < CIreal) v = ldin(w, ((size_t)co * CIreal + ci) * 9 + k, f32);
        const ushort_t h = f2bfbits(v);
        vals[e] = pl ? f2bfbits(v - bfbits2f(h)) : h;
    }
    uint4 o;
    o.x = (unsigned)vals[0] | ((unsigned)vals[1] << 16);
    o.y = (unsigned)vals[2] | ((unsigned)vals[3] << 16);
    o.z = (unsigned)vals[4] | ((unsigned)vals[5] << 16);
    o.w = (unsigned)vals[6] | ((unsigned)vals[7] << 16);
    *(uint4*)&wfrag[(size_t)idx * 8] = o;
}

// =====================================================================
// Kernel 1a: split-transpose feats: [b][64ch][4096px] -> [b][4096px][64ch]
// =====================================================================
__global__ __launch_bounds__(256) void split_transpose_kernel(
    const void* __restrict__ src, ushort_t* __restrict__ hi,
    ushort_t* __restrict__ lo, const int* __restrict__ dflag)
{
    const int f32 = *dflag;
    __shared__ float t[64][65];
    const int blk = blockIdx.x;
    const int b = blk >> 6;
    const int px0 = (blk & 63) * 64;
    const int tid = threadIdx.x;
    const int px = tid & 63;
    for (int i = 0; i < 16; ++i) {
        const int c = (tid >> 6) + 4 * i;
        t[px][c] = ldin(src, ((size_t)b * 64 + c) * 4096 + px0 + px, f32);
    }
    __syncthreads();
    for (int it = 0; it < 2; ++it) {
        const int p = tid + it * 256;
        const int opx = p >> 3, chk = (p & 7) * 8;
        unsigned hh[4], ll[4];
#pragma unroll
        for (int e = 0; e < 4; ++e) {
            const float v0 = t[opx][chk + 2 * e];
            const float v1 = t[opx][chk + 2 * e + 1];
            const ushort_t h0 = f2bfbits(v0);
            const ushort_t h1 = f2bfbits(v1);
            hh[e] = (unsigned)h0 | ((unsigned)h1 << 16);
            ll[e] = (unsigned)f2bfbits(v0 - bfbits2f(h0))
                  | ((unsigned)f2bfbits(v1 - bfbits2f(h1)) << 16);
        }
        const size_t obase = ((size_t)b * 4096 + px0 + opx) * 64 + chk;
        *(uint4*)&hi[obase] = make_uint4(hh[0], hh[1], hh[2], hh[3]);
        *(uint4*)&lo[obase] = make_uint4(ll[0], ll[1], ll[2], ll[3]);
    }
}

// =====================================================================
// Kernel 1b: correlation + softmax + expectation via split-bf16 MFMA.
// =====================================================================
#define KCH 128
__global__ __launch_bounds__(256) void corr_mfma_kernel(
    const ushort_t* __restrict__ qhi, const ushort_t* __restrict__ qlo,
    const ushort_t* __restrict__ khi, const ushort_t* __restrict__ klo,
    float* __restrict__ cm0)
{
    __shared__ ushort_t kbh[KCH * 72];
    __shared__ ushort_t kbl[KCH * 72];
    __shared__ float red[4][64][3];
    const int h = blockIdx.x, b = blockIdx.y;
    const int tid = threadIdx.x;
    const int wv = tid >> 6, ln = tid & 63;
    const int lm = ln & 15, quad = ln >> 4, q8 = quad * 8;

    v8s qf[4][2][2];
#pragma unroll
    for (int mt = 0; mt < 4; ++mt)
#pragma unroll
        for (int kc = 0; kc < 2; ++kc) {
            const size_t qoff = ((size_t)b * 4096 + h * 64 + mt * 16 + lm) * 64 + kc * 32 + q8;
            qf[mt][kc][0] = *(const v8s*)&qhi[qoff];
            qf[mt][kc][1] = *(const v8s*)&qlo[qoff];
        }

    float P[4][4][3];
#pragma unroll
    for (int mt = 0; mt < 4; ++mt)
#pragma unroll
        for (int i = 0; i < 4; ++i)
            P[mt][i][0] = P[mt][i][1] = P[mt][i][2] = 0.f;

    const size_t kbase = (size_t)b * 4096 * 64;
    for (int c = 0; c < 4096 / KCH; ++c) {
        const int j0 = c * KCH;
        __syncthreads();
        for (int p = tid; p < 2048; p += 256) {
            const int pl = p >> 10;
            const int r = p & 1023;
            const int key = r >> 3, chk = (r & 7) * 8;
            const ushort_t* gsrc = pl ? klo : khi;
            const uint4 v = *(const uint4*)&gsrc[kbase + (size_t)(j0 + key) * 64 + chk];
            ushort_t* dst = pl ? kbl : kbh;
            *(uint4*)&dst[key * 72 + chk] = v;
        }
        __syncthreads();

#pragma unroll
        for (int nt = 0; nt < 2; ++nt) {
            const int kb = wv * 32 + nt * 16;
            const int j = j0 + kb + lm;
            const float gx = (float)((j & 63) * 2 + 1) * (1.f / 64.f) - 1.f;
            const float gy = (float)((j >> 6) * 2 + 1) * (1.f / 64.f) - 1.f;
            const v8s bh0 = *(const v8s*)&kbh[(kb + lm) * 72 + q8];
            const v8s bh1 = *(const v8s*)&kbh[(kb + lm) * 72 + 32 + q8];
            const v8s bl0 = *(const v8s*)&kbl[(kb + lm) * 72 + q8];
            const v8s bl1 = *(const v8s*)&kbl[(kb + lm) * 72 + 32 + q8];
#pragma unroll
            for (int mt = 0; mt < 4; ++mt) {
                v4f acc = (v4f)(0.f);
                acc = __builtin_amdgcn_mfma_f32_16x16x32_bf16(qf[mt][0][0], bl0, acc, 0, 0, 0);
                acc = __builtin_amdgcn_mfma_f32_16x16x32_bf16(qf[mt][0][1], bh0, acc, 0, 0, 0);
                acc = __builtin_amdgcn_mfma_f32_16x16x32_bf16(qf[mt][0][0], bh0, acc, 0, 0, 0);
                acc = __builtin_amdgcn_mfma_f32_16x16x32_bf16(qf[mt][1][0], bl1, acc, 0, 0, 0);
                acc = __builtin_amdgcn_mfma_f32_16x16x32_bf16(qf[mt][1][1], bh1, acc, 0, 0, 0);
                acc = __builtin_amdgcn_mfma_f32_16x16x32_bf16(qf[mt][1][0], bh1, acc, 0, 0, 0);
#pragma unroll
                for (int i = 0; i < 4; ++i) {
                    const float p_ = __expf(acc[i] * 0.125f);
                    P[mt][i][0] += p_;
                    P[mt][i][1] += p_ * gx;
                    P[mt][i][2] += p_ * gy;
                }
            }
        }
    }

#pragma unroll
    for (int mt = 0; mt < 4; ++mt)
#pragma unroll
        for (int i = 0; i < 4; ++i)
#pragma unroll
            for (int d = 0; d < 3; ++d) {
                float v = P[mt][i][d];
                v += __shfl_xor(v, 1);
                v += __shfl_xor(v, 2);
                v += __shfl_xor(v, 4);
                v += __shfl_xor(v, 8);
                P[mt][i][d] = v;
            }
    if (lm == 0) {
#pragma unroll
        for (int mt = 0; mt < 4; ++mt)
#pragma unroll
            for (int i = 0; i < 4; ++i) {
                const int q = mt * 16 + quad * 4 + i;
                red[wv][q][0] = P[mt][i][0];
                red[wv][q][1] = P[mt][i][1];
                red[wv][q][2] = P[mt][i][2];
            }
    }
    __syncthreads();
    if (tid < 64) {
        const int q = tid;
        float l = 0.f, ax = 0.f, ay = 0.f;
        for (int w = 0; w < 4; ++w) {
            l += red[w][q][0]; ax += red[w][q][1]; ay += red[w][q][2];
        }
        const float inv = 1.f / l;
        const size_t base = (size_t)b * 3 * JC + h * 64 + q;
        cm0[base]          = ax * inv;
        cm0[base + JC]     = ay * inv;
        cm0[base + 2 * JC] = 0.f;
    }
}

// =====================================================================
// Kernel 2: coarse concat -> SPLIT hi/lo bf16 NHWC planes [b][px][160]
// =====================================================================
__global__ __launch_bounds__(256) void coarse_concat_split(
    const void* __restrict__ f0c, const void* __restrict__ f1c,
    const float* __restrict__ cm0, ushort_t* __restrict__ hiP,
    ushort_t* __restrict__ loP, const int* __restrict__ dflag)
{
    const int f32 = *dflag;
    const int idx = blockIdx.x * 256 + threadIdx.x;   // B*JC
    const int b = idx >> 12, hw = idx & (JC - 1);
    const size_t ib = (size_t)b * CC * JC;
    ushort_t* oh = hiP + (size_t)idx * 160;
    ushort_t* ol = loP + (size_t)idx * 160;

#pragma unroll 4
    for (int c = 0; c < CC; ++c) {
        const float v = ldin(f0c, ib + (size_t)c * JC + hw, f32);
        const ushort_t h = f2bfbits(v);
        oh[c] = h; ol[c] = f2bfbits(v - bfbits2f(h));
    }

    const float gx = cm0[((size_t)b * 3 + 0) * JC + hw];
    const float gy = cm0[((size_t)b * 3 + 1) * JC + hw];
    const float x = (gx + 1.f) * 32.f - 0.5f;
    const float y = (gy + 1.f) * 32.f - 0.5f;
    const float x0f = floorf(x), y0f = floorf(y);
    const float wx = x - x0f, wy = y - y0f;
    const int x0 = (int)x0f, y0 = (int)y0f;
    const int x1 = x0 + 1, y1 = y0 + 1;
    const float vx0 = (x0 >= 0 && x0 < WC) ? 1.f : 0.f;
    const float vx1 = (x1 >= 0 && x1 < WC) ? 1.f : 0.f;
    const float vy0 = (y0 >= 0 && y0 < HC) ? 1.f : 0.f;
    const float vy1 = (y1 >= 0 && y1 < HC) ? 1.f : 0.f;
    const int cx0 = min(max(x0, 0), WC - 1), cx1 = min(max(x1, 0), WC - 1);
    const int cy0 = min(max(y0, 0), HC - 1), cy1 = min(max(y1, 0), HC - 1);
    const float w00 = (1.f - wx) * (1.f - wy) * vx0 * vy0;
    const float w01 = wx * (1.f - wy) * vx1 * vy0;
    const float w10 = (1.f - wx) * wy * vx0 * vy1;
    const float w11 = wx * wy * vx1 * vy1;
    const int i00 = cy0 * WC + cx0, i01 = cy0 * WC + cx1;
    const int i10 = cy1 * WC + cx0, i11 = cy1 * WC + cx1;

#pragma unroll 4
    for (int c = 0; c < CC; ++c) {
        const size_t pb = ib + (size_t)c * JC;
        const float v = w00 * ldin(f1c, pb + i00, f32) + w01 * ldin(f1c, pb + i01, f32)
                      + w10 * ldin(f1c, pb + i10, f32) + w11 * ldin(f1c, pb + i11, f32);
        const ushort_t h = f2bfbits(v);
        oh[64 + c] = h; ol[64 + c] = f2bfbits(v - bfbits2f(h));
    }
    {
        const ushort_t h = f2bfbits(gx);
        oh[128] = h; ol[128] = f2bfbits(gx - bfbits2f(h));
    }
    {
        const ushort_t h = f2bfbits(gy);
        oh[129] = h; ol[129] = f2bfbits(gy - bfbits2f(h));
    }
    for (int c = 130; c < 160; ++c) { oh[c] = 0; ol[c] = 0; }
}

// =====================================================================
// BN+ReLU+split elementwise: fp32 NHWC 256 -> hi/lo bf16 planes (once
// per layer instead of 8x redundantly inside the conv staging)
// =====================================================================
__global__ __launch_bounds__(256) void bnrelu_split_kernel(
    const float* __restrict__ x, const float2* __restrict__ st,
    ushort_t* __restrict__ hiP, ushort_t* __restrict__ loP)
{
    const int idx = blockIdx.x * 256 + threadIdx.x;   // B*JC*32
    const int px = idx >> 5;
    const int c8 = (idx & 31) << 3;
    const float4 v0 = *(const float4*)&x[(size_t)px * 256 + c8];
    const float4 v1 = *(const float4*)&x[(size_t)px * 256 + c8 + 4];
    const float vv[8] = {v0.x, v0.y, v0.z, v0.w, v1.x, v1.y, v1.z, v1.w};
    ushort_t hh[8], ll[8];
#pragma unroll
    for (int e = 0; e < 8; ++e) {
        const float2 s = st[c8 + e];
        const float f = fmaxf((vv[e] - s.x) * s.y, 0.f);
        const ushort_t h = f2bfbits(f);
        hh[e] = h; ll[e] = f2bfbits(f - bfbits2f(h));
    }
    uint4 oh, ol;
    oh.x = (unsigned)hh[0] | ((unsigned)hh[1] << 16);
    oh.y = (unsigned)hh[2] | ((unsigned)hh[3] << 16);
    oh.z = (unsigned)hh[4] | ((unsigned)hh[5] << 16);
    oh.w = (unsigned)hh[6] | ((unsigned)hh[7] << 16);
    ol.x = (unsigned)ll[0] | ((unsigned)ll[1] << 16);
    ol.y = (unsigned)ll[2] | ((unsigned)ll[3] << 16);
    ol.z = (unsigned)ll[4] | ((unsigned)ll[5] << 16);
    ol.w = (unsigned)ll[6] | ((unsigned)ll[7] << 16);
    *(uint4*)&hiP[(size_t)px * 256 + c8] = oh;
    *(uint4*)&loP[(size_t)px * 256 + c8] = ol;
}

// =====================================================================
// Kernel 3a v2: COARSE 3x3 conv, split-bf16 MFMA.
// Inputs: pre-split hi/lo act planes; weights as pre-split FRAGMENTS in
// global (coalesced 1KB/wave loads, L2-hot, no weight LDS).
// LDS: act only, pad 36 (stride 18 banks = conflict-free) = 46.7 KB
// -> 3 blocks/CU.
// =====================================================================
__global__ __launch_bounds__(256, 3) void conv3x3_wsplit(
    const ushort_t* __restrict__ hiP, const ushort_t* __restrict__ loP,
    const ushort_t* __restrict__ wfrag,
    float* __restrict__ out,
    int CIP, int CO, int H, int W, int tilesX)
{
    __shared__ ushort_t actH[18 * 18 * 36];   // 23328 B
    __shared__ ushort_t actL[18 * 18 * 36];   // 23328 B

    const int nch = CIP >> 5;
    const int tid = threadIdx.x;
    const int tile = blockIdx.x;
    const int b = blockIdx.y;
    const int cog = blockIdx.z;
    const int ty = (tile / tilesX) * 16;
    const int tx = (tile % tilesX) * 16;
    const int wv = tid >> 6;
    const int ln = tid & 63;
    const int lm = ln & 15;
    const int q8 = (ln >> 4) * 8;

    v4f acc[4][2];
#pragma unroll
    for (int i = 0; i < 4; ++i)
#pragma unroll
        for (int j = 0; j < 2; ++j) acc[i][j] = (v4f)(0.f);

    for (int ch = 0; ch < nch; ++ch) {
        const int ci0 = ch << 5;
        __syncthreads();
        // ---- stage act: 2 planes x 18x18 px x 32 ci as uint4 copies ----
        for (int p = tid; p < 2592; p += 256) {
            const int pl = (p >= 1296) ? 1 : 0;
            const int r = p - pl * 1296;
            const int yy = r / 72;
            const int rem = r - yy * 72;
            const int xx = rem >> 2;
            const int cs = (rem & 3) << 3;
            const int gy = ty + yy - 1, gx = tx + xx - 1;
            uint4 val = make_uint4(0u, 0u, 0u, 0u);
            if (gy >= 0 && gy < H && gx >= 0 && gx < W) {
                const ushort_t* src = pl ? loP : hiP;
                val = *(const uint4*)&src[(((size_t)(b * H + gy)) * W + gx) * CIP + ci0 + cs];
            }
            ushort_t* dst = pl ? actL : actH;
            *(uint4*)&dst[(yy * 18 + xx) * 36 + cs] = val;
        }
        __syncthreads();

#pragma unroll
        for (int k = 0; k < 9; ++k) {
            const int dy = k / 3, dx = k - 3 * (k / 3);
            // fragment weights straight from global (coalesced, L2-hot)
            const size_t fb = (((size_t)(cog * 9 + k) * 4) * nch + ch) * 64 + ln;
            const size_t step = (size_t)nch * 64;
            const v8s bh0 = *(const v8s*)&wfrag[fb * 8];
            const v8s bl0 = *(const v8s*)&wfrag[(fb + step) * 8];
            const v8s bh1 = *(const v8s*)&wfrag[(fb + 2 * step) * 8];
            const v8s bl1 = *(const v8s*)&wfrag[(fb + 3 * step) * 8];
#pragma unroll
            for (int mt = 0; mt < 4; ++mt) {
                const int r = wv * 4 + mt;
                const int aoff = ((r + dy) * 18 + lm + dx) * 36 + q8;
                const v8s ah = *(const v8s*)&actH[aoff];
                const v8s al = *(const v8s*)&actL[aoff];
                acc[mt][0] = __builtin_amdgcn_mfma_f32_16x16x32_bf16(ah, bl0, acc[mt][0], 0, 0, 0);
                acc[mt][0] = __builtin_amdgcn_mfma_f32_16x16x32_bf16(al, bh0, acc[mt][0], 0, 0, 0);
                acc[mt][0] = __builtin_amdgcn_mfma_f32_16x16x32_bf16(ah, bh0, acc[mt][0], 0, 0, 0);
                acc[mt][1] = __builtin_amdgcn_mfma_f32_16x16x32_bf16(ah, bl1, acc[mt][1], 0, 0, 0);
                acc[mt][1] = __builtin_amdgcn_mfma_f32_16x16x32_bf16(al, bh1, acc[mt][1], 0, 0, 0);
                acc[mt][1] = __builtin_amdgcn_mfma_f32_16x16x32_bf16(ah, bh1, acc[mt][1], 0, 0, 0);
            }
        }
    }

    // D layout: col(n=co)=ln&15, row(m=x)=(ln>>4)*4+i
#pragma unroll
    for (int mt = 0; mt < 4; ++mt) {
        const int y = ty + wv * 4 + mt;
#pragma unroll
        for (int nt = 0; nt < 2; ++nt) {
            const int co = cog * 32 + nt * 16 + lm;
#pragma unroll
            for (int i = 0; i < 4; ++i) {
                const int x = tx + ((ln >> 4) << 2) + i;
                out[(((size_t)(b * H + y)) * W + x) * CO + co] = acc[mt][nt][i];
            }
        }
    }
}

// =====================================================================
// Kernel 3b: FINE 3x3 conv, single-bf16 MFMA (unchanged, validated)
// =====================================================================
template <bool BN>
__global__ __launch_bounds__(256) void conv3x3_mfma(
    const ushort_t* __restrict__ in,
    const ushort_t* __restrict__ wp,   // [9][CO][CI] bf16
    const float2* __restrict__ stats,
    ushort_t* __restrict__ out,
    int CI, int CO, int H, int W, int tilesX)
{
    __shared__ ushort_t act[18 * 18 * 40];
    __shared__ ushort_t wbuf[9 * 32 * 40];
    __shared__ float2 st[256];

    const int tid = threadIdx.x;
    const int tile = blockIdx.x;
    const int b = blockIdx.y;
    const int cog = blockIdx.z;
    const int ty = (tile / tilesX) * 16;
    const int tx = (tile % tilesX) * 16;
    const int wv = tid >> 6;
    const int ln = tid & 63;
    const int lm = ln & 15;
    const int q8 = (ln >> 4) * 8;

    if (BN) for (int c = tid; c < CI; c += 256) st[c] = stats[c];

    v4f acc[4][2];
#pragma unroll
    for (int i = 0; i < 4; ++i)
#pragma unroll
        for (int j = 0; j < 2; ++j) acc[i][j] = (v4f)(0.f);

    const int nChunks = CI >> 5;
    for (int ch = 0; ch < nChunks; ++ch) {
        const int ci0 = ch << 5;
        __syncthreads();
        for (int p = tid; p < 1296; p += 256) {
            const int yy = p / 72;
            const int rem = p - yy * 72;
            const int xx = rem >> 2;
            const int cs = (rem & 3) << 3;
            const int gy = ty + yy - 1, gx = tx + xx - 1;
            uint4 val = make_uint4(0u, 0u, 0u, 0u);
            if (gy >= 0 && gy < H && gx >= 0 && gx < W) {
                const ushort_t* gp = in + (((size_t)(b * H + gy)) * W + gx) * CI + ci0 + cs;
                val = *(const uint4*)gp;
                if (BN) {
                    unsigned u[4] = {val.x, val.y, val.z, val.w};
                    unsigned o[4];
#pragma unroll
                    for (int e = 0; e < 4; ++e) {
                        float lo = bfbits2f(u[e] & 0xffffu);
                        float hi = bfbits2f(u[e] >> 16);
                        const float2 s0 = st[ci0 + cs + 2 * e];
                        const float2 s1 = st[ci0 + cs + 2 * e + 1];
                        lo = fmaxf((lo - s0.x) * s0.y, 0.f);
                        hi = fmaxf((hi - s1.x) * s1.y, 0.f);
                        o[e] = (unsigned)f2bfbits(lo) | ((unsigned)f2bfbits(hi) << 16);
                    }
                    val = make_uint4(o[0], o[1], o[2], o[3]);
                }
            }
            *(uint4*)&act[(yy * 18 + xx) * 40 + cs] = val;
        }
        for (int p = tid; p < 1152; p += 256) {
            const int k = p / 128;
            const int rem = p - k * 128;
            const int co = rem >> 2;
            const int cs = (rem & 3) << 3;
            const ushort_t* gp = wp + ((size_t)k * CO + cog * 32 + co) * CI + ci0 + cs;
            *(uint4*)&wbuf[(k * 32 + co) * 40 + cs] = *(const uint4*)gp;
        }
        __syncthreads();

#pragma unroll
        for (int k = 0; k < 9; ++k) {
            const int dy = k / 3, dx = k - 3 * (k / 3);
            const v8s bf0 = *(const v8s*)&wbuf[(k * 32 + lm) * 40 + q8];
            const v8s bf1 = *(const v8s*)&wbuf[(k * 32 + 16 + lm) * 40 + q8];
#pragma unroll
            for (int mt = 0; mt < 4; ++mt) {
                const int r = wv * 4 + mt;
                const v8s af = *(const v8s*)&act[((r + dy) * 18 + lm + dx) * 40 + q8];
                acc[mt][0] = __builtin_amdgcn_mfma_f32_16x16x32_bf16(af, bf0, acc[mt][0], 0, 0, 0);
                acc[mt][1] = __builtin_amdgcn_mfma_f32_16x16x32_bf16(af, bf1, acc[mt][1], 0, 0, 0);
            }
        }
    }

#pragma unroll
    for (int mt = 0; mt < 4; ++mt) {
        const int y = ty + wv * 4 + mt;
#pragma unroll
        for (int nt = 0; nt < 2; ++nt) {
            const int co = cog * 32 + nt * 16 + lm;
#pragma unroll
            for (int i = 0; i < 4; ++i) {
                const int x = tx + ((ln >> 4) << 2) + i;
                out[(((size_t)(b * H + y)) * W + x) * CO + co] = f2bfbits(acc[mt][nt][i]);
            }
        }
    }
}

// =====================================================================
// Stats: two-stage deterministic over NHWC tensor (fp32 or bf16 source)
// =====================================================================
template <bool F32IN>
__global__ __launch_bounds__(256) void stats_stage1(
    const void* __restrict__ x, float* __restrict__ partial, int C, int PXblk)
{
    __shared__ float ls[256], lq[256];
    const int tid = threadIdx.x, blk = blockIdx.x;
    const int SUB = 256 / C;
    const int ci = (SUB == 1) ? tid : (tid & (C - 1));
    const int sub = (SUB == 1) ? 0 : (tid / C);
    float s = 0.f, s2 = 0.f;
    for (int j = sub; j < PXblk; j += SUB) {
        const size_t e = ((size_t)blk * PXblk + j) * C + ci;
        const float v = F32IN ? ((const float*)x)[e] : bfbits2f(((const ushort_t*)x)[e]);
        s += v; s2 += v * v;
    }
    if (SUB > 1) {
        ls[tid] = s; lq[tid] = s2;
        __syncthreads();
        if (tid < C) {
            for (int k2 = 1; k2 < SUB; ++k2) { s += ls[tid + k2 * C]; s2 += lq[tid + k2 * C]; }
        }
    }
    if (tid < C) {
        partial[((size_t)blk * C + tid) * 2]     = s;
        partial[((size_t)blk * C + tid) * 2 + 1] = s2;
    }
}

__global__ void stats_stage2(const float* __restrict__ partial, float2* __restrict__ st,
                             int C, float inv_n)
{
    const int ci = threadIdx.x;
    if (ci >= C) return;
    float s = 0.f, s2 = 0.f;
    for (int b = 0; b < 64; ++b) {
        s  += partial[((size_t)b * C + ci) * 2];
        s2 += partial[((size_t)b * C + ci) * 2 + 1];
    }
    const float mean = s * inv_n;
    const float var = s2 * inv_n - mean * mean;
    st[ci] = make_float2(mean, 1.0f / sqrtf(var + 1e-5f));
}

// =====================================================================
// Kernel 5: coarse head (fp32 NHWC): 1x1 conv 256->3 + bias + cm0;
// writes cmatch in place over cm0, and output 0.
// =====================================================================
__global__ __launch_bounds__(256) void coarse_head_kernel(
    const float* __restrict__ A, const float2* __restrict__ stats,
    const void* __restrict__ w5, const void* __restrict__ b5,
    float* __restrict__ cm0, void* __restrict__ out,
    const int* __restrict__ dflag)
{
    const int f32 = *dflag;
    __shared__ float wl[3][256];
    __shared__ float bl[3];
    __shared__ float2 st[256];
    const int tid = threadIdx.x;
    for (int i = tid; i < 768; i += 256) wl[i >> 8][i & 255] = ldin(w5, i, f32);
    if (tid < 3) bl[tid] = ldin(b5, tid, f32);
    st[tid] = stats[tid];
    __syncthreads();

    const int idx = blockIdx.x * 256 + tid;
    const int b = idx >> 12, hw = idx & (JC - 1);
    float a0 = bl[0], a1 = bl[1], a2 = bl[2];
    const float* p = A + (size_t)idx * 256;
    for (int c = 0; c < 256; c += 4) {
        const float4 raw = *(const float4*)(p + c);
        const float rv[4] = {raw.x, raw.y, raw.z, raw.w};
#pragma unroll
        for (int e = 0; e < 4; ++e) {
            const int cc = c + e;
            const float v = fmaxf((rv[e] - st[cc].x) * st[cc].y, 0.f);
            a0 += v * wl[0][cc]; a1 += v * wl[1][cc]; a2 += v * wl[2][cc];
        }
    }
    const size_t base = (size_t)b * 3 * JC + hw;
    const float c0 = cm0[base] + a0;
    const float c1 = cm0[base + JC] + a1;
    const float c2 = cm0[base + 2 * JC] + a2;
    cm0[base] = c0; cm0[base + JC] = c1; cm0[base + 2 * JC] = c2;
    stout(out, base, c0, f32);
    stout(out, base + JC, c1, f32);
    stout(out, base + 2 * JC, c2, f32);
}

// =====================================================================
// Kernel 6: bilinear 2x upsample (half-pixel, edge clamp)
// =====================================================================
__global__ __launch_bounds__(256) void upsample_kernel(
    const float* __restrict__ cm, float* __restrict__ up)
{
    const int idx = blockIdx.x * 256 + threadIdx.x;
    const int ox = idx & 127, oy = (idx >> 7) & 127, bc = idx >> 14;
    const float sx = ox * 0.5f - 0.25f;
    const float sy = oy * 0.5f - 0.25f;
    const int x0 = (int)floorf(sx), y0 = (int)floorf(sy);
    const float fx = sx - x0, fy = sy - y0;
    const int cx0 = max(x0, 0), cx1 = min(x0 + 1, WC - 1);
    const int cy0 = max(y0, 0), cy1 = min(y0 + 1, HC - 1);
    const float* p = cm + (size_t)bc * JC;
    const float v = (1.f - fy) * ((1.f - fx) * p[cy0 * WC + cx0] + fx * p[cy0 * WC + cx1])
                  + fy * ((1.f - fx) * p[cy1 * WC + cx0] + fx * p[cy1 * WC + cx1]);
    up[idx] = v;
}

// =====================================================================
// Kernel 7: fine concat -> NHWC bf16 [b][y][x][64] (50 real + 14 zero)
// =====================================================================
__global__ __launch_bounds__(256) void fine_concat_nhwc(
    const void* __restrict__ f0f, const void* __restrict__ f1f,
    const float* __restrict__ up, ushort_t* __restrict__ A,
    const int* __restrict__ dflag)
{
    const int f32 = *dflag;
    const int idx = blockIdx.x * 256 + threadIdx.x;   // B*JF
    const int b = idx >> 14, hw = idx & (JF - 1);
    const size_t ib = (size_t)b * CF * JF;
    ushort_t* o = A + (size_t)idx * 64;

    for (int c = 0; c < CF; ++c)
        o[c] = f2bfbits(ldin(f0f, ib + (size_t)c * JF + hw, f32));

    const size_t ub = (size_t)b * 3 * JF + hw;
    const float gx = up[ub], gy = up[ub + JF];
    const float x = (gx + 1.f) * 64.f - 0.5f;
    const float y = (gy + 1.f) * 64.f - 0.5f;
    const float x0f = floorf(x), y0f = floorf(y);
    const float wx = x - x0f, wy = y - y0f;
    const int x0 = (int)x0f, y0 = (int)y0f;
    const int x1 = x0 + 1, y1 = y0 + 1;
    const float vx0 = (x0 >= 0 && x0 < WF) ? 1.f : 0.f;
    const float vx1 = (x1 >= 0 && x1 < WF) ? 1.f : 0.f;
    const float vy0 = (y0 >= 0 && y0 < HF) ? 1.f : 0.f;
    const float vy1 = (y1 >= 0 && y1 < HF) ? 1.f : 0.f;
    const int cx0 = min(max(x0, 0), WF - 1), cx1 = min(max(x1, 0), WF - 1);
    const int cy0 = min(max(y0, 0), HF - 1), cy1 = min(max(y1, 0), HF - 1);
    const float w00 = (1.f - wx) * (1.f - wy) * vx0 * vy0;
    const float w01 = wx * (1.f - wy) * vx1 * vy0;
    const float w10 = (1.f - wx) * wy * vx0 * vy1;
    const float w11 = wx * wy * vx1 * vy1;
    const int i00 = cy0 * WF + cx0, i01 = cy0 * WF + cx1;
    const int i10 = cy1 * WF + cx0, i11 = cy1 * WF + cx1;

    for (int c = 0; c < CF; ++c) {
        const size_t pb = ib + (size_t)c * JF;
        const float v = w00 * ldin(f1f, pb + i00, f32) + w01 * ldin(f1f, pb + i01, f32)
                      + w10 * ldin(f1f, pb + i10, f32) + w11 * ldin(f1f, pb + i11, f32);
        o[24 + c] = f2bfbits(v);
    }
    o[48] = f2bfbits(gx);
    o[49] = f2bfbits(gy);
    for (int c = 50; c < 64; ++c) o[c] = 0;
}

// =====================================================================
// Kernel 8: fine head (NHWC bf16): 1x1 conv 64->3 + bias + up -> out1
// =====================================================================
__global__ __launch_bounds__(256) void fine_head_kernel(
    const ushort_t* __restrict__ A, const float2* __restrict__ stats,
    const void* __restrict__ w5, const void* __restrict__ b5,
    const float* __restrict__ up, void* __restrict__ out,
    const int* __restrict__ dflag)
{
    const int f32 = *dflag;
    __shared__ float wl[3][64];
    __shared__ float bl[3];
    __shared__ float2 st[64];
    const int tid = threadIdx.x;
    if (tid < 192) wl[tid >> 6][tid & 63] = ldin(w5, tid, f32);
    if (tid < 3) bl[tid] = ldin(b5, tid, f32);
    if (tid < 64) st[tid] = stats[tid];
    __syncthreads();

    const int idx = blockIdx.x * 256 + tid;
    const int b = idx >> 14, hw = idx & (JF - 1);
    float a0 = bl[0], a1 = bl[1], a2 = bl[2];
    const ushort_t* p = A + (size_t)idx * 64;
    for (int c = 0; c < 64; c += 8) {
        const uint4 raw = *(const uint4*)(p + c);
        const unsigned u[4] = {raw.x, raw.y, raw.z, raw.w};
#pragma unroll
        for (int e = 0; e < 4; ++e) {
            const int c0 = c + 2 * e, c1 = c0 + 1;
            float lo = bfbits2f(u[e] & 0xffffu);
            float hi = bfbits2f(u[e] >> 16);
            lo = fmaxf((lo - st[c0].x) * st[c0].y, 0.f);
            hi = fmaxf((hi - st[c1].x) * st[c1].y, 0.f);
            a0 += lo * wl[0][c0] + hi * wl[0][c1];
            a1 += lo * wl[1][c0] + hi * wl[1][c1];
            a2 += lo * wl[2][c0] + hi * wl[2][c1];
        }
    }
    const size_t base = (size_t)b * 3 * JF + hw;
    stout(out, OUT0_ELEMS + base,          up[base] + a0, f32);
    stout(out, OUT0_ELEMS + base + JF,     up[base + JF] + a1, f32);
    stout(out, OUT0_ELEMS + base + 2 * JF, up[base + 2 * JF] + a2, f32);
}

// =====================================================================
extern "C" void kernel_launch(void* const* d_in, const int* in_sizes, int n_in,
                              void* d_out, int out_size, void* d_ws, size_t ws_size,
                              hipStream_t stream)
{
    const void* f0c = d_in[0];
    const void* f1c = d_in[1];
    const void* f0f = d_in[2];
    const void* f1f = d_in[3];
    const void* cw1 = d_in[4];
    const void* cw2 = d_in[5];
    const void* cw3 = d_in[6];
    const void* cw4 = d_in[7];
    const void* cw5 = d_in[8];
    const void* cb5 = d_in[9];
    const void* fw1 = d_in[10];
    const void* fw2 = d_in[11];
    const void* fw3 = d_in[12];
    const void* fw4 = d_in[13];
    const void* fw5 = d_in[14];
    const void* fb5 = d_in[15];

    // ---- workspace layout (byte offsets; total ~37.3 MiB) ----
    char* wsb = (char*)d_ws;
    float* bufA    = (float*)wsb;                       // 16 MiB
    float* bufB    = (float*)(wsb + 16777216);          // 16 MiB
    float* cm0     = (float*)(wsb + 33554432);          // 196,608 B
    float* up      = (float*)(wsb + 33751040);          // 786,432 B
    float* partial = (float*)(wsb + 34537472);          // 131,072 B
    float2* st_g   = (float2*)(wsb + 34668544);         // 2,048 B
    int* dflag     = (int*)(wsb + 34670592);            // 64 B
    ushort_t* fwp  = (ushort_t*)(wsb + 34670656);       // 294,912 B
    ushort_t* fw1p = fwp;
    ushort_t* fw2p = fwp + 36864;
    ushort_t* fw3p = fwp + 73728;
    ushort_t* fw4p = fwp + 110592;
    ushort_t* wfrag = (ushort_t*)(wsb + 34965568);      // 2,359,296 B (reused per layer)

    // split activation planes: hi = bufA[0..8MB), lo = bufA[8..16MB)
    ushort_t* hiP = (ushort_t*)bufA;
    ushort_t* loP = (ushort_t*)(wsb + 8388608);

    // corr split Q/K planes also live in bufA's first 8 MB (dead before concat)
    ushort_t* qhi = (ushort_t*)bufA;          // 2 MB each
    ushort_t* qlo = qhi + 1048576;
    ushort_t* khi = qlo + 1048576;
    ushort_t* klo = khi + 1048576;

    ushort_t* fF1 = (ushort_t*)bufB;   // fine ping
    ushort_t* fF2 = (ushort_t*)bufA;   // fine pong

    // 0. dtype probe
    dtype_probe_kernel<<<1, 256, 0, stream>>>((const ushort_t*)f0c, dflag);

    // fine weight repacks (bf16 [k][co][ci_pad])
    repack_w_kernel<<<(9 * 64 * 64 + 255) / 256, 256, 0, stream>>>(fw1, fw1p, 64, 50, 64, dflag);
    repack_w_kernel<<<(9 * 64 * 64 + 255) / 256, 256, 0, stream>>>(fw2, fw2p, 64, 64, 64, dflag);
    repack_w_kernel<<<(9 * 64 * 64 + 255) / 256, 256, 0, stream>>>(fw3, fw3p, 64, 64, 64, dflag);
    repack_w_kernel<<<(9 * 64 * 64 + 255) / 256, 256, 0, stream>>>(fw4, fw4p, 64, 64, 64, dflag);

    // 1. correlation: split-transpose Q/K then MFMA flash softmax-expectation
    split_transpose_kernel<<<dim3(B_ * 64), 256, 0, stream>>>(f0c, qhi, qlo, dflag);
    split_transpose_kernel<<<dim3(B_ * 64), 256, 0, stream>>>(f1c, khi, klo, dflag);
    corr_mfma_kernel<<<dim3(HC, B_), 256, 0, stream>>>(qhi, qlo, khi, klo, cm0);

    // 2. coarse concat -> split planes (CIP=160); overwrites q/k (dead)
    coarse_concat_split<<<dim3(B_ * JC / 256), 256, 0, stream>>>(f0c, f1c, cm0, hiP, loP, dflag);

    // 3. coarse conv stack: fragment-weight split-bf16 MFMA
    const dim3 cgrid(16, B_, 8);
    // layer 1: CIP=160 (nch=5)
    repack_wfrag_kernel<<<(8 * 9 * 2 * 2 * 5 * 64 + 255) / 256, 256, 0, stream>>>(cw1, wfrag, 130, 5, dflag);
    conv3x3_wsplit<<<cgrid, 256, 0, stream>>>(hiP, loP, wfrag, bufB, 160, 256, HC, WC, 4);
    stats_stage1<true><<<64, 256, 0, stream>>>(bufB, partial, 256, 256);
    stats_stage2<<<1, 256, 0, stream>>>(partial, st_g, 256, 1.f / 16384.f);
    // layers 2-4: CIP=256 (nch=8)
    bnrelu_split_kernel<<<B_ * JC * 32 / 256, 256, 0, stream>>>(bufB, st_g, hiP, loP);
    repack_wfrag_kernel<<<(8 * 9 * 2 * 2 * 8 * 64 + 255) / 256, 256, 0, stream>>>(cw2, wfrag, 256, 8, dflag);
    conv3x3_wsplit<<<cgrid, 256, 0, stream>>>(hiP, loP, wfrag, bufB, 256, 256, HC, WC, 4);
    stats_stage1<true><<<64, 256, 0, stream>>>(bufB, partial, 256, 256);
    stats_stage2<<<1, 256, 0, stream>>>(partial, st_g, 256, 1.f / 16384.f);

    bnrelu_split_kernel<<<B_ * JC * 32 / 256, 256, 0, stream>>>(bufB, st_g, hiP, loP);
    repack_wfrag_kernel<<<(8 * 9 * 2 * 2 * 8 * 64 + 255) / 256, 256, 0, stream>>>(cw3, wfrag, 256, 8, dflag);
    conv3x3_wsplit<<<cgrid, 256, 0, stream>>>(hiP, loP, wfrag, bufB, 256, 256, HC, WC, 4);
    stats_stage1<true><<<64, 256, 0, stream>>>(bufB, partial, 256, 256);
    stats_stage2<<<1, 256, 0, stream>>>(partial, st_g, 256, 1.f / 16384.f);

    bnrelu_split_kernel<<<B_ * JC * 32 / 256, 256, 0, stream>>>(bufB, st_g, hiP, loP);
    repack_wfrag_kernel<<<(8 * 9 * 2 * 2 * 8 * 64 + 255) / 256, 256, 0, stream>>>(cw4, wfrag, 256, 8, dflag);
    conv3x3_wsplit<<<cgrid, 256, 0, stream>>>(hiP, loP, wfrag, bufB, 256, 256, HC, WC, 4);
    stats_stage1<true><<<64, 256, 0, stream>>>(bufB, partial, 256, 256);
    stats_stage2<<<1, 256, 0, stream>>>(partial, st_g, 256, 1.f / 16384.f);

    // 4. coarse head -> out0, cmatch (in place over cm0)
    coarse_head_kernel<<<dim3(B_ * JC / 256), 256, 0, stream>>>(bufB, st_g, cw5, cb5, cm0, d_out, dflag);

    // 5. upsample (cm0 now holds cmatch)
    upsample_kernel<<<dim3(B_ * 3 * JF / 256), 256, 0, stream>>>(cm0, up);

    // 6. fine concat -> fF1 (bufB region; conv4 raw is dead after head)
    fine_concat_nhwc<<<dim3(B_ * JF / 256), 256, 0, stream>>>(f0f, f1f, up, fF1, dflag);

    // 7. fine conv stack (bf16 MFMA)
    const dim3 fgrid(64, B_, 2);
    conv3x3_mfma<false><<<fgrid, 256, 0, stream>>>(fF1, fw1p, nullptr, fF2, 64, 64, HF, WF, 8);
    stats_stage1<false><<<64, 256, 0, stream>>>(fF2, partial, 64, 1024);
    stats_stage2<<<1, 256, 0, stream>>>(partial, st_g, 64, 1.f / 65536.f);
    conv3x3_mfma<true><<<fgrid, 256, 0, stream>>>(fF2, fw2p, st_g, fF1, 64, 64, HF, WF, 8);
    stats_stage1<false><<<64, 256, 0, stream>>>(fF1, partial, 64, 1024);
    stats_stage2<<<1, 256, 0, stream>>>(partial, st_g, 64, 1.f / 65536.f);
    conv3x3_mfma<true><<<fgrid, 256, 0, stream>>>(fF1, fw3p, st_g, fF2, 64, 64, HF, WF, 8);
    stats_stage1<false><<<64, 256, 0, stream>>>(fF2, partial, 64, 1024);
    stats_stage2<<<1, 256, 0, stream>>>(partial, st_g, 64, 1.f / 65536.f);
    conv3x3_mfma<true><<<fgrid, 256, 0, stream>>>(fF2, fw4p, st_g, fF1, 64, 64, HF, WF, 8);
    stats_stage1<false><<<64, 256, 0, stream>>>(fF1, partial, 64, 1024);
    stats_stage2<<<1, 256, 0, stream>>>(partial, st_g, 64, 1.f / 65536.f);

    // 8. fine head -> out1
    fine_head_kernel<<<dim3(B_ * JF / 256), 256, 0, stream>>>(fF1, st_g, fw5, fb5, up, d_out, dflag);
}

// Round 8
// 812.944 us; speedup vs baseline: 6.0584x; 1.6260x over previous
//
#include <hip/hip_runtime.h>
#include <hip/hip_bf16.h>

using bf16 = __hip_bfloat16;
typedef unsigned short ushort_t;
typedef __attribute__((ext_vector_type(8))) short v8s;
typedef __attribute__((ext_vector_type(4))) float v4f;

__device__ __forceinline__ float bfbits2f(unsigned u) {
    return __uint_as_float(u << 16);
}
__device__ __forceinline__ ushort_t f2bfbits(float f) {
    unsigned x = __float_as_uint(f);
    return (ushort_t)((x + 0x7fffu + ((x >> 16) & 1u)) >> 16);
}
// dtype-adaptive input load / output store (flag: 1 = fp32 buffers, 0 = bf16)
__device__ __forceinline__ float ldin(const void* p, size_t i, int f32) {
    return f32 ? ((const float*)p)[i] : bfbits2f(((const ushort_t*)p)[i]);
}
__device__ __forceinline__ void stout(void* p, size_t i, float v, int f32) {
    if (f32) ((float*)p)[i] = v;
    else     ((ushort_t*)p)[i] = f2bfbits(v);
}

// ---------------- sizes ----------------
#define B_   4
#define CC   64
#define HC   64
#define WC   64
#define JC   4096
#define CF   24
#define HF   128
#define WF   128
#define JF   16384
#define OUT0_ELEMS (B_ * 3 * JC)

// =====================================================================
// Kernel 0: dtype probe. flag=1 -> fp32 inputs (R3: confirmed fp32).
// =====================================================================
__global__ void dtype_probe_kernel(const ushort_t* __restrict__ x,
                                   int* __restrict__ flag)
{
    __shared__ int cnt;
    if (threadIdx.x == 0) cnt = 0;
    __syncthreads();
    int c = 0;
    for (int i = threadIdx.x; i < 8192; i += 256) {
        const unsigned e = (x[i] >> 7) & 0xFF;
        if (e >= 0x89) ++c;
    }
    atomicAdd(&cnt, c);
    __syncthreads();
    if (threadIdx.x == 0) *flag = (cnt > 64) ? 1 : 0;
}

// =====================================================================
// Fine weight repack: w[co][ci][3][3] -> wp[k][co][ci_pad] bf16
// =====================================================================
__global__ void repack_w_kernel(const void* __restrict__ w, ushort_t* __restrict__ wp,
                                int CO, int CIreal, int CIP, const int* __restrict__ dflag)
{
    const int f32 = *dflag;
    const int idx = blockIdx.x * 256 + threadIdx.x;
    const int total = 9 * CO * CIP;
    if (idx >= total) return;
    const int k = idx / (CO * CIP);
    const int rem = idx - k * (CO * CIP);
    const int co = rem / CIP;
    const int cip = rem - co * CIP;
    float v = 0.f;
    if (cip < CIreal) v = ldin(w, ((size_t)co * CIreal + cip) * 9 + k, f32);
    wp[((size_t)k * CO + co) * CIP + cip] = f2bfbits(v);
}

// =====================================================================
// Coarse weight repack into MFMA FRAGMENT order, split hi/lo.
// =====================================================================
__global__ void repack_wfrag_kernel(const void* __restrict__ w, ushort_t* __restrict__ wfrag,
                                    int CIreal, int nch, const int* __restrict__ dflag)
{
    const int f32 = *dflag;
    const int idx = blockIdx.x * 256 + threadIdx.x;
    const int total = 8 * 9 * 2 * 2 * nch * 64;
    if (idx >= total) return;
    const int ln = idx & 63;
    int t = idx >> 6;
    const int ch = t % nch; t /= nch;
    const int pl = t & 1; t >>= 1;
    const int nt = t & 1; t >>= 1;
    const int k = t % 9;
    const int cog = t / 9;
    const int co = cog * 32 + nt * 16 + (ln & 15);
    const int cib = ch * 32 + (ln >> 4) * 8;
    ushort_t vals[8];
#pragma unroll
    for (int e = 0; e < 8; ++e) {
        const int ci = cib + e;
        float v = 0.f;
        if (ci < CIreal) v = ldin(w, ((size_t)co * CIreal + ci) * 9 + k, f32);
        const ushort_t h = f2bfbits(v);
        vals[e] = pl ? f2bfbits(v - bfbits2f(h)) : h;
    }
    uint4 o;
    o.x = (unsigned)vals[0] | ((unsigned)vals[1] << 16);
    o.y = (unsigned)vals[2] | ((unsigned)vals[3] << 16);
    o.z = (unsigned)vals[4] | ((unsigned)vals[5] << 16);
    o.w = (unsigned)vals[6] | ((unsigned)vals[7] << 16);
    *(uint4*)&wfrag[(size_t)idx * 8] = o;
}

// =====================================================================
// Kernel 1a: split-transpose feats: [b][64ch][4096px] -> [b][4096px][64ch]
// =====================================================================
__global__ __launch_bounds__(256) void split_transpose_kernel(
    const void* __restrict__ src, ushort_t* __restrict__ hi,
    ushort_t* __restrict__ lo, const int* __restrict__ dflag)
{
    const int f32 = *dflag;
    __shared__ float t[64][65];
    const int blk = blockIdx.x;
    const int b = blk >> 6;
    const int px0 = (blk & 63) * 64;
    const int tid = threadIdx.x;
    const int px = tid & 63;
    for (int i = 0; i < 16; ++i) {
        const int c = (tid >> 6) + 4 * i;
        t[px][c] = ldin(src, ((size_t)b * 64 + c) * 4096 + px0 + px, f32);
    }
    __syncthreads();
    for (int it = 0; it < 2; ++it) {
        const int p = tid + it * 256;
        const int opx = p >> 3, chk = (p & 7) * 8;
        unsigned hh[4], ll[4];
#pragma unroll
        for (int e = 0; e < 4; ++e) {
            const float v0 = t[opx][chk + 2 * e];
            const float v1 = t[opx][chk + 2 * e + 1];
            const ushort_t h0 = f2bfbits(v0);
            const ushort_t h1 = f2bfbits(v1);
            hh[e] = (unsigned)h0 | ((unsigned)h1 << 16);
            ll[e] = (unsigned)f2bfbits(v0 - bfbits2f(h0))
                  | ((unsigned)f2bfbits(v1 - bfbits2f(h1)) << 16);
        }
        const size_t obase = ((size_t)b * 4096 + px0 + opx) * 64 + chk;
        *(uint4*)&hi[obase] = make_uint4(hh[0], hh[1], hh[2], hh[3]);
        *(uint4*)&lo[obase] = make_uint4(ll[0], ll[1], ll[2], ll[3]);
    }
}

// =====================================================================
// Kernel 1b: correlation, SPLIT-K: grid (HC, B, 4). Each block: 64 q x
// 1024 keys (8 chunks of 128). Writes unnormalized partials (l, px, py).
// =====================================================================
#define KCH 128
__global__ __launch_bounds__(256) void corr_mfma_kernel(
    const ushort_t* __restrict__ qhi, const ushort_t* __restrict__ qlo,
    const ushort_t* __restrict__ khi, const ushort_t* __restrict__ klo,
    float* __restrict__ part)
{
    __shared__ ushort_t kbh[KCH * 72];
    __shared__ ushort_t kbl[KCH * 72];
    __shared__ float red[4][64][3];
    const int h = blockIdx.x, b = blockIdx.y, sl = blockIdx.z;
    const int tid = threadIdx.x;
    const int wv = tid >> 6, ln = tid & 63;
    const int lm = ln & 15, quad = ln >> 4, q8 = quad * 8;

    v8s qf[4][2][2];
#pragma unroll
    for (int mt = 0; mt < 4; ++mt)
#pragma unroll
        for (int kc = 0; kc < 2; ++kc) {
            const size_t qoff = ((size_t)b * 4096 + h * 64 + mt * 16 + lm) * 64 + kc * 32 + q8;
            qf[mt][kc][0] = *(const v8s*)&qhi[qoff];
            qf[mt][kc][1] = *(const v8s*)&qlo[qoff];
        }

    float P[4][4][3];
#pragma unroll
    for (int mt = 0; mt < 4; ++mt)
#pragma unroll
        for (int i = 0; i < 4; ++i)
            P[mt][i][0] = P[mt][i][1] = P[mt][i][2] = 0.f;

    const size_t kbase = (size_t)b * 4096 * 64;
    for (int c = 0; c < 1024 / KCH; ++c) {
        const int j0 = sl * 1024 + c * KCH;
        __syncthreads();
        for (int p = tid; p < 2048; p += 256) {
            const int pl = p >> 10;
            const int r = p & 1023;
            const int key = r >> 3, chk = (r & 7) * 8;
            const ushort_t* gsrc = pl ? klo : khi;
            const uint4 v = *(const uint4*)&gsrc[kbase + (size_t)(j0 + key) * 64 + chk];
            ushort_t* dst = pl ? kbl : kbh;
            *(uint4*)&dst[key * 72 + chk] = v;
        }
        __syncthreads();

#pragma unroll
        for (int nt = 0; nt < 2; ++nt) {
            const int kb = wv * 32 + nt * 16;
            const int j = j0 + kb + lm;
            const float gx = (float)((j & 63) * 2 + 1) * (1.f / 64.f) - 1.f;
            const float gy = (float)((j >> 6) * 2 + 1) * (1.f / 64.f) - 1.f;
            const v8s bh0 = *(const v8s*)&kbh[(kb + lm) * 72 + q8];
            const v8s bh1 = *(const v8s*)&kbh[(kb + lm) * 72 + 32 + q8];
            const v8s bl0 = *(const v8s*)&kbl[(kb + lm) * 72 + q8];
            const v8s bl1 = *(const v8s*)&kbl[(kb + lm) * 72 + 32 + q8];
#pragma unroll
            for (int mt = 0; mt < 4; ++mt) {
                v4f acc = (v4f)(0.f);
                acc = __builtin_amdgcn_mfma_f32_16x16x32_bf16(qf[mt][0][0], bl0, acc, 0, 0, 0);
                acc = __builtin_amdgcn_mfma_f32_16x16x32_bf16(qf[mt][0][1], bh0, acc, 0, 0, 0);
                acc = __builtin_amdgcn_mfma_f32_16x16x32_bf16(qf[mt][0][0], bh0, acc, 0, 0, 0);
                acc = __builtin_amdgcn_mfma_f32_16x16x32_bf16(qf[mt][1][0], bl1, acc, 0, 0, 0);
                acc = __builtin_amdgcn_mfma_f32_16x16x32_bf16(qf[mt][1][1], bh1, acc, 0, 0, 0);
                acc = __builtin_amdgcn_mfma_f32_16x16x32_bf16(qf[mt][1][0], bh1, acc, 0, 0, 0);
#pragma unroll
                for (int i = 0; i < 4; ++i) {
                    const float p_ = __expf(acc[i] * 0.125f);
                    P[mt][i][0] += p_;
                    P[mt][i][1] += p_ * gx;
                    P[mt][i][2] += p_ * gy;
                }
            }
        }
    }

#pragma unroll
    for (int mt = 0; mt < 4; ++mt)
#pragma unroll
        for (int i = 0; i < 4; ++i)
#pragma unroll
            for (int d = 0; d < 3; ++d) {
                float v = P[mt][i][d];
                v += __shfl_xor(v, 1);
                v += __shfl_xor(v, 2);
                v += __shfl_xor(v, 4);
                v += __shfl_xor(v, 8);
                P[mt][i][d] = v;
            }
    if (lm == 0) {
#pragma unroll
        for (int mt = 0; mt < 4; ++mt)
#pragma unroll
            for (int i = 0; i < 4; ++i) {
                const int q = mt * 16 + quad * 4 + i;
                red[wv][q][0] = P[mt][i][0];
                red[wv][q][1] = P[mt][i][1];
                red[wv][q][2] = P[mt][i][2];
            }
    }
    __syncthreads();
    if (tid < 64) {
        const int q = tid;
        float l = 0.f, ax = 0.f, ay = 0.f;
        for (int w = 0; w < 4; ++w) {
            l += red[w][q][0]; ax += red[w][q][1]; ay += red[w][q][2];
        }
        const size_t base = (((size_t)sl * B_ + b) * 4096 + h * 64 + q) * 4;
        part[base] = l; part[base + 1] = ax; part[base + 2] = ay;
    }
}

// =====================================================================
// Kernel 1c: merge split-K partials -> cm0 (deterministic)
// =====================================================================
__global__ __launch_bounds__(256) void corr_reduce_kernel(
    const float* __restrict__ part, float* __restrict__ cm0)
{
    const int idx = blockIdx.x * 256 + threadIdx.x;   // B*JC
    const int b = idx >> 12, hq = idx & 4095;
    float l = 0.f, ax = 0.f, ay = 0.f;
    for (int s = 0; s < 4; ++s) {
        const size_t base = (((size_t)s * B_ + b) * 4096 + hq) * 4;
        l += part[base]; ax += part[base + 1]; ay += part[base + 2];
    }
    const float inv = 1.f / l;
    const size_t o = (size_t)b * 3 * JC + hq;
    cm0[o]          = ax * inv;
    cm0[o + JC]     = ay * inv;
    cm0[o + 2 * JC] = 0.f;
}

// =====================================================================
// Kernel 2: coarse concat -> SPLIT hi/lo bf16 NHWC planes [b][px][160]
// =====================================================================
__global__ __launch_bounds__(256) void coarse_concat_split(
    const void* __restrict__ f0c, const void* __restrict__ f1c,
    const float* __restrict__ cm0, ushort_t* __restrict__ hiP,
    ushort_t* __restrict__ loP, const int* __restrict__ dflag)
{
    const int f32 = *dflag;
    const int idx = blockIdx.x * 256 + threadIdx.x;   // B*JC
    const int b = idx >> 12, hw = idx & (JC - 1);
    const size_t ib = (size_t)b * CC * JC;
    ushort_t* oh = hiP + (size_t)idx * 160;
    ushort_t* ol = loP + (size_t)idx * 160;

#pragma unroll 4
    for (int c = 0; c < CC; ++c) {
        const float v = ldin(f0c, ib + (size_t)c * JC + hw, f32);
        const ushort_t h = f2bfbits(v);
        oh[c] = h; ol[c] = f2bfbits(v - bfbits2f(h));
    }

    const float gx = cm0[((size_t)b * 3 + 0) * JC + hw];
    const float gy = cm0[((size_t)b * 3 + 1) * JC + hw];
    const float x = (gx + 1.f) * 32.f - 0.5f;
    const float y = (gy + 1.f) * 32.f - 0.5f;
    const float x0f = floorf(x), y0f = floorf(y);
    const float wx = x - x0f, wy = y - y0f;
    const int x0 = (int)x0f, y0 = (int)y0f;
    const int x1 = x0 + 1, y1 = y0 + 1;
    const float vx0 = (x0 >= 0 && x0 < WC) ? 1.f : 0.f;
    const float vx1 = (x1 >= 0 && x1 < WC) ? 1.f : 0.f;
    const float vy0 = (y0 >= 0 && y0 < HC) ? 1.f : 0.f;
    const float vy1 = (y1 >= 0 && y1 < HC) ? 1.f : 0.f;
    const int cx0 = min(max(x0, 0), WC - 1), cx1 = min(max(x1, 0), WC - 1);
    const int cy0 = min(max(y0, 0), HC - 1), cy1 = min(max(y1, 0), HC - 1);
    const float w00 = (1.f - wx) * (1.f - wy) * vx0 * vy0;
    const float w01 = wx * (1.f - wy) * vx1 * vy0;
    const float w10 = (1.f - wx) * wy * vx0 * vy1;
    const float w11 = wx * wy * vx1 * vy1;
    const int i00 = cy0 * WC + cx0, i01 = cy0 * WC + cx1;
    const int i10 = cy1 * WC + cx0, i11 = cy1 * WC + cx1;

#pragma unroll 4
    for (int c = 0; c < CC; ++c) {
        const size_t pb = ib + (size_t)c * JC;
        const float v = w00 * ldin(f1c, pb + i00, f32) + w01 * ldin(f1c, pb + i01, f32)
                      + w10 * ldin(f1c, pb + i10, f32) + w11 * ldin(f1c, pb + i11, f32);
        const ushort_t h = f2bfbits(v);
        oh[64 + c] = h; ol[64 + c] = f2bfbits(v - bfbits2f(h));
    }
    {
        const ushort_t h = f2bfbits(gx);
        oh[128] = h; ol[128] = f2bfbits(gx - bfbits2f(h));
    }
    {
        const ushort_t h = f2bfbits(gy);
        oh[129] = h; ol[129] = f2bfbits(gy - bfbits2f(h));
    }
    for (int c = 130; c < 160; ++c) { oh[c] = 0; ol[c] = 0; }
}

// =====================================================================
// BN+ReLU+split elementwise: fp32 NHWC 256 -> hi/lo bf16 planes
// =====================================================================
__global__ __launch_bounds__(256) void bnrelu_split_kernel(
    const float* __restrict__ x, const float2* __restrict__ st,
    ushort_t* __restrict__ hiP, ushort_t* __restrict__ loP)
{
    const int idx = blockIdx.x * 256 + threadIdx.x;   // B*JC*32
    const int px = idx >> 5;
    const int c8 = (idx & 31) << 3;
    const float4 v0 = *(const float4*)&x[(size_t)px * 256 + c8];
    const float4 v1 = *(const float4*)&x[(size_t)px * 256 + c8 + 4];
    const float vv[8] = {v0.x, v0.y, v0.z, v0.w, v1.x, v1.y, v1.z, v1.w};
    ushort_t hh[8], ll[8];
#pragma unroll
    for (int e = 0; e < 8; ++e) {
        const float2 s = st[c8 + e];
        const float f = fmaxf((vv[e] - s.x) * s.y, 0.f);
        const ushort_t h = f2bfbits(f);
        hh[e] = h; ll[e] = f2bfbits(f - bfbits2f(h));
    }
    uint4 oh, ol;
    oh.x = (unsigned)hh[0] | ((unsigned)hh[1] << 16);
    oh.y = (unsigned)hh[2] | ((unsigned)hh[3] << 16);
    oh.z = (unsigned)hh[4] | ((unsigned)hh[5] << 16);
    oh.w = (unsigned)hh[6] | ((unsigned)hh[7] << 16);
    ol.x = (unsigned)ll[0] | ((unsigned)ll[1] << 16);
    ol.y = (unsigned)ll[2] | ((unsigned)ll[3] << 16);
    ol.z = (unsigned)ll[4] | ((unsigned)ll[5] << 16);
    ol.w = (unsigned)ll[6] | ((unsigned)ll[7] << 16);
    *(uint4*)&hiP[(size_t)px * 256 + c8] = oh;
    *(uint4*)&loP[(size_t)px * 256 + c8] = ol;
}

// =====================================================================
// Kernel 3a: COARSE 3x3 conv, split-bf16 MFMA + fused BN-stat atomics.
// =====================================================================
__global__ __launch_bounds__(256, 3) void conv3x3_wsplit(
    const ushort_t* __restrict__ hiP, const ushort_t* __restrict__ loP,
    const ushort_t* __restrict__ wfrag,
    float* __restrict__ out, float* __restrict__ chsum,
    int CIP, int CO, int H, int W, int tilesX)
{
    __shared__ ushort_t actH[18 * 18 * 36];   // 23328 B
    __shared__ ushort_t actL[18 * 18 * 36];   // 23328 B
    __shared__ float smS[4][2][16], smQ[4][2][16];   // 1 KB

    const int nch = CIP >> 5;
    const int tid = threadIdx.x;
    const int tile = blockIdx.x;
    const int b = blockIdx.y;
    const int cog = blockIdx.z;
    const int ty = (tile / tilesX) * 16;
    const int tx = (tile % tilesX) * 16;
    const int wv = tid >> 6;
    const int ln = tid & 63;
    const int lm = ln & 15;
    const int q8 = (ln >> 4) * 8;

    v4f acc[4][2];
#pragma unroll
    for (int i = 0; i < 4; ++i)
#pragma unroll
        for (int j = 0; j < 2; ++j) acc[i][j] = (v4f)(0.f);

    for (int ch = 0; ch < nch; ++ch) {
        const int ci0 = ch << 5;
        __syncthreads();
        for (int p = tid; p < 2592; p += 256) {
            const int pl = (p >= 1296) ? 1 : 0;
            const int r = p - pl * 1296;
            const int yy = r / 72;
            const int rem = r - yy * 72;
            const int xx = rem >> 2;
            const int cs = (rem & 3) << 3;
            const int gy = ty + yy - 1, gx = tx + xx - 1;
            uint4 val = make_uint4(0u, 0u, 0u, 0u);
            if (gy >= 0 && gy < H && gx >= 0 && gx < W) {
                const ushort_t* src = pl ? loP : hiP;
                val = *(const uint4*)&src[(((size_t)(b * H + gy)) * W + gx) * CIP + ci0 + cs];
            }
            ushort_t* dst = pl ? actL : actH;
            *(uint4*)&dst[(yy * 18 + xx) * 36 + cs] = val;
        }
        __syncthreads();

#pragma unroll
        for (int k = 0; k < 9; ++k) {
            const int dy = k / 3, dx = k - 3 * (k / 3);
            const size_t fb = (((size_t)(cog * 9 + k) * 4) * nch + ch) * 64 + ln;
            const size_t step = (size_t)nch * 64;
            const v8s bh0 = *(const v8s*)&wfrag[fb * 8];
            const v8s bl0 = *(const v8s*)&wfrag[(fb + step) * 8];
            const v8s bh1 = *(const v8s*)&wfrag[(fb + 2 * step) * 8];
            const v8s bl1 = *(const v8s*)&wfrag[(fb + 3 * step) * 8];
#pragma unroll
            for (int mt = 0; mt < 4; ++mt) {
                const int r = wv * 4 + mt;
                const int aoff = ((r + dy) * 18 + lm + dx) * 36 + q8;
                const v8s ah = *(const v8s*)&actH[aoff];
                const v8s al = *(const v8s*)&actL[aoff];
                acc[mt][0] = __builtin_amdgcn_mfma_f32_16x16x32_bf16(ah, bl0, acc[mt][0], 0, 0, 0);
                acc[mt][0] = __builtin_amdgcn_mfma_f32_16x16x32_bf16(al, bh0, acc[mt][0], 0, 0, 0);
                acc[mt][0] = __builtin_amdgcn_mfma_f32_16x16x32_bf16(ah, bh0, acc[mt][0], 0, 0, 0);
                acc[mt][1] = __builtin_amdgcn_mfma_f32_16x16x32_bf16(ah, bl1, acc[mt][1], 0, 0, 0);
                acc[mt][1] = __builtin_amdgcn_mfma_f32_16x16x32_bf16(al, bh1, acc[mt][1], 0, 0, 0);
                acc[mt][1] = __builtin_amdgcn_mfma_f32_16x16x32_bf16(ah, bh1, acc[mt][1], 0, 0, 0);
            }
        }
    }

    // D layout: col(n=co)=ln&15, row(m=x)=(ln>>4)*4+i
#pragma unroll
    for (int mt = 0; mt < 4; ++mt) {
        const int y = ty + wv * 4 + mt;
#pragma unroll
        for (int nt = 0; nt < 2; ++nt) {
            const int co = cog * 32 + nt * 16 + lm;
#pragma unroll
            for (int i = 0; i < 4; ++i) {
                const int x = tx + ((ln >> 4) << 2) + i;
                out[(((size_t)(b * H + y)) * W + x) * CO + co] = acc[mt][nt][i];
            }
        }
    }

    // ---- fused BN-stat partial sums (per-channel sum & sumsq) ----
    float s0 = 0.f, s1 = 0.f, q0 = 0.f, q1 = 0.f;
#pragma unroll
    for (int mt = 0; mt < 4; ++mt)
#pragma unroll
        for (int i = 0; i < 4; ++i) {
            float v = acc[mt][0][i]; s0 += v; q0 += v * v;
            v = acc[mt][1][i]; s1 += v; q1 += v * v;
        }
    s0 += __shfl_xor(s0, 16); s0 += __shfl_xor(s0, 32);
    s1 += __shfl_xor(s1, 16); s1 += __shfl_xor(s1, 32);
    q0 += __shfl_xor(q0, 16); q0 += __shfl_xor(q0, 32);
    q1 += __shfl_xor(q1, 16); q1 += __shfl_xor(q1, 32);
    __syncthreads();
    if (ln < 16) {
        smS[wv][0][ln] = s0; smS[wv][1][ln] = s1;
        smQ[wv][0][ln] = q0; smQ[wv][1][ln] = q1;
    }
    __syncthreads();
    if (tid < 32) {
        const int nt = tid >> 4, l2 = tid & 15;
        float S = 0.f, Q = 0.f;
        for (int w = 0; w < 4; ++w) { S += smS[w][nt][l2]; Q += smQ[w][nt][l2]; }
        const int co = cog * 32 + nt * 16 + l2;
        atomicAdd(&chsum[2 * co], S);
        atomicAdd(&chsum[2 * co + 1], Q);
    }
}

// =====================================================================
// Kernel 3b: FINE 3x3 conv, single-bf16 MFMA + fused BN-stat atomics.
// =====================================================================
template <bool BN>
__global__ __launch_bounds__(256) void conv3x3_mfma(
    const ushort_t* __restrict__ in,
    const ushort_t* __restrict__ wp,   // [9][CO][CI] bf16
    const float2* __restrict__ stats,
    ushort_t* __restrict__ out, float* __restrict__ chsum,
    int CI, int CO, int H, int W, int tilesX)
{
    __shared__ ushort_t act[18 * 18 * 40];
    __shared__ ushort_t wbuf[9 * 32 * 40];
    __shared__ float2 st[256];
    __shared__ float smS[4][2][16], smQ[4][2][16];

    const int tid = threadIdx.x;
    const int tile = blockIdx.x;
    const int b = blockIdx.y;
    const int cog = blockIdx.z;
    const int ty = (tile / tilesX) * 16;
    const int tx = (tile % tilesX) * 16;
    const int wv = tid >> 6;
    const int ln = tid & 63;
    const int lm = ln & 15;
    const int q8 = (ln >> 4) * 8;

    if (BN) for (int c = tid; c < CI; c += 256) st[c] = stats[c];

    v4f acc[4][2];
#pragma unroll
    for (int i = 0; i < 4; ++i)
#pragma unroll
        for (int j = 0; j < 2; ++j) acc[i][j] = (v4f)(0.f);

    const int nChunks = CI >> 5;
    for (int ch = 0; ch < nChunks; ++ch) {
        const int ci0 = ch << 5;
        __syncthreads();
        for (int p = tid; p < 1296; p += 256) {
            const int yy = p / 72;
            const int rem = p - yy * 72;
            const int xx = rem >> 2;
            const int cs = (rem & 3) << 3;
            const int gy = ty + yy - 1, gx = tx + xx - 1;
            uint4 val = make_uint4(0u, 0u, 0u, 0u);
            if (gy >= 0 && gy < H && gx >= 0 && gx < W) {
                const ushort_t* gp = in + (((size_t)(b * H + gy)) * W + gx) * CI + ci0 + cs;
                val = *(const uint4*)gp;
                if (BN) {
                    unsigned u[4] = {val.x, val.y, val.z, val.w};
                    unsigned o[4];
#pragma unroll
                    for (int e = 0; e < 4; ++e) {
                        float lo = bfbits2f(u[e] & 0xffffu);
                        float hi = bfbits2f(u[e] >> 16);
                        const float2 s0 = st[ci0 + cs + 2 * e];
                        const float2 s1 = st[ci0 + cs + 2 * e + 1];
                        lo = fmaxf((lo - s0.x) * s0.y, 0.f);
                        hi = fmaxf((hi - s1.x) * s1.y, 0.f);
                        o[e] = (unsigned)f2bfbits(lo) | ((unsigned)f2bfbits(hi) << 16);
                    }
                    val = make_uint4(o[0], o[1], o[2], o[3]);
                }
            }
            *(uint4*)&act[(yy * 18 + xx) * 40 + cs] = val;
        }
        for (int p = tid; p < 1152; p += 256) {
            const int k = p / 128;
            const int rem = p - k * 128;
            const int co = rem >> 2;
            const int cs = (rem & 3) << 3;
            const ushort_t* gp = wp + ((size_t)k * CO + cog * 32 + co) * CI + ci0 + cs;
            *(uint4*)&wbuf[(k * 32 + co) * 40 + cs] = *(const uint4*)gp;
        }
        __syncthreads();

#pragma unroll
        for (int k = 0; k < 9; ++k) {
            const int dy = k / 3, dx = k - 3 * (k / 3);
            const v8s bf0 = *(const v8s*)&wbuf[(k * 32 + lm) * 40 + q8];
            const v8s bf1 = *(const v8s*)&wbuf[(k * 32 + 16 + lm) * 40 + q8];
#pragma unroll
            for (int mt = 0; mt < 4; ++mt) {
                const int r = wv * 4 + mt;
                const v8s af = *(const v8s*)&act[((r + dy) * 18 + lm + dx) * 40 + q8];
                acc[mt][0] = __builtin_amdgcn_mfma_f32_16x16x32_bf16(af, bf0, acc[mt][0], 0, 0, 0);
                acc[mt][1] = __builtin_amdgcn_mfma_f32_16x16x32_bf16(af, bf1, acc[mt][1], 0, 0, 0);
            }
        }
    }

#pragma unroll
    for (int mt = 0; mt < 4; ++mt) {
        const int y = ty + wv * 4 + mt;
#pragma unroll
        for (int nt = 0; nt < 2; ++nt) {
            const int co = cog * 32 + nt * 16 + lm;
#pragma unroll
            for (int i = 0; i < 4; ++i) {
                const int x = tx + ((ln >> 4) << 2) + i;
                out[(((size_t)(b * H + y)) * W + x) * CO + co] = f2bfbits(acc[mt][nt][i]);
            }
        }
    }

    // ---- fused BN-stat partial sums ----
    float s0 = 0.f, s1 = 0.f, q0 = 0.f, q1 = 0.f;
#pragma unroll
    for (int mt = 0; mt < 4; ++mt)
#pragma unroll
        for (int i = 0; i < 4; ++i) {
            float v = acc[mt][0][i]; s0 += v; q0 += v * v;
            v = acc[mt][1][i]; s1 += v; q1 += v * v;
        }
    s0 += __shfl_xor(s0, 16); s0 += __shfl_xor(s0, 32);
    s1 += __shfl_xor(s1, 16); s1 += __shfl_xor(s1, 32);
    q0 += __shfl_xor(q0, 16); q0 += __shfl_xor(q0, 32);
    q1 += __shfl_xor(q1, 16); q1 += __shfl_xor(q1, 32);
    __syncthreads();
    if (ln < 16) {
        smS[wv][0][ln] = s0; smS[wv][1][ln] = s1;
        smQ[wv][0][ln] = q0; smQ[wv][1][ln] = q1;
    }
    __syncthreads();
    if (tid < 32) {
        const int nt = tid >> 4, l2 = tid & 15;
        float S = 0.f, Q = 0.f;
        for (int w = 0; w < 4; ++w) { S += smS[w][nt][l2]; Q += smQ[w][nt][l2]; }
        const int co = cog * 32 + nt * 16 + l2;
        atomicAdd(&chsum[2 * co], S);
        atomicAdd(&chsum[2 * co + 1], Q);
    }
}

// =====================================================================
// stats finalize: (sum, sumsq) -> (mean, rsqrt(var+eps))
// =====================================================================
__global__ void stats_finalize_kernel(const float* __restrict__ chsum,
                                      float2* __restrict__ st, int C, float inv_n)
{
    const int c = threadIdx.x;
    if (c >= C) return;
    const float mean = chsum[2 * c] * inv_n;
    const float var = chsum[2 * c + 1] * inv_n - mean * mean;
    st[c] = make_float2(mean, 1.0f / sqrtf(var + 1e-5f));
}

// =====================================================================
// Kernel 5: coarse head (fp32 NHWC): 1x1 conv 256->3 + bias + cm0
// =====================================================================
__global__ __launch_bounds__(256) void coarse_head_kernel(
    const float* __restrict__ A, const float2* __restrict__ stats,
    const void* __restrict__ w5, const void* __restrict__ b5,
    float* __restrict__ cm0, void* __restrict__ out,
    const int* __restrict__ dflag)
{
    const int f32 = *dflag;
    __shared__ float wl[3][256];
    __shared__ float bl[3];
    __shared__ float2 st[256];
    const int tid = threadIdx.x;
    for (int i = tid; i < 768; i += 256) wl[i >> 8][i & 255] = ldin(w5, i, f32);
    if (tid < 3) bl[tid] = ldin(b5, tid, f32);
    st[tid] = stats[tid];
    __syncthreads();

    const int idx = blockIdx.x * 256 + tid;
    const int b = idx >> 12, hw = idx & (JC - 1);
    float a0 = bl[0], a1 = bl[1], a2 = bl[2];
    const float* p = A + (size_t)idx * 256;
    for (int c = 0; c < 256; c += 4) {
        const float4 raw = *(const float4*)(p + c);
        const float rv[4] = {raw.x, raw.y, raw.z, raw.w};
#pragma unroll
        for (int e = 0; e < 4; ++e) {
            const int cc = c + e;
            const float v = fmaxf((rv[e] - st[cc].x) * st[cc].y, 0.f);
            a0 += v * wl[0][cc]; a1 += v * wl[1][cc]; a2 += v * wl[2][cc];
        }
    }
    const size_t base = (size_t)b * 3 * JC + hw;
    const float c0 = cm0[base] + a0;
    const float c1 = cm0[base + JC] + a1;
    const float c2 = cm0[base + 2 * JC] + a2;
    cm0[base] = c0; cm0[base + JC] = c1; cm0[base + 2 * JC] = c2;
    stout(out, base, c0, f32);
    stout(out, base + JC, c1, f32);
    stout(out, base + 2 * JC, c2, f32);
}

// =====================================================================
// Kernel 6: bilinear 2x upsample (half-pixel, edge clamp)
// =====================================================================
__global__ __launch_bounds__(256) void upsample_kernel(
    const float* __restrict__ cm, float* __restrict__ up)
{
    const int idx = blockIdx.x * 256 + threadIdx.x;
    const int ox = idx & 127, oy = (idx >> 7) & 127, bc = idx >> 14;
    const float sx = ox * 0.5f - 0.25f;
    const float sy = oy * 0.5f - 0.25f;
    const int x0 = (int)floorf(sx), y0 = (int)floorf(sy);
    const float fx = sx - x0, fy = sy - y0;
    const int cx0 = max(x0, 0), cx1 = min(x0 + 1, WC - 1);
    const int cy0 = max(y0, 0), cy1 = min(y0 + 1, HC - 1);
    const float* p = cm + (size_t)bc * JC;
    const float v = (1.f - fy) * ((1.f - fx) * p[cy0 * WC + cx0] + fx * p[cy0 * WC + cx1])
                  + fy * ((1.f - fx) * p[cy1 * WC + cx0] + fx * p[cy1 * WC + cx1]);
    up[idx] = v;
}

// =====================================================================
// Kernel 7: fine concat -> NHWC bf16 [b][y][x][64] (50 real + 14 zero)
// =====================================================================
__global__ __launch_bounds__(256) void fine_concat_nhwc(
    const void* __restrict__ f0f, const void* __restrict__ f1f,
    const float* __restrict__ up, ushort_t* __restrict__ A,
    const int* __restrict__ dflag)
{
    const int f32 = *dflag;
    const int idx = blockIdx.x * 256 + threadIdx.x;   // B*JF
    const int b = idx >> 14, hw = idx & (JF - 1);
    const size_t ib = (size_t)b * CF * JF;
    ushort_t* o = A + (size_t)idx * 64;

    for (int c = 0; c < CF; ++c)
        o[c] = f2bfbits(ldin(f0f, ib + (size_t)c * JF + hw, f32));

    const size_t ub = (size_t)b * 3 * JF + hw;
    const float gx = up[ub], gy = up[ub + JF];
    const float x = (gx + 1.f) * 64.f - 0.5f;
    const float y = (gy + 1.f) * 64.f - 0.5f;
    const float x0f = floorf(x), y0f = floorf(y);
    const float wx = x - x0f, wy = y - y0f;
    const int x0 = (int)x0f, y0 = (int)y0f;
    const int x1 = x0 + 1, y1 = y0 + 1;
    const float vx0 = (x0 >= 0 && x0 < WF) ? 1.f : 0.f;
    const float vx1 = (x1 >= 0 && x1 < WF) ? 1.f : 0.f;
    const float vy0 = (y0 >= 0 && y0 < HF) ? 1.f : 0.f;
    const float vy1 = (y1 >= 0 && y1 < HF) ? 1.f : 0.f;
    const int cx0 = min(max(x0, 0), WF - 1), cx1 = min(max(x1, 0), WF - 1);
    const int cy0 = min(max(y0, 0), HF - 1), cy1 = min(max(y1, 0), HF - 1);
    const float w00 = (1.f - wx) * (1.f - wy) * vx0 * vy0;
    const float w01 = wx * (1.f - wy) * vx1 * vy0;
    const float w10 = (1.f - wx) * wy * vx0 * vy1;
    const float w11 = wx * wy * vx1 * vy1;
    const int i00 = cy0 * WF + cx0, i01 = cy0 * WF + cx1;
    const int i10 = cy1 * WF + cx0, i11 = cy1 * WF + cx1;

    for (int c = 0; c < CF; ++c) {
        const size_t pb = ib + (size_t)c * JF;
        const float v = w00 * ldin(f1f, pb + i00, f32) + w01 * ldin(f1f, pb + i01, f32)
                      + w10 * ldin(f1f, pb + i10, f32) + w11 * ldin(f1f, pb + i11, f32);
        o[24 + c] = f2bfbits(v);
    }
    o[48] = f2bfbits(gx);
    o[49] = f2bfbits(gy);
    for (int c = 50; c < 64; ++c) o[c] = 0;
}

// =====================================================================
// Kernel 8: fine head (NHWC bf16): 1x1 conv 64->3 + bias + up -> out1
// =====================================================================
__global__ __launch_bounds__(256) void fine_head_kernel(
    const ushort_t* __restrict__ A, const float2* __restrict__ stats,
    const void* __restrict__ w5, const void* __restrict__ b5,
    const float* __restrict__ up, void* __restrict__ out,
    const int* __restrict__ dflag)
{
    const int f32 = *dflag;
    __shared__ float wl[3][64];
    __shared__ float bl[3];
    __shared__ float2 st[64];
    const int tid = threadIdx.x;
    if (tid < 192) wl[tid >> 6][tid & 63] = ldin(w5, tid, f32);
    if (tid < 3) bl[tid] = ldin(b5, tid, f32);
    if (tid < 64) st[tid] = stats[tid];
    __syncthreads();

    const int idx = blockIdx.x * 256 + tid;
    const int b = idx >> 14, hw = idx & (JF - 1);
    float a0 = bl[0], a1 = bl[1], a2 = bl[2];
    const ushort_t* p = A + (size_t)idx * 64;
    for (int c = 0; c < 64; c += 8) {
        const uint4 raw = *(const uint4*)(p + c);
        const unsigned u[4] = {raw.x, raw.y, raw.z, raw.w};
#pragma unroll
        for (int e = 0; e < 4; ++e) {
            const int c0 = c + 2 * e, c1 = c0 + 1;
            float lo = bfbits2f(u[e] & 0xffffu);
            float hi = bfbits2f(u[e] >> 16);
            lo = fmaxf((lo - st[c0].x) * st[c0].y, 0.f);
            hi = fmaxf((hi - st[c1].x) * st[c1].y, 0.f);
            a0 += lo * wl[0][c0] + hi * wl[0][c1];
            a1 += lo * wl[1][c0] + hi * wl[1][c1];
            a2 += lo * wl[2][c0] + hi * wl[2][c1];
        }
    }
    const size_t base = (size_t)b * 3 * JF + hw;
    stout(out, OUT0_ELEMS + base,          up[base] + a0, f32);
    stout(out, OUT0_ELEMS + base + JF,     up[base + JF] + a1, f32);
    stout(out, OUT0_ELEMS + base + 2 * JF, up[base + 2 * JF] + a2, f32);
}

// =====================================================================
extern "C" void kernel_launch(void* const* d_in, const int* in_sizes, int n_in,
                              void* d_out, int out_size, void* d_ws, size_t ws_size,
                              hipStream_t stream)
{
    const void* f0c = d_in[0];
    const void* f1c = d_in[1];
    const void* f0f = d_in[2];
    const void* f1f = d_in[3];
    const void* cw1 = d_in[4];
    const void* cw2 = d_in[5];
    const void* cw3 = d_in[6];
    const void* cw4 = d_in[7];
    const void* cw5 = d_in[8];
    const void* cb5 = d_in[9];
    const void* fw1 = d_in[10];
    const void* fw2 = d_in[11];
    const void* fw3 = d_in[12];
    const void* fw4 = d_in[13];
    const void* fw5 = d_in[14];
    const void* fb5 = d_in[15];

    // ---- workspace layout (same proven footprint as R7) ----
    char* wsb = (char*)d_ws;
    float* bufA    = (float*)wsb;                       // 16 MiB
    float* bufB    = (float*)(wsb + 16777216);          // 16 MiB
    float* cm0     = (float*)(wsb + 33554432);          // 196,608 B
    float* up      = (float*)(wsb + 33751040);          // 786,432 B
    float* chsum   = (float*)(wsb + 34537472);          // 2,048 B (ex-partial region)
    float2* st_g   = (float2*)(wsb + 34668544);         // 2,048 B
    int* dflag     = (int*)(wsb + 34670592);            // 64 B
    ushort_t* fwp  = (ushort_t*)(wsb + 34670656);       // 294,912 B
    ushort_t* fw1p = fwp;
    ushort_t* fw2p = fwp + 36864;
    ushort_t* fw3p = fwp + 73728;
    ushort_t* fw4p = fwp + 110592;
    ushort_t* wfrag = (ushort_t*)(wsb + 34965568);      // up to 9,437,184 B

    // split activation planes: hi = bufA[0..8MB), lo = bufA[8..16MB)
    ushort_t* hiP = (ushort_t*)bufA;
    ushort_t* loP = (ushort_t*)(wsb + 8388608);

    // corr split Q/K planes in bufA's first 8 MB (dead before concat)
    ushort_t* qhi = (ushort_t*)bufA;
    ushort_t* qlo = qhi + 1048576;
    ushort_t* khi = qlo + 1048576;
    ushort_t* klo = khi + 1048576;
    float* cpart = (float*)bufB;   // 1 MB corr partials (bufB dead during corr)

    ushort_t* fF1 = (ushort_t*)bufB;   // fine ping
    ushort_t* fF2 = (ushort_t*)bufA;   // fine pong

    // 0. dtype probe
    dtype_probe_kernel<<<1, 256, 0, stream>>>((const ushort_t*)f0c, dflag);

    // fine weight repacks (bf16 [k][co][ci_pad])
    repack_w_kernel<<<(9 * 64 * 64 + 255) / 256, 256, 0, stream>>>(fw1, fw1p, 64, 50, 64, dflag);
    repack_w_kernel<<<(9 * 64 * 64 + 255) / 256, 256, 0, stream>>>(fw2, fw2p, 64, 64, 64, dflag);
    repack_w_kernel<<<(9 * 64 * 64 + 255) / 256, 256, 0, stream>>>(fw3, fw3p, 64, 64, 64, dflag);
    repack_w_kernel<<<(9 * 64 * 64 + 255) / 256, 256, 0, stream>>>(fw4, fw4p, 64, 64, 64, dflag);

    // 1. correlation: split-transpose Q/K, split-K MFMA, reduce
    split_transpose_kernel<<<dim3(B_ * 64), 256, 0, stream>>>(f0c, qhi, qlo, dflag);
    split_transpose_kernel<<<dim3(B_ * 64), 256, 0, stream>>>(f1c, khi, klo, dflag);
    corr_mfma_kernel<<<dim3(HC, B_, 4), 256, 0, stream>>>(qhi, qlo, khi, klo, cpart);
    corr_reduce_kernel<<<dim3(B_ * JC / 256), 256, 0, stream>>>(cpart, cm0);

    // 2. coarse concat -> split planes (CIP=160); overwrites q/k (dead)
    coarse_concat_split<<<dim3(B_ * JC / 256), 256, 0, stream>>>(f0c, f1c, cm0, hiP, loP, dflag);

    // 3. coarse conv stack: fragment-weight split-bf16 MFMA, fused stats
    const dim3 cgrid(16, B_, 8);
    repack_wfrag_kernel<<<(8 * 9 * 2 * 2 * 5 * 64 + 255) / 256, 256, 0, stream>>>(cw1, wfrag, 130, 5, dflag);
    hipMemsetAsync(chsum, 0, 2048, stream);
    conv3x3_wsplit<<<cgrid, 256, 0, stream>>>(hiP, loP, wfrag, bufB, chsum, 160, 256, HC, WC, 4);
    stats_finalize_kernel<<<1, 256, 0, stream>>>(chsum, st_g, 256, 1.f / 16384.f);

    bnrelu_split_kernel<<<B_ * JC * 32 / 256, 256, 0, stream>>>(bufB, st_g, hiP, loP);
    repack_wfrag_kernel<<<(8 * 9 * 2 * 2 * 8 * 64 + 255) / 256, 256, 0, stream>>>(cw2, wfrag, 256, 8, dflag);
    hipMemsetAsync(chsum, 0, 2048, stream);
    conv3x3_wsplit<<<cgrid, 256, 0, stream>>>(hiP, loP, wfrag, bufB, chsum, 256, 256, HC, WC, 4);
    stats_finalize_kernel<<<1, 256, 0, stream>>>(chsum, st_g, 256, 1.f / 16384.f);

    bnrelu_split_kernel<<<B_ * JC * 32 / 256, 256, 0, stream>>>(bufB, st_g, hiP, loP);
    repack_wfrag_kernel<<<(8 * 9 * 2 * 2 * 8 * 64 + 255) / 256, 256, 0, stream>>>(cw3, wfrag, 256, 8, dflag);
    hipMemsetAsync(chsum, 0, 2048, stream);
    conv3x3_wsplit<<<cgrid, 256, 0, stream>>>(hiP, loP, wfrag, bufB, chsum, 256, 256, HC, WC, 4);
    stats_finalize_kernel<<<1, 256, 0, stream>>>(chsum, st_g, 256, 1.f / 16384.f);

    bnrelu_split_kernel<<<B_ * JC * 32 / 256, 256, 0, stream>>>(bufB, st_g, hiP, loP);
    repack_wfrag_kernel<<<(8 * 9 * 2 * 2 * 8 * 64 + 255) / 256, 256, 0, stream>>>(cw4, wfrag, 256, 8, dflag);
    hipMemsetAsync(chsum, 0, 2048, stream);
    conv3x3_wsplit<<<cgrid, 256, 0, stream>>>(hiP, loP, wfrag, bufB, chsum, 256, 256, HC, WC, 4);
    stats_finalize_kernel<<<1, 256, 0, stream>>>(chsum, st_g, 256, 1.f / 16384.f);

    // 4. coarse head -> out0, cmatch (in place over cm0)
    coarse_head_kernel<<<dim3(B_ * JC / 256), 256, 0, stream>>>(bufB, st_g, cw5, cb5, cm0, d_out, dflag);

    // 5. upsample (cm0 now holds cmatch)
    upsample_kernel<<<dim3(B_ * 3 * JF / 256), 256, 0, stream>>>(cm0, up);

    // 6. fine concat -> fF1 (bufB region; conv4 raw dead after head)
    fine_concat_nhwc<<<dim3(B_ * JF / 256), 256, 0, stream>>>(f0f, f1f, up, fF1, dflag);

    // 7. fine conv stack (bf16 MFMA, fused stats)
    const dim3 fgrid(64, B_, 2);
    hipMemsetAsync(chsum, 0, 512, stream);
    conv3x3_mfma<false><<<fgrid, 256, 0, stream>>>(fF1, fw1p, nullptr, fF2, chsum, 64, 64, HF, WF, 8);
    stats_finalize_kernel<<<1, 256, 0, stream>>>(chsum, st_g, 64, 1.f / 65536.f);
    hipMemsetAsync(chsum, 0, 512, stream);
    conv3x3_mfma<true><<<fgrid, 256, 0, stream>>>(fF2, fw2p, st_g, fF1, chsum, 64, 64, HF, WF, 8);
    stats_finalize_kernel<<<1, 256, 0, stream>>>(chsum, st_g, 64, 1.f / 65536.f);
    hipMemsetAsync(chsum, 0, 512, stream);
    conv3x3_mfma<true><<<fgrid, 256, 0, stream>>>(fF1, fw3p, st_g, fF2, chsum, 64, 64, HF, WF, 8);
    stats_finalize_kernel<<<1, 256, 0, stream>>>(chsum, st_g, 64, 1.f / 65536.f);
    hipMemsetAsync(chsum, 0, 512, stream);
    conv3x3_mfma<true><<<fgrid, 256, 0, stream>>>(fF2, fw4p, st_g, fF1, chsum, 64, 64, HF, WF, 8);
    stats_finalize_kernel<<<1, 256, 0, stream>>>(chsum, st_g, 64, 1.f / 65536.f);

    // 8. fine head -> out1
    fine_head_kernel<<<dim3(B_ * JF / 256), 256, 0, stream>>>(fF1, st_g, fw5, fb5, up, d_out, dflag);
}

// Round 9
// 805.900 us; speedup vs baseline: 6.1113x; 1.0087x over previous
//
#include <hip/hip_runtime.h>
#include <hip/hip_bf16.h>

using bf16 = __hip_bfloat16;
typedef unsigned short ushort_t;
typedef __attribute__((ext_vector_type(8))) short v8s;
typedef __attribute__((ext_vector_type(4))) float v4f;

__device__ __forceinline__ float bfbits2f(unsigned u) {
    return __uint_as_float(u << 16);
}
__device__ __forceinline__ ushort_t f2bfbits(float f) {
    unsigned x = __float_as_uint(f);
    return (ushort_t)((x + 0x7fffu + ((x >> 16) & 1u)) >> 16);
}
// dtype-adaptive input load / output store (flag: 1 = fp32 buffers, 0 = bf16)
__device__ __forceinline__ float ldin(const void* p, size_t i, int f32) {
    return f32 ? ((const float*)p)[i] : bfbits2f(((const ushort_t*)p)[i]);
}
__device__ __forceinline__ void stout(void* p, size_t i, float v, int f32) {
    if (f32) ((float*)p)[i] = v;
    else     ((ushort_t*)p)[i] = f2bfbits(v);
}

// ---------------- sizes ----------------
#define B_   4
#define CC   64
#define HC   64
#define WC   64
#define JC   4096
#define CF   24
#define HF   128
#define WF   128
#define JF   16384
#define OUT0_ELEMS (B_ * 3 * JC)

// =====================================================================
// Kernel 0: dtype probe. flag=1 -> fp32 inputs (R3: confirmed fp32).
// =====================================================================
__global__ void dtype_probe_kernel(const ushort_t* __restrict__ x,
                                   int* __restrict__ flag)
{
    __shared__ int cnt;
    if (threadIdx.x == 0) cnt = 0;
    __syncthreads();
    int c = 0;
    for (int i = threadIdx.x; i < 8192; i += 256) {
        const unsigned e = (x[i] >> 7) & 0xFF;
        if (e >= 0x89) ++c;
    }
    atomicAdd(&cnt, c);
    __syncthreads();
    if (threadIdx.x == 0) *flag = (cnt > 64) ? 1 : 0;
}

// =====================================================================
// Fine weight repack: w[co][ci][3][3] -> wp[k][co][ci_pad] bf16
// =====================================================================
__global__ void repack_w_kernel(const void* __restrict__ w, ushort_t* __restrict__ wp,
                                int CO, int CIreal, int CIP, const int* __restrict__ dflag)
{
    const int f32 = *dflag;
    const int idx = blockIdx.x * 256 + threadIdx.x;
    const int total = 9 * CO * CIP;
    if (idx >= total) return;
    const int k = idx / (CO * CIP);
    const int rem = idx - k * (CO * CIP);
    const int co = rem / CIP;
    const int cip = rem - co * CIP;
    float v = 0.f;
    if (cip < CIreal) v = ldin(w, ((size_t)co * CIreal + cip) * 9 + k, f32);
    wp[((size_t)k * CO + co) * CIP + cip] = f2bfbits(v);
}

// =====================================================================
// Coarse weight repack into MFMA FRAGMENT order, split hi/lo.
// =====================================================================
__global__ void repack_wfrag_kernel(const void* __restrict__ w, ushort_t* __restrict__ wfrag,
                                    int CIreal, int nch, const int* __restrict__ dflag)
{
    const int f32 = *dflag;
    const int idx = blockIdx.x * 256 + threadIdx.x;
    const int total = 8 * 9 * 2 * 2 * nch * 64;
    if (idx >= total) return;
    const int ln = idx & 63;
    int t = idx >> 6;
    const int ch = t % nch; t /= nch;
    const int pl = t & 1; t >>= 1;
    const int nt = t & 1; t >>= 1;
    const int k = t % 9;
    const int cog = t / 9;
    const int co = cog * 32 + nt * 16 + (ln & 15);
    const int cib = ch * 32 + (ln >> 4) * 8;
    ushort_t vals[8];
#pragma unroll
    for (int e = 0; e < 8; ++e) {
        const int ci = cib + e;
        float v = 0.f;
        if (ci < CIreal) v = ldin(w, ((size_t)co * CIreal + ci) * 9 + k, f32);
        const ushort_t h = f2bfbits(v);
        vals[e] = pl ? f2bfbits(v - bfbits2f(h)) : h;
    }
    uint4 o;
    o.x = (unsigned)vals[0] | ((unsigned)vals[1] << 16);
    o.y = (unsigned)vals[2] | ((unsigned)vals[3] << 16);
    o.z = (unsigned)vals[4] | ((unsigned)vals[5] << 16);
    o.w = (unsigned)vals[6] | ((unsigned)vals[7] << 16);
    *(uint4*)&wfrag[(size_t)idx * 8] = o;
}

// =====================================================================
// Kernel 1a: split-transpose feats: [b][64ch][4096px] -> [b][4096px][64ch]
// =====================================================================
__global__ __launch_bounds__(256) void split_transpose_kernel(
    const void* __restrict__ src, ushort_t* __restrict__ hi,
    ushort_t* __restrict__ lo, const int* __restrict__ dflag)
{
    const int f32 = *dflag;
    __shared__ float t[64][65];
    const int blk = blockIdx.x;
    const int b = blk >> 6;
    const int px0 = (blk & 63) * 64;
    const int tid = threadIdx.x;
    const int px = tid & 63;
    for (int i = 0; i < 16; ++i) {
        const int c = (tid >> 6) + 4 * i;
        t[px][c] = ldin(src, ((size_t)b * 64 + c) * 4096 + px0 + px, f32);
    }
    __syncthreads();
    for (int it = 0; it < 2; ++it) {
        const int p = tid + it * 256;
        const int opx = p >> 3, chk = (p & 7) * 8;
        unsigned hh[4], ll[4];
#pragma unroll
        for (int e = 0; e < 4; ++e) {
            const float v0 = t[opx][chk + 2 * e];
            const float v1 = t[opx][chk + 2 * e + 1];
            const ushort_t h0 = f2bfbits(v0);
            const ushort_t h1 = f2bfbits(v1);
            hh[e] = (unsigned)h0 | ((unsigned)h1 << 16);
            ll[e] = (unsigned)f2bfbits(v0 - bfbits2f(h0))
                  | ((unsigned)f2bfbits(v1 - bfbits2f(h1)) << 16);
        }
        const size_t obase = ((size_t)b * 4096 + px0 + opx) * 64 + chk;
        *(uint4*)&hi[obase] = make_uint4(hh[0], hh[1], hh[2], hh[3]);
        *(uint4*)&lo[obase] = make_uint4(ll[0], ll[1], ll[2], ll[3]);
    }
}

// =====================================================================
// Kernel 1b: correlation, SPLIT-K: grid (HC, B, 4). Each block: 64 q x
// 1024 keys (8 chunks of 128). Writes unnormalized partials (l, px, py).
// =====================================================================
#define KCH 128
__global__ __launch_bounds__(256) void corr_mfma_kernel(
    const ushort_t* __restrict__ qhi, const ushort_t* __restrict__ qlo,
    const ushort_t* __restrict__ khi, const ushort_t* __restrict__ klo,
    float* __restrict__ part)
{
    __shared__ ushort_t kbh[KCH * 72];
    __shared__ ushort_t kbl[KCH * 72];
    __shared__ float red[4][64][3];
    const int h = blockIdx.x, b = blockIdx.y, sl = blockIdx.z;
    const int tid = threadIdx.x;
    const int wv = tid >> 6, ln = tid & 63;
    const int lm = ln & 15, quad = ln >> 4, q8 = quad * 8;

    v8s qf[4][2][2];
#pragma unroll
    for (int mt = 0; mt < 4; ++mt)
#pragma unroll
        for (int kc = 0; kc < 2; ++kc) {
            const size_t qoff = ((size_t)b * 4096 + h * 64 + mt * 16 + lm) * 64 + kc * 32 + q8;
            qf[mt][kc][0] = *(const v8s*)&qhi[qoff];
            qf[mt][kc][1] = *(const v8s*)&qlo[qoff];
        }

    float P[4][4][3];
#pragma unroll
    for (int mt = 0; mt < 4; ++mt)
#pragma unroll
        for (int i = 0; i < 4; ++i)
            P[mt][i][0] = P[mt][i][1] = P[mt][i][2] = 0.f;

    const size_t kbase = (size_t)b * 4096 * 64;
    for (int c = 0; c < 1024 / KCH; ++c) {
        const int j0 = sl * 1024 + c * KCH;
        __syncthreads();
        for (int p = tid; p < 2048; p += 256) {
            const int pl = p >> 10;
            const int r = p & 1023;
            const int key = r >> 3, chk = (r & 7) * 8;
            const ushort_t* gsrc = pl ? klo : khi;
            const uint4 v = *(const uint4*)&gsrc[kbase + (size_t)(j0 + key) * 64 + chk];
            ushort_t* dst = pl ? kbl : kbh;
            *(uint4*)&dst[key * 72 + chk] = v;
        }
        __syncthreads();

#pragma unroll
        for (int nt = 0; nt < 2; ++nt) {
            const int kb = wv * 32 + nt * 16;
            const int j = j0 + kb + lm;
            const float gx = (float)((j & 63) * 2 + 1) * (1.f / 64.f) - 1.f;
            const float gy = (float)((j >> 6) * 2 + 1) * (1.f / 64.f) - 1.f;
            const v8s bh0 = *(const v8s*)&kbh[(kb + lm) * 72 + q8];
            const v8s bh1 = *(const v8s*)&kbh[(kb + lm) * 72 + 32 + q8];
            const v8s bl0 = *(const v8s*)&kbl[(kb + lm) * 72 + q8];
            const v8s bl1 = *(const v8s*)&kbl[(kb + lm) * 72 + 32 + q8];
#pragma unroll
            for (int mt = 0; mt < 4; ++mt) {
                v4f acc = (v4f)(0.f);
                acc = __builtin_amdgcn_mfma_f32_16x16x32_bf16(qf[mt][0][0], bl0, acc, 0, 0, 0);
                acc = __builtin_amdgcn_mfma_f32_16x16x32_bf16(qf[mt][0][1], bh0, acc, 0, 0, 0);
                acc = __builtin_amdgcn_mfma_f32_16x16x32_bf16(qf[mt][0][0], bh0, acc, 0, 0, 0);
                acc = __builtin_amdgcn_mfma_f32_16x16x32_bf16(qf[mt][1][0], bl1, acc, 0, 0, 0);
                acc = __builtin_amdgcn_mfma_f32_16x16x32_bf16(qf[mt][1][1], bh1, acc, 0, 0, 0);
                acc = __builtin_amdgcn_mfma_f32_16x16x32_bf16(qf[mt][1][0], bh1, acc, 0, 0, 0);
#pragma unroll
                for (int i = 0; i < 4; ++i) {
                    const float p_ = __expf(acc[i] * 0.125f);
                    P[mt][i][0] += p_;
                    P[mt][i][1] += p_ * gx;
                    P[mt][i][2] += p_ * gy;
                }
            }
        }
    }

#pragma unroll
    for (int mt = 0; mt < 4; ++mt)
#pragma unroll
        for (int i = 0; i < 4; ++i)
#pragma unroll
            for (int d = 0; d < 3; ++d) {
                float v = P[mt][i][d];
                v += __shfl_xor(v, 1);
                v += __shfl_xor(v, 2);
                v += __shfl_xor(v, 4);
                v += __shfl_xor(v, 8);
                P[mt][i][d] = v;
            }
    if (lm == 0) {
#pragma unroll
        for (int mt = 0; mt < 4; ++mt)
#pragma unroll
            for (int i = 0; i < 4; ++i) {
                const int q = mt * 16 + quad * 4 + i;
                red[wv][q][0] = P[mt][i][0];
                red[wv][q][1] = P[mt][i][1];
                red[wv][q][2] = P[mt][i][2];
            }
    }
    __syncthreads();
    if (tid < 64) {
        const int q = tid;
        float l = 0.f, ax = 0.f, ay = 0.f;
        for (int w = 0; w < 4; ++w) {
            l += red[w][q][0]; ax += red[w][q][1]; ay += red[w][q][2];
        }
        const size_t base = (((size_t)sl * B_ + b) * 4096 + h * 64 + q) * 4;
        part[base] = l; part[base + 1] = ax; part[base + 2] = ay;
    }
}

// =====================================================================
// Kernel 1c: merge split-K partials -> cm0 (deterministic)
// =====================================================================
__global__ __launch_bounds__(256) void corr_reduce_kernel(
    const float* __restrict__ part, float* __restrict__ cm0)
{
    const int idx = blockIdx.x * 256 + threadIdx.x;   // B*JC
    const int b = idx >> 12, hq = idx & 4095;
    float l = 0.f, ax = 0.f, ay = 0.f;
    for (int s = 0; s < 4; ++s) {
        const size_t base = (((size_t)s * B_ + b) * 4096 + hq) * 4;
        l += part[base]; ax += part[base + 1]; ay += part[base + 2];
    }
    const float inv = 1.f / l;
    const size_t o = (size_t)b * 3 * JC + hq;
    cm0[o]          = ax * inv;
    cm0[o + JC]     = ay * inv;
    cm0[o + 2 * JC] = 0.f;
}

// =====================================================================
// Kernel 2: coarse concat -> SPLIT hi/lo bf16 NHWC planes [b][px][160]
// =====================================================================
__global__ __launch_bounds__(256) void coarse_concat_split(
    const void* __restrict__ f0c, const void* __restrict__ f1c,
    const float* __restrict__ cm0, ushort_t* __restrict__ hiP,
    ushort_t* __restrict__ loP, const int* __restrict__ dflag)
{
    const int f32 = *dflag;
    const int idx = blockIdx.x * 256 + threadIdx.x;   // B*JC
    const int b = idx >> 12, hw = idx & (JC - 1);
    const size_t ib = (size_t)b * CC * JC;
    ushort_t* oh = hiP + (size_t)idx * 160;
    ushort_t* ol = loP + (size_t)idx * 160;

#pragma unroll 4
    for (int c = 0; c < CC; ++c) {
        const float v = ldin(f0c, ib + (size_t)c * JC + hw, f32);
        const ushort_t h = f2bfbits(v);
        oh[c] = h; ol[c] = f2bfbits(v - bfbits2f(h));
    }

    const float gx = cm0[((size_t)b * 3 + 0) * JC + hw];
    const float gy = cm0[((size_t)b * 3 + 1) * JC + hw];
    const float x = (gx + 1.f) * 32.f - 0.5f;
    const float y = (gy + 1.f) * 32.f - 0.5f;
    const float x0f = floorf(x), y0f = floorf(y);
    const float wx = x - x0f, wy = y - y0f;
    const int x0 = (int)x0f, y0 = (int)y0f;
    const int x1 = x0 + 1, y1 = y0 + 1;
    const float vx0 = (x0 >= 0 && x0 < WC) ? 1.f : 0.f;
    const float vx1 = (x1 >= 0 && x1 < WC) ? 1.f : 0.f;
    const float vy0 = (y0 >= 0 && y0 < HC) ? 1.f : 0.f;
    const float vy1 = (y1 >= 0 && y1 < HC) ? 1.f : 0.f;
    const int cx0 = min(max(x0, 0), WC - 1), cx1 = min(max(x1, 0), WC - 1);
    const int cy0 = min(max(y0, 0), HC - 1), cy1 = min(max(y1, 0), HC - 1);
    const float w00 = (1.f - wx) * (1.f - wy) * vx0 * vy0;
    const float w01 = wx * (1.f - wy) * vx1 * vy0;
    const float w10 = (1.f - wx) * wy * vx0 * vy1;
    const float w11 = wx * wy * vx1 * vy1;
    const int i00 = cy0 * WC + cx0, i01 = cy0 * WC + cx1;
    const int i10 = cy1 * WC + cx0, i11 = cy1 * WC + cx1;

#pragma unroll 4
    for (int c = 0; c < CC; ++c) {
        const size_t pb = ib + (size_t)c * JC;
        const float v = w00 * ldin(f1c, pb + i00, f32) + w01 * ldin(f1c, pb + i01, f32)
                      + w10 * ldin(f1c, pb + i10, f32) + w11 * ldin(f1c, pb + i11, f32);
        const ushort_t h = f2bfbits(v);
        oh[64 + c] = h; ol[64 + c] = f2bfbits(v - bfbits2f(h));
    }
    {
        const ushort_t h = f2bfbits(gx);
        oh[128] = h; ol[128] = f2bfbits(gx - bfbits2f(h));
    }
    {
        const ushort_t h = f2bfbits(gy);
        oh[129] = h; ol[129] = f2bfbits(gy - bfbits2f(h));
    }
    for (int c = 130; c < 160; ++c) { oh[c] = 0; ol[c] = 0; }
}

// =====================================================================
// BN+ReLU+split elementwise: fp32 NHWC 256 -> hi/lo bf16 planes
// =====================================================================
__global__ __launch_bounds__(256) void bnrelu_split_kernel(
    const float* __restrict__ x, const float2* __restrict__ st,
    ushort_t* __restrict__ hiP, ushort_t* __restrict__ loP)
{
    const int idx = blockIdx.x * 256 + threadIdx.x;   // B*JC*32
    const int px = idx >> 5;
    const int c8 = (idx & 31) << 3;
    const float4 v0 = *(const float4*)&x[(size_t)px * 256 + c8];
    const float4 v1 = *(const float4*)&x[(size_t)px * 256 + c8 + 4];
    const float vv[8] = {v0.x, v0.y, v0.z, v0.w, v1.x, v1.y, v1.z, v1.w};
    ushort_t hh[8], ll[8];
#pragma unroll
    for (int e = 0; e < 8; ++e) {
        const float2 s = st[c8 + e];
        const float f = fmaxf((vv[e] - s.x) * s.y, 0.f);
        const ushort_t h = f2bfbits(f);
        hh[e] = h; ll[e] = f2bfbits(f - bfbits2f(h));
    }
    uint4 oh, ol;
    oh.x = (unsigned)hh[0] | ((unsigned)hh[1] << 16);
    oh.y = (unsigned)hh[2] | ((unsigned)hh[3] << 16);
    oh.z = (unsigned)hh[4] | ((unsigned)hh[5] << 16);
    oh.w = (unsigned)hh[6] | ((unsigned)hh[7] << 16);
    ol.x = (unsigned)ll[0] | ((unsigned)ll[1] << 16);
    ol.y = (unsigned)ll[2] | ((unsigned)ll[3] << 16);
    ol.z = (unsigned)ll[4] | ((unsigned)ll[5] << 16);
    ol.w = (unsigned)ll[6] | ((unsigned)ll[7] << 16);
    *(uint4*)&hiP[(size_t)px * 256 + c8] = oh;
    *(uint4*)&loP[(size_t)px * 256 + c8] = ol;
}

// =====================================================================
// Kernel 3a: COARSE 3x3 conv, split-bf16 MFMA + fused BN-stat atomics.
// R9: row-reuse register caching — per dx, load 6 row-fragments (x2
// planes) once; dy x mt inner loop does 72 MFMAs on them. LDS reads
// halve (72 -> 36 per lane per chunk): MFMA:LDS cycle ratio 1:1 -> 2:1.
// =====================================================================
__global__ __launch_bounds__(256, 3) void conv3x3_wsplit(
    const ushort_t* __restrict__ hiP, const ushort_t* __restrict__ loP,
    const ushort_t* __restrict__ wfrag,
    float* __restrict__ out, float* __restrict__ chsum,
    int CIP, int CO, int H, int W, int tilesX)
{
    __shared__ ushort_t actH[18 * 18 * 36];   // 23328 B
    __shared__ ushort_t actL[18 * 18 * 36];   // 23328 B
    __shared__ float smS[4][2][16], smQ[4][2][16];   // 1 KB

    const int nch = CIP >> 5;
    const int tid = threadIdx.x;
    const int tile = blockIdx.x;
    const int b = blockIdx.y;
    const int cog = blockIdx.z;
    const int ty = (tile / tilesX) * 16;
    const int tx = (tile % tilesX) * 16;
    const int wv = tid >> 6;
    const int ln = tid & 63;
    const int lm = ln & 15;
    const int q8 = (ln >> 4) * 8;

    v4f acc[4][2];
#pragma unroll
    for (int i = 0; i < 4; ++i)
#pragma unroll
        for (int j = 0; j < 2; ++j) acc[i][j] = (v4f)(0.f);

    for (int ch = 0; ch < nch; ++ch) {
        const int ci0 = ch << 5;
        __syncthreads();
        for (int p = tid; p < 2592; p += 256) {
            const int pl = (p >= 1296) ? 1 : 0;
            const int r = p - pl * 1296;
            const int yy = r / 72;
            const int rem = r - yy * 72;
            const int xx = rem >> 2;
            const int cs = (rem & 3) << 3;
            const int gy = ty + yy - 1, gx = tx + xx - 1;
            uint4 val = make_uint4(0u, 0u, 0u, 0u);
            if (gy >= 0 && gy < H && gx >= 0 && gx < W) {
                const ushort_t* src = pl ? loP : hiP;
                val = *(const uint4*)&src[(((size_t)(b * H + gy)) * W + gx) * CIP + ci0 + cs];
            }
            ushort_t* dst = pl ? actL : actH;
            *(uint4*)&dst[(yy * 18 + xx) * 36 + cs] = val;
        }
        __syncthreads();

#pragma unroll
        for (int dx = 0; dx < 3; ++dx) {
            // cache 6 row-fragments (rows wv*4 .. wv*4+5 of the halo tile)
            v8s ah[6], al[6];
#pragma unroll
            for (int rr = 0; rr < 6; ++rr) {
                const int aoff = ((wv * 4 + rr) * 18 + lm + dx) * 36 + q8;
                ah[rr] = *(const v8s*)&actH[aoff];
                al[rr] = *(const v8s*)&actL[aoff];
            }
#pragma unroll
            for (int dy = 0; dy < 3; ++dy) {
                const int k = dy * 3 + dx;
                const size_t fb = (((size_t)(cog * 9 + k) * 4) * nch + ch) * 64 + ln;
                const size_t step = (size_t)nch * 64;
                const v8s bh0 = *(const v8s*)&wfrag[fb * 8];
                const v8s bl0 = *(const v8s*)&wfrag[(fb + step) * 8];
                const v8s bh1 = *(const v8s*)&wfrag[(fb + 2 * step) * 8];
                const v8s bl1 = *(const v8s*)&wfrag[(fb + 3 * step) * 8];
#pragma unroll
                for (int mt = 0; mt < 4; ++mt) {
                    const v8s a_h = ah[mt + dy];
                    const v8s a_l = al[mt + dy];
                    acc[mt][0] = __builtin_amdgcn_mfma_f32_16x16x32_bf16(a_h, bl0, acc[mt][0], 0, 0, 0);
                    acc[mt][0] = __builtin_amdgcn_mfma_f32_16x16x32_bf16(a_l, bh0, acc[mt][0], 0, 0, 0);
                    acc[mt][0] = __builtin_amdgcn_mfma_f32_16x16x32_bf16(a_h, bh0, acc[mt][0], 0, 0, 0);
                    acc[mt][1] = __builtin_amdgcn_mfma_f32_16x16x32_bf16(a_h, bl1, acc[mt][1], 0, 0, 0);
                    acc[mt][1] = __builtin_amdgcn_mfma_f32_16x16x32_bf16(a_l, bh1, acc[mt][1], 0, 0, 0);
                    acc[mt][1] = __builtin_amdgcn_mfma_f32_16x16x32_bf16(a_h, bh1, acc[mt][1], 0, 0, 0);
                }
            }
        }
    }

    // D layout: col(n=co)=ln&15, row(m=x)=(ln>>4)*4+i
#pragma unroll
    for (int mt = 0; mt < 4; ++mt) {
        const int y = ty + wv * 4 + mt;
#pragma unroll
        for (int nt = 0; nt < 2; ++nt) {
            const int co = cog * 32 + nt * 16 + lm;
#pragma unroll
            for (int i = 0; i < 4; ++i) {
                const int x = tx + ((ln >> 4) << 2) + i;
                out[(((size_t)(b * H + y)) * W + x) * CO + co] = acc[mt][nt][i];
            }
        }
    }

    // ---- fused BN-stat partial sums (per-channel sum & sumsq) ----
    float s0 = 0.f, s1 = 0.f, q0 = 0.f, q1 = 0.f;
#pragma unroll
    for (int mt = 0; mt < 4; ++mt)
#pragma unroll
        for (int i = 0; i < 4; ++i) {
            float v = acc[mt][0][i]; s0 += v; q0 += v * v;
            v = acc[mt][1][i]; s1 += v; q1 += v * v;
        }
    s0 += __shfl_xor(s0, 16); s0 += __shfl_xor(s0, 32);
    s1 += __shfl_xor(s1, 16); s1 += __shfl_xor(s1, 32);
    q0 += __shfl_xor(q0, 16); q0 += __shfl_xor(q0, 32);
    q1 += __shfl_xor(q1, 16); q1 += __shfl_xor(q1, 32);
    __syncthreads();
    if (ln < 16) {
        smS[wv][0][ln] = s0; smS[wv][1][ln] = s1;
        smQ[wv][0][ln] = q0; smQ[wv][1][ln] = q1;
    }
    __syncthreads();
    if (tid < 32) {
        const int nt = tid >> 4, l2 = tid & 15;
        float S = 0.f, Q = 0.f;
        for (int w = 0; w < 4; ++w) { S += smS[w][nt][l2]; Q += smQ[w][nt][l2]; }
        const int co = cog * 32 + nt * 16 + l2;
        atomicAdd(&chsum[2 * co], S);
        atomicAdd(&chsum[2 * co + 1], Q);
    }
}

// =====================================================================
// Kernel 3b: FINE 3x3 conv, single-bf16 MFMA + fused BN-stat atomics.
// R9: same row-reuse register caching (LDS reads 36 -> 18 per chunk).
// =====================================================================
template <bool BN>
__global__ __launch_bounds__(256) void conv3x3_mfma(
    const ushort_t* __restrict__ in,
    const ushort_t* __restrict__ wp,   // [9][CO][CI] bf16
    const float2* __restrict__ stats,
    ushort_t* __restrict__ out, float* __restrict__ chsum,
    int CI, int CO, int H, int W, int tilesX)
{
    __shared__ ushort_t act[18 * 18 * 40];
    __shared__ ushort_t wbuf[9 * 32 * 40];
    __shared__ float2 st[256];
    __shared__ float smS[4][2][16], smQ[4][2][16];

    const int tid = threadIdx.x;
    const int tile = blockIdx.x;
    const int b = blockIdx.y;
    const int cog = blockIdx.z;
    const int ty = (tile / tilesX) * 16;
    const int tx = (tile % tilesX) * 16;
    const int wv = tid >> 6;
    const int ln = tid & 63;
    const int lm = ln & 15;
    const int q8 = (ln >> 4) * 8;

    if (BN) for (int c = tid; c < CI; c += 256) st[c] = stats[c];

    v4f acc[4][2];
#pragma unroll
    for (int i = 0; i < 4; ++i)
#pragma unroll
        for (int j = 0; j < 2; ++j) acc[i][j] = (v4f)(0.f);

    const int nChunks = CI >> 5;
    for (int ch = 0; ch < nChunks; ++ch) {
        const int ci0 = ch << 5;
        __syncthreads();
        for (int p = tid; p < 1296; p += 256) {
            const int yy = p / 72;
            const int rem = p - yy * 72;
            const int xx = rem >> 2;
            const int cs = (rem & 3) << 3;
            const int gy = ty + yy - 1, gx = tx + xx - 1;
            uint4 val = make_uint4(0u, 0u, 0u, 0u);
            if (gy >= 0 && gy < H && gx >= 0 && gx < W) {
                const ushort_t* gp = in + (((size_t)(b * H + gy)) * W + gx) * CI + ci0 + cs;
                val = *(const uint4*)gp;
                if (BN) {
                    unsigned u[4] = {val.x, val.y, val.z, val.w};
                    unsigned o[4];
#pragma unroll
                    for (int e = 0; e < 4; ++e) {
                        float lo = bfbits2f(u[e] & 0xffffu);
                        float hi = bfbits2f(u[e] >> 16);
                        const float2 s0 = st[ci0 + cs + 2 * e];
                        const float2 s1 = st[ci0 + cs + 2 * e + 1];
                        lo = fmaxf((lo - s0.x) * s0.y, 0.f);
                        hi = fmaxf((hi - s1.x) * s1.y, 0.f);
                        o[e] = (unsigned)f2bfbits(lo) | ((unsigned)f2bfbits(hi) << 16);
                    }
                    val = make_uint4(o[0], o[1], o[2], o[3]);
                }
            }
            *(uint4*)&act[(yy * 18 + xx) * 40 + cs] = val;
        }
        for (int p = tid; p < 1152; p += 256) {
            const int k = p / 128;
            const int rem = p - k * 128;
            const int co = rem >> 2;
            const int cs = (rem & 3) << 3;
            const ushort_t* gp = wp + ((size_t)k * CO + cog * 32 + co) * CI + ci0 + cs;
            *(uint4*)&wbuf[(k * 32 + co) * 40 + cs] = *(const uint4*)gp;
        }
        __syncthreads();

#pragma unroll
        for (int dx = 0; dx < 3; ++dx) {
            v8s af[6];
#pragma unroll
            for (int rr = 0; rr < 6; ++rr)
                af[rr] = *(const v8s*)&act[((wv * 4 + rr) * 18 + lm + dx) * 40 + q8];
#pragma unroll
            for (int dy = 0; dy < 3; ++dy) {
                const int k = dy * 3 + dx;
                const v8s bf0 = *(const v8s*)&wbuf[(k * 32 + lm) * 40 + q8];
                const v8s bf1 = *(const v8s*)&wbuf[(k * 32 + 16 + lm) * 40 + q8];
#pragma unroll
                for (int mt = 0; mt < 4; ++mt) {
                    acc[mt][0] = __builtin_amdgcn_mfma_f32_16x16x32_bf16(af[mt + dy], bf0, acc[mt][0], 0, 0, 0);
                    acc[mt][1] = __builtin_amdgcn_mfma_f32_16x16x32_bf16(af[mt + dy], bf1, acc[mt][1], 0, 0, 0);
                }
            }
        }
    }

#pragma unroll
    for (int mt = 0; mt < 4; ++mt) {
        const int y = ty + wv * 4 + mt;
#pragma unroll
        for (int nt = 0; nt < 2; ++nt) {
            const int co = cog * 32 + nt * 16 + lm;
#pragma unroll
            for (int i = 0; i < 4; ++i) {
                const int x = tx + ((ln >> 4) << 2) + i;
                out[(((size_t)(b * H + y)) * W + x) * CO + co] = f2bfbits(acc[mt][nt][i]);
            }
        }
    }

    // ---- fused BN-stat partial sums ----
    float s0 = 0.f, s1 = 0.f, q0 = 0.f, q1 = 0.f;
#pragma unroll
    for (int mt = 0; mt < 4; ++mt)
#pragma unroll
        for (int i = 0; i < 4; ++i) {
            float v = acc[mt][0][i]; s0 += v; q0 += v * v;
            v = acc[mt][1][i]; s1 += v; q1 += v * v;
        }
    s0 += __shfl_xor(s0, 16); s0 += __shfl_xor(s0, 32);
    s1 += __shfl_xor(s1, 16); s1 += __shfl_xor(s1, 32);
    q0 += __shfl_xor(q0, 16); q0 += __shfl_xor(q0, 32);
    q1 += __shfl_xor(q1, 16); q1 += __shfl_xor(q1, 32);
    __syncthreads();
    if (ln < 16) {
        smS[wv][0][ln] = s0; smS[wv][1][ln] = s1;
        smQ[wv][0][ln] = q0; smQ[wv][1][ln] = q1;
    }
    __syncthreads();
    if (tid < 32) {
        const int nt = tid >> 4, l2 = tid & 15;
        float S = 0.f, Q = 0.f;
        for (int w = 0; w < 4; ++w) { S += smS[w][nt][l2]; Q += smQ[w][nt][l2]; }
        const int co = cog * 32 + nt * 16 + l2;
        atomicAdd(&chsum[2 * co], S);
        atomicAdd(&chsum[2 * co + 1], Q);
    }
}

// =====================================================================
// stats finalize: (sum, sumsq) -> (mean, rsqrt(var+eps))
// =====================================================================
__global__ void stats_finalize_kernel(const float* __restrict__ chsum,
                                      float2* __restrict__ st, int C, float inv_n)
{
    const int c = threadIdx.x;
    if (c >= C) return;
    const float mean = chsum[2 * c] * inv_n;
    const float var = chsum[2 * c + 1] * inv_n - mean * mean;
    st[c] = make_float2(mean, 1.0f / sqrtf(var + 1e-5f));
}

// =====================================================================
// Kernel 5: coarse head (fp32 NHWC): 1x1 conv 256->3 + bias + cm0
// =====================================================================
__global__ __launch_bounds__(256) void coarse_head_kernel(
    const float* __restrict__ A, const float2* __restrict__ stats,
    const void* __restrict__ w5, const void* __restrict__ b5,
    float* __restrict__ cm0, void* __restrict__ out,
    const int* __restrict__ dflag)
{
    const int f32 = *dflag;
    __shared__ float wl[3][256];
    __shared__ float bl[3];
    __shared__ float2 st[256];
    const int tid = threadIdx.x;
    for (int i = tid; i < 768; i += 256) wl[i >> 8][i & 255] = ldin(w5, i, f32);
    if (tid < 3) bl[tid] = ldin(b5, tid, f32);
    st[tid] = stats[tid];
    __syncthreads();

    const int idx = blockIdx.x * 256 + tid;
    const int b = idx >> 12, hw = idx & (JC - 1);
    float a0 = bl[0], a1 = bl[1], a2 = bl[2];
    const float* p = A + (size_t)idx * 256;
    for (int c = 0; c < 256; c += 4) {
        const float4 raw = *(const float4*)(p + c);
        const float rv[4] = {raw.x, raw.y, raw.z, raw.w};
#pragma unroll
        for (int e = 0; e < 4; ++e) {
            const int cc = c + e;
            const float v = fmaxf((rv[e] - st[cc].x) * st[cc].y, 0.f);
            a0 += v * wl[0][cc]; a1 += v * wl[1][cc]; a2 += v * wl[2][cc];
        }
    }
    const size_t base = (size_t)b * 3 * JC + hw;
    const float c0 = cm0[base] + a0;
    const float c1 = cm0[base + JC] + a1;
    const float c2 = cm0[base + 2 * JC] + a2;
    cm0[base] = c0; cm0[base + JC] = c1; cm0[base + 2 * JC] = c2;
    stout(out, base, c0, f32);
    stout(out, base + JC, c1, f32);
    stout(out, base + 2 * JC, c2, f32);
}

// =====================================================================
// Kernel 6: bilinear 2x upsample (half-pixel, edge clamp)
// =====================================================================
__global__ __launch_bounds__(256) void upsample_kernel(
    const float* __restrict__ cm, float* __restrict__ up)
{
    const int idx = blockIdx.x * 256 + threadIdx.x;
    const int ox = idx & 127, oy = (idx >> 7) & 127, bc = idx >> 14;
    const float sx = ox * 0.5f - 0.25f;
    const float sy = oy * 0.5f - 0.25f;
    const int x0 = (int)floorf(sx), y0 = (int)floorf(sy);
    const float fx = sx - x0, fy = sy - y0;
    const int cx0 = max(x0, 0), cx1 = min(x0 + 1, WC - 1);
    const int cy0 = max(y0, 0), cy1 = min(y0 + 1, HC - 1);
    const float* p = cm + (size_t)bc * JC;
    const float v = (1.f - fy) * ((1.f - fx) * p[cy0 * WC + cx0] + fx * p[cy0 * WC + cx1])
                  + fy * ((1.f - fx) * p[cy1 * WC + cx0] + fx * p[cy1 * WC + cx1]);
    up[idx] = v;
}

// =====================================================================
// Kernel 7: fine concat -> NHWC bf16 [b][y][x][64] (50 real + 14 zero)
// =====================================================================
__global__ __launch_bounds__(256) void fine_concat_nhwc(
    const void* __restrict__ f0f, const void* __restrict__ f1f,
    const float* __restrict__ up, ushort_t* __restrict__ A,
    const int* __restrict__ dflag)
{
    const int f32 = *dflag;
    const int idx = blockIdx.x * 256 + threadIdx.x;   // B*JF
    const int b = idx >> 14, hw = idx & (JF - 1);
    const size_t ib = (size_t)b * CF * JF;
    ushort_t* o = A + (size_t)idx * 64;

    for (int c = 0; c < CF; ++c)
        o[c] = f2bfbits(ldin(f0f, ib + (size_t)c * JF + hw, f32));

    const size_t ub = (size_t)b * 3 * JF + hw;
    const float gx = up[ub], gy = up[ub + JF];
    const float x = (gx + 1.f) * 64.f - 0.5f;
    const float y = (gy + 1.f) * 64.f - 0.5f;
    const float x0f = floorf(x), y0f = floorf(y);
    const float wx = x - x0f, wy = y - y0f;
    const int x0 = (int)x0f, y0 = (int)y0f;
    const int x1 = x0 + 1, y1 = y0 + 1;
    const float vx0 = (x0 >= 0 && x0 < WF) ? 1.f : 0.f;
    const float vx1 = (x1 >= 0 && x1 < WF) ? 1.f : 0.f;
    const float vy0 = (y0 >= 0 && y0 < HF) ? 1.f : 0.f;
    const float vy1 = (y1 >= 0 && y1 < HF) ? 1.f : 0.f;
    const int cx0 = min(max(x0, 0), WF - 1), cx1 = min(max(x1, 0), WF - 1);
    const int cy0 = min(max(y0, 0), HF - 1), cy1 = min(max(y1, 0), HF - 1);
    const float w00 = (1.f - wx) * (1.f - wy) * vx0 * vy0;
    const float w01 = wx * (1.f - wy) * vx1 * vy0;
    const float w10 = (1.f - wx) * wy * vx0 * vy1;
    const float w11 = wx * wy * vx1 * vy1;
    const int i00 = cy0 * WF + cx0, i01 = cy0 * WF + cx1;
    const int i10 = cy1 * WF + cx0, i11 = cy1 * WF + cx1;

    for (int c = 0; c < CF; ++c) {
        const size_t pb = ib + (size_t)c * JF;
        const float v = w00 * ldin(f1f, pb + i00, f32) + w01 * ldin(f1f, pb + i01, f32)
                      + w10 * ldin(f1f, pb + i10, f32) + w11 * ldin(f1f, pb + i11, f32);
        o[24 + c] = f2bfbits(v);
    }
    o[48] = f2bfbits(gx);
    o[49] = f2bfbits(gy);
    for (int c = 50; c < 64; ++c) o[c] = 0;
}

// =====================================================================
// Kernel 8: fine head (NHWC bf16): 1x1 conv 64->3 + bias + up -> out1
// =====================================================================
__global__ __launch_bounds__(256) void fine_head_kernel(
    const ushort_t* __restrict__ A, const float2* __restrict__ stats,
    const void* __restrict__ w5, const void* __restrict__ b5,
    const float* __restrict__ up, void* __restrict__ out,
    const int* __restrict__ dflag)
{
    const int f32 = *dflag;
    __shared__ float wl[3][64];
    __shared__ float bl[3];
    __shared__ float2 st[64];
    const int tid = threadIdx.x;
    if (tid < 192) wl[tid >> 6][tid & 63] = ldin(w5, tid, f32);
    if (tid < 3) bl[tid] = ldin(b5, tid, f32);
    if (tid < 64) st[tid] = stats[tid];
    __syncthreads();

    const int idx = blockIdx.x * 256 + tid;
    const int b = idx >> 14, hw = idx & (JF - 1);
    float a0 = bl[0], a1 = bl[1], a2 = bl[2];
    const ushort_t* p = A + (size_t)idx * 64;
    for (int c = 0; c < 64; c += 8) {
        const uint4 raw = *(const uint4*)(p + c);
        const unsigned u[4] = {raw.x, raw.y, raw.z, raw.w};
#pragma unroll
        for (int e = 0; e < 4; ++e) {
            const int c0 = c + 2 * e, c1 = c0 + 1;
            float lo = bfbits2f(u[e] & 0xffffu);
            float hi = bfbits2f(u[e] >> 16);
            lo = fmaxf((lo - st[c0].x) * st[c0].y, 0.f);
            hi = fmaxf((hi - st[c1].x) * st[c1].y, 0.f);
            a0 += lo * wl[0][c0] + hi * wl[0][c1];
            a1 += lo * wl[1][c0] + hi * wl[1][c1];
            a2 += lo * wl[2][c0] + hi * wl[2][c1];
        }
    }
    const size_t base = (size_t)b * 3 * JF + hw;
    stout(out, OUT0_ELEMS + base,          up[base] + a0, f32);
    stout(out, OUT0_ELEMS + base + JF,     up[base + JF] + a1, f32);
    stout(out, OUT0_ELEMS + base + 2 * JF, up[base + 2 * JF] + a2, f32);
}

// =====================================================================
extern "C" void kernel_launch(void* const* d_in, const int* in_sizes, int n_in,
                              void* d_out, int out_size, void* d_ws, size_t ws_size,
                              hipStream_t stream)
{
    const void* f0c = d_in[0];
    const void* f1c = d_in[1];
    const void* f0f = d_in[2];
    const void* f1f = d_in[3];
    const void* cw1 = d_in[4];
    const void* cw2 = d_in[5];
    const void* cw3 = d_in[6];
    const void* cw4 = d_in[7];
    const void* cw5 = d_in[8];
    const void* cb5 = d_in[9];
    const void* fw1 = d_in[10];
    const void* fw2 = d_in[11];
    const void* fw3 = d_in[12];
    const void* fw4 = d_in[13];
    const void* fw5 = d_in[14];
    const void* fb5 = d_in[15];

    // ---- workspace layout (same proven footprint as R8) ----
    char* wsb = (char*)d_ws;
    float* bufA    = (float*)wsb;                       // 16 MiB
    float* bufB    = (float*)(wsb + 16777216);          // 16 MiB
    float* cm0     = (float*)(wsb + 33554432);          // 196,608 B
    float* up      = (float*)(wsb + 33751040);          // 786,432 B
    float* chsum   = (float*)(wsb + 34537472);          // 2,048 B
    float2* st_g   = (float2*)(wsb + 34668544);         // 2,048 B
    int* dflag     = (int*)(wsb + 34670592);            // 64 B
    ushort_t* fwp  = (ushort_t*)(wsb + 34670656);       // 294,912 B
    ushort_t* fw1p = fwp;
    ushort_t* fw2p = fwp + 36864;
    ushort_t* fw3p = fwp + 73728;
    ushort_t* fw4p = fwp + 110592;
    ushort_t* wfrag = (ushort_t*)(wsb + 34965568);      // up to 9,437,184 B

    // split activation planes: hi = bufA[0..8MB), lo = bufA[8..16MB)
    ushort_t* hiP = (ushort_t*)bufA;
    ushort_t* loP = (ushort_t*)(wsb + 8388608);

    // corr split Q/K planes in bufA's first 8 MB (dead before concat)
    ushort_t* qhi = (ushort_t*)bufA;
    ushort_t* qlo = qhi + 1048576;
    ushort_t* khi = qlo + 1048576;
    ushort_t* klo = khi + 1048576;
    float* cpart = (float*)bufB;   // 1 MB corr partials (bufB dead during corr)

    ushort_t* fF1 = (ushort_t*)bufB;   // fine ping
    ushort_t* fF2 = (ushort_t*)bufA;   // fine pong

    // 0. dtype probe
    dtype_probe_kernel<<<1, 256, 0, stream>>>((const ushort_t*)f0c, dflag);

    // fine weight repacks (bf16 [k][co][ci_pad])
    repack_w_kernel<<<(9 * 64 * 64 + 255) / 256, 256, 0, stream>>>(fw1, fw1p, 64, 50, 64, dflag);
    repack_w_kernel<<<(9 * 64 * 64 + 255) / 256, 256, 0, stream>>>(fw2, fw2p, 64, 64, 64, dflag);
    repack_w_kernel<<<(9 * 64 * 64 + 255) / 256, 256, 0, stream>>>(fw3, fw3p, 64, 64, 64, dflag);
    repack_w_kernel<<<(9 * 64 * 64 + 255) / 256, 256, 0, stream>>>(fw4, fw4p, 64, 64, 64, dflag);

    // 1. correlation: split-transpose Q/K, split-K MFMA, reduce
    split_transpose_kernel<<<dim3(B_ * 64), 256, 0, stream>>>(f0c, qhi, qlo, dflag);
    split_transpose_kernel<<<dim3(B_ * 64), 256, 0, stream>>>(f1c, khi, klo, dflag);
    corr_mfma_kernel<<<dim3(HC, B_, 4), 256, 0, stream>>>(qhi, qlo, khi, klo, cpart);
    corr_reduce_kernel<<<dim3(B_ * JC / 256), 256, 0, stream>>>(cpart, cm0);

    // 2. coarse concat -> split planes (CIP=160); overwrites q/k (dead)
    coarse_concat_split<<<dim3(B_ * JC / 256), 256, 0, stream>>>(f0c, f1c, cm0, hiP, loP, dflag);

    // 3. coarse conv stack: fragment-weight split-bf16 MFMA, fused stats
    const dim3 cgrid(16, B_, 8);
    repack_wfrag_kernel<<<(8 * 9 * 2 * 2 * 5 * 64 + 255) / 256, 256, 0, stream>>>(cw1, wfrag, 130, 5, dflag);
    hipMemsetAsync(chsum, 0, 2048, stream);
    conv3x3_wsplit<<<cgrid, 256, 0, stream>>>(hiP, loP, wfrag, bufB, chsum, 160, 256, HC, WC, 4);
    stats_finalize_kernel<<<1, 256, 0, stream>>>(chsum, st_g, 256, 1.f / 16384.f);

    bnrelu_split_kernel<<<B_ * JC * 32 / 256, 256, 0, stream>>>(bufB, st_g, hiP, loP);
    repack_wfrag_kernel<<<(8 * 9 * 2 * 2 * 8 * 64 + 255) / 256, 256, 0, stream>>>(cw2, wfrag, 256, 8, dflag);
    hipMemsetAsync(chsum, 0, 2048, stream);
    conv3x3_wsplit<<<cgrid, 256, 0, stream>>>(hiP, loP, wfrag, bufB, chsum, 256, 256, HC, WC, 4);
    stats_finalize_kernel<<<1, 256, 0, stream>>>(chsum, st_g, 256, 1.f / 16384.f);

    bnrelu_split_kernel<<<B_ * JC * 32 / 256, 256, 0, stream>>>(bufB, st_g, hiP, loP);
    repack_wfrag_kernel<<<(8 * 9 * 2 * 2 * 8 * 64 + 255) / 256, 256, 0, stream>>>(cw3, wfrag, 256, 8, dflag);
    hipMemsetAsync(chsum, 0, 2048, stream);
    conv3x3_wsplit<<<cgrid, 256, 0, stream>>>(hiP, loP, wfrag, bufB, chsum, 256, 256, HC, WC, 4);
    stats_finalize_kernel<<<1, 256, 0, stream>>>(chsum, st_g, 256, 1.f / 16384.f);

    bnrelu_split_kernel<<<B_ * JC * 32 / 256, 256, 0, stream>>>(bufB, st_g, hiP, loP);
    repack_wfrag_kernel<<<(8 * 9 * 2 * 2 * 8 * 64 + 255) / 256, 256, 0, stream>>>(cw4, wfrag, 256, 8, dflag);
    hipMemsetAsync(chsum, 0, 2048, stream);
    conv3x3_wsplit<<<cgrid, 256, 0, stream>>>(hiP, loP, wfrag, bufB, chsum, 256, 256, HC, WC, 4);
    stats_finalize_kernel<<<1, 256, 0, stream>>>(chsum, st_g, 256, 1.f / 16384.f);

    // 4. coarse head -> out0, cmatch (in place over cm0)
    coarse_head_kernel<<<dim3(B_ * JC / 256), 256, 0, stream>>>(bufB, st_g, cw5, cb5, cm0, d_out, dflag);

    // 5. upsample (cm0 now holds cmatch)
    upsample_kernel<<<dim3(B_ * 3 * JF / 256), 256, 0, stream>>>(cm0, up);

    // 6. fine concat -> fF1 (bufB region; conv4 raw dead after head)
    fine_concat_nhwc<<<dim3(B_ * JF / 256), 256, 0, stream>>>(f0f, f1f, up, fF1, dflag);

    // 7. fine conv stack (bf16 MFMA, fused stats)
    const dim3 fgrid(64, B_, 2);
    hipMemsetAsync(chsum, 0, 512, stream);
    conv3x3_mfma<false><<<fgrid, 256, 0, stream>>>(fF1, fw1p, nullptr, fF2, chsum, 64, 64, HF, WF, 8);
    stats_finalize_kernel<<<1, 256, 0, stream>>>(chsum, st_g, 64, 1.f / 65536.f);
    hipMemsetAsync(chsum, 0, 512, stream);
    conv3x3_mfma<true><<<fgrid, 256, 0, stream>>>(fF2, fw2p, st_g, fF1, chsum, 64, 64, HF, WF, 8);
    stats_finalize_kernel<<<1, 256, 0, stream>>>(chsum, st_g, 64, 1.f / 65536.f);
    hipMemsetAsync(chsum, 0, 512, stream);
    conv3x3_mfma<true><<<fgrid, 256, 0, stream>>>(fF1, fw3p, st_g, fF2, chsum, 64, 64, HF, WF, 8);
    stats_finalize_kernel<<<1, 256, 0, stream>>>(chsum, st_g, 64, 1.f / 65536.f);
    hipMemsetAsync(chsum, 0, 512, stream);
    conv3x3_mfma<true><<<fgrid, 256, 0, stream>>>(fF2, fw4p, st_g, fF1, chsum, 64, 64, HF, WF, 8);
    stats_finalize_kernel<<<1, 256, 0, stream>>>(chsum, st_g, 64, 1.f / 65536.f);

    // 8. fine head -> out1
    fine_head_kernel<<<dim3(B_ * JF / 256), 256, 0, stream>>>(fF1, st_g, fw5, fb5, up, d_out, dflag);
}

// Round 11
// 805.239 us; speedup vs baseline: 6.1163x; 1.0008x over previous
//
#include <hip/hip_runtime.h>
#include <hip/hip_bf16.h>

using bf16 = __hip_bfloat16;
typedef unsigned short ushort_t;
typedef __attribute__((ext_vector_type(8))) short v8s;
typedef __attribute__((ext_vector_type(4))) float v4f;

__device__ __forceinline__ float bfbits2f(unsigned u) {
    return __uint_as_float(u << 16);
}
__device__ __forceinline__ ushort_t f2bfbits(float f) {
    unsigned x = __float_as_uint(f);
    return (ushort_t)((x + 0x7fffu + ((x >> 16) & 1u)) >> 16);
}
// dtype-adaptive input load / output store (flag: 1 = fp32 buffers, 0 = bf16)
__device__ __forceinline__ float ldin(const void* p, size_t i, int f32) {
    return f32 ? ((const float*)p)[i] : bfbits2f(((const ushort_t*)p)[i]);
}
__device__ __forceinline__ void stout(void* p, size_t i, float v, int f32) {
    if (f32) ((float*)p)[i] = v;
    else     ((ushort_t*)p)[i] = f2bfbits(v);
}

// ---------------- sizes ----------------
#define B_   4
#define CC   64
#define HC   64
#define WC   64
#define JC   4096
#define CF   24
#define HF   128
#define WF   128
#define JF   16384
#define OUT0_ELEMS (B_ * 3 * JC)

// =====================================================================
// Kernel 0: dtype probe. flag=1 -> fp32 inputs (R3: confirmed fp32).
// =====================================================================
__global__ void dtype_probe_kernel(const ushort_t* __restrict__ x,
                                   int* __restrict__ flag)
{
    __shared__ int cnt;
    if (threadIdx.x == 0) cnt = 0;
    __syncthreads();
    int c = 0;
    for (int i = threadIdx.x; i < 8192; i += 256) {
        const unsigned e = (x[i] >> 7) & 0xFF;
        if (e >= 0x89) ++c;
    }
    atomicAdd(&cnt, c);
    __syncthreads();
    if (threadIdx.x == 0) *flag = (cnt > 64) ? 1 : 0;
}

// =====================================================================
// Fine weight repack: w[co][ci][3][3] -> wp[k][co][ci_pad] bf16
// =====================================================================
__global__ void repack_w_kernel(const void* __restrict__ w, ushort_t* __restrict__ wp,
                                int CO, int CIreal, int CIP, const int* __restrict__ dflag)
{
    const int f32 = *dflag;
    const int idx = blockIdx.x * 256 + threadIdx.x;
    const int total = 9 * CO * CIP;
    if (idx >= total) return;
    const int k = idx / (CO * CIP);
    const int rem = idx - k * (CO * CIP);
    const int co = rem / CIP;
    const int cip = rem - co * CIP;
    float v = 0.f;
    if (cip < CIreal) v = ldin(w, ((size_t)co * CIreal + cip) * 9 + k, f32);
    wp[((size_t)k * CO + co) * CIP + cip] = f2bfbits(v);
}

// =====================================================================
// Coarse weight repack into MFMA FRAGMENT order, split hi/lo.
// =====================================================================
__global__ void repack_wfrag_kernel(const void* __restrict__ w, ushort_t* __restrict__ wfrag,
                                    int CIreal, int nch, const int* __restrict__ dflag)
{
    const int f32 = *dflag;
    const int idx = blockIdx.x * 256 + threadIdx.x;
    const int total = 8 * 9 * 2 * 2 * nch * 64;
    if (idx >= total) return;
    const int ln = idx & 63;
    int t = idx >> 6;
    const int ch = t % nch; t /= nch;
    const int pl = t & 1; t >>= 1;
    const int nt = t & 1; t >>= 1;
    const int k = t % 9;
    const int cog = t / 9;
    const int co = cog * 32 + nt * 16 + (ln & 15);
    const int cib = ch * 32 + (ln >> 4) * 8;
    ushort_t vals[8];
#pragma unroll
    for (int e = 0; e < 8; ++e) {
        const int ci = cib + e;
        float v = 0.f;
        if (ci < CIreal) v = ldin(w, ((size_t)co * CIreal + ci) * 9 + k, f32);
        const ushort_t h = f2bfbits(v);
        vals[e] = pl ? f2bfbits(v - bfbits2f(h)) : h;
    }
    uint4 o;
    o.x = (unsigned)vals[0] | ((unsigned)vals[1] << 16);
    o.y = (unsigned)vals[2] | ((unsigned)vals[3] << 16);
    o.z = (unsigned)vals[4] | ((unsigned)vals[5] << 16);
    o.w = (unsigned)vals[6] | ((unsigned)vals[7] << 16);
    *(uint4*)&wfrag[(size_t)idx * 8] = o;
}

// =====================================================================
// Kernel 1a: split-transpose feats: [b][64ch][4096px] -> [b][4096px][64ch]
// =====================================================================
__global__ __launch_bounds__(256) void split_transpose_kernel(
    const void* __restrict__ src, ushort_t* __restrict__ hi,
    ushort_t* __restrict__ lo, const int* __restrict__ dflag)
{
    const int f32 = *dflag;
    __shared__ float t[64][65];
    const int blk = blockIdx.x;
    const int b = blk >> 6;
    const int px0 = (blk & 63) * 64;
    const int tid = threadIdx.x;
    const int px = tid & 63;
    for (int i = 0; i < 16; ++i) {
        const int c = (tid >> 6) + 4 * i;
        t[px][c] = ldin(src, ((size_t)b * 64 + c) * 4096 + px0 + px, f32);
    }
    __syncthreads();
    for (int it = 0; it < 2; ++it) {
        const int p = tid + it * 256;
        const int opx = p >> 3, chk = (p & 7) * 8;
        unsigned hh[4], ll[4];
#pragma unroll
        for (int e = 0; e < 4; ++e) {
            const float v0 = t[opx][chk + 2 * e];
            const float v1 = t[opx][chk + 2 * e + 1];
            const ushort_t h0 = f2bfbits(v0);
            const ushort_t h1 = f2bfbits(v1);
            hh[e] = (unsigned)h0 | ((unsigned)h1 << 16);
            ll[e] = (unsigned)f2bfbits(v0 - bfbits2f(h0))
                  | ((unsigned)f2bfbits(v1 - bfbits2f(h1)) << 16);
        }
        const size_t obase = ((size_t)b * 4096 + px0 + opx) * 64 + chk;
        *(uint4*)&hi[obase] = make_uint4(hh[0], hh[1], hh[2], hh[3]);
        *(uint4*)&lo[obase] = make_uint4(ll[0], ll[1], ll[2], ll[3]);
    }
}

// =====================================================================
// Kernel 1b: correlation, SPLIT-K: grid (HC, B, 4). Each block: 64 q x
// 1024 keys (8 chunks of 128). Writes unnormalized partials (l, px, py).
// =====================================================================
#define KCH 128
__global__ __launch_bounds__(256) void corr_mfma_kernel(
    const ushort_t* __restrict__ qhi, const ushort_t* __restrict__ qlo,
    const ushort_t* __restrict__ khi, const ushort_t* __restrict__ klo,
    float* __restrict__ part)
{
    __shared__ ushort_t kbh[KCH * 72];
    __shared__ ushort_t kbl[KCH * 72];
    __shared__ float red[4][64][3];
    const int h = blockIdx.x, b = blockIdx.y, sl = blockIdx.z;
    const int tid = threadIdx.x;
    const int wv = tid >> 6, ln = tid & 63;
    const int lm = ln & 15, quad = ln >> 4, q8 = quad * 8;

    v8s qf[4][2][2];
#pragma unroll
    for (int mt = 0; mt < 4; ++mt)
#pragma unroll
        for (int kc = 0; kc < 2; ++kc) {
            const size_t qoff = ((size_t)b * 4096 + h * 64 + mt * 16 + lm) * 64 + kc * 32 + q8;
            qf[mt][kc][0] = *(const v8s*)&qhi[qoff];
            qf[mt][kc][1] = *(const v8s*)&qlo[qoff];
        }

    float P[4][4][3];
#pragma unroll
    for (int mt = 0; mt < 4; ++mt)
#pragma unroll
        for (int i = 0; i < 4; ++i)
            P[mt][i][0] = P[mt][i][1] = P[mt][i][2] = 0.f;

    const size_t kbase = (size_t)b * 4096 * 64;
    for (int c = 0; c < 1024 / KCH; ++c) {
        const int j0 = sl * 1024 + c * KCH;
        __syncthreads();
        for (int p = tid; p < 2048; p += 256) {
            const int pl = p >> 10;
            const int r = p & 1023;
            const int key = r >> 3, chk = (r & 7) * 8;
            const ushort_t* gsrc = pl ? klo : khi;
            const uint4 v = *(const uint4*)&gsrc[kbase + (size_t)(j0 + key) * 64 + chk];
            ushort_t* dst = pl ? kbl : kbh;
            *(uint4*)&dst[key * 72 + chk] = v;
        }
        __syncthreads();

#pragma unroll
        for (int nt = 0; nt < 2; ++nt) {
            const int kb = wv * 32 + nt * 16;
            const int j = j0 + kb + lm;
            const float gx = (float)((j & 63) * 2 + 1) * (1.f / 64.f) - 1.f;
            const float gy = (float)((j >> 6) * 2 + 1) * (1.f / 64.f) - 1.f;
            const v8s bh0 = *(const v8s*)&kbh[(kb + lm) * 72 + q8];
            const v8s bh1 = *(const v8s*)&kbh[(kb + lm) * 72 + 32 + q8];
            const v8s bl0 = *(const v8s*)&kbl[(kb + lm) * 72 + q8];
            const v8s bl1 = *(const v8s*)&kbl[(kb + lm) * 72 + 32 + q8];
#pragma unroll
            for (int mt = 0; mt < 4; ++mt) {
                v4f acc = (v4f)(0.f);
                acc = __builtin_amdgcn_mfma_f32_16x16x32_bf16(qf[mt][0][0], bl0, acc, 0, 0, 0);
                acc = __builtin_amdgcn_mfma_f32_16x16x32_bf16(qf[mt][0][1], bh0, acc, 0, 0, 0);
                acc = __builtin_amdgcn_mfma_f32_16x16x32_bf16(qf[mt][0][0], bh0, acc, 0, 0, 0);
                acc = __builtin_amdgcn_mfma_f32_16x16x32_bf16(qf[mt][1][0], bl1, acc, 0, 0, 0);
                acc = __builtin_amdgcn_mfma_f32_16x16x32_bf16(qf[mt][1][1], bh1, acc, 0, 0, 0);
                acc = __builtin_amdgcn_mfma_f32_16x16x32_bf16(qf[mt][1][0], bh1, acc, 0, 0, 0);
#pragma unroll
                for (int i = 0; i < 4; ++i) {
                    const float p_ = __expf(acc[i] * 0.125f);
                    P[mt][i][0] += p_;
                    P[mt][i][1] += p_ * gx;
                    P[mt][i][2] += p_ * gy;
                }
            }
        }
    }

#pragma unroll
    for (int mt = 0; mt < 4; ++mt)
#pragma unroll
        for (int i = 0; i < 4; ++i)
#pragma unroll
            for (int d = 0; d < 3; ++d) {
                float v = P[mt][i][d];
                v += __shfl_xor(v, 1);
                v += __shfl_xor(v, 2);
                v += __shfl_xor(v, 4);
                v += __shfl_xor(v, 8);
                P[mt][i][d] = v;
            }
    if (lm == 0) {
#pragma unroll
        for (int mt = 0; mt < 4; ++mt)
#pragma unroll
            for (int i = 0; i < 4; ++i) {
                const int q = mt * 16 + quad * 4 + i;
                red[wv][q][0] = P[mt][i][0];
                red[wv][q][1] = P[mt][i][1];
                red[wv][q][2] = P[mt][i][2];
            }
    }
    __syncthreads();
    if (tid < 64) {
        const int q = tid;
        float l = 0.f, ax = 0.f, ay = 0.f;
        for (int w = 0; w < 4; ++w) {
            l += red[w][q][0]; ax += red[w][q][1]; ay += red[w][q][2];
        }
        const size_t base = (((size_t)sl * B_ + b) * 4096 + h * 64 + q) * 4;
        part[base] = l; part[base + 1] = ax; part[base + 2] = ay;
    }
}

// =====================================================================
// Kernel 1c: merge split-K partials -> cm0 (deterministic)
// =====================================================================
__global__ __launch_bounds__(256) void corr_reduce_kernel(
    const float* __restrict__ part, float* __restrict__ cm0)
{
    const int idx = blockIdx.x * 256 + threadIdx.x;   // B*JC
    const int b = idx >> 12, hq = idx & 4095;
    float l = 0.f, ax = 0.f, ay = 0.f;
    for (int s = 0; s < 4; ++s) {
        const size_t base = (((size_t)s * B_ + b) * 4096 + hq) * 4;
        l += part[base]; ax += part[base + 1]; ay += part[base + 2];
    }
    const float inv = 1.f / l;
    const size_t o = (size_t)b * 3 * JC + hq;
    cm0[o]          = ax * inv;
    cm0[o + JC]     = ay * inv;
    cm0[o + 2 * JC] = 0.f;
}

// =====================================================================
// Kernel 2: coarse concat -> SPLIT hi/lo bf16 NHWC planes [b][px][160]
// =====================================================================
__global__ __launch_bounds__(256) void coarse_concat_split(
    const void* __restrict__ f0c, const void* __restrict__ f1c,
    const float* __restrict__ cm0, ushort_t* __restrict__ hiP,
    ushort_t* __restrict__ loP, const int* __restrict__ dflag)
{
    const int f32 = *dflag;
    const int idx = blockIdx.x * 256 + threadIdx.x;   // B*JC
    const int b = idx >> 12, hw = idx & (JC - 1);
    const size_t ib = (size_t)b * CC * JC;
    ushort_t* oh = hiP + (size_t)idx * 160;
    ushort_t* ol = loP + (size_t)idx * 160;

#pragma unroll 4
    for (int c = 0; c < CC; ++c) {
        const float v = ldin(f0c, ib + (size_t)c * JC + hw, f32);
        const ushort_t h = f2bfbits(v);
        oh[c] = h; ol[c] = f2bfbits(v - bfbits2f(h));
    }

    const float gx = cm0[((size_t)b * 3 + 0) * JC + hw];
    const float gy = cm0[((size_t)b * 3 + 1) * JC + hw];
    const float x = (gx + 1.f) * 32.f - 0.5f;
    const float y = (gy + 1.f) * 32.f - 0.5f;
    const float x0f = floorf(x), y0f = floorf(y);
    const float wx = x - x0f, wy = y - y0f;
    const int x0 = (int)x0f, y0 = (int)y0f;
    const int x1 = x0 + 1, y1 = y0 + 1;
    const float vx0 = (x0 >= 0 && x0 < WC) ? 1.f : 0.f;
    const float vx1 = (x1 >= 0 && x1 < WC) ? 1.f : 0.f;
    const float vy0 = (y0 >= 0 && y0 < HC) ? 1.f : 0.f;
    const float vy1 = (y1 >= 0 && y1 < HC) ? 1.f : 0.f;
    const int cx0 = min(max(x0, 0), WC - 1), cx1 = min(max(x1, 0), WC - 1);
    const int cy0 = min(max(y0, 0), HC - 1), cy1 = min(max(y1, 0), HC - 1);
    const float w00 = (1.f - wx) * (1.f - wy) * vx0 * vy0;
    const float w01 = wx * (1.f - wy) * vx1 * vy0;
    const float w10 = (1.f - wx) * wy * vx0 * vy1;
    const float w11 = wx * wy * vx1 * vy1;
    const int i00 = cy0 * WC + cx0, i01 = cy0 * WC + cx1;
    const int i10 = cy1 * WC + cx0, i11 = cy1 * WC + cx1;

#pragma unroll 4
    for (int c = 0; c < CC; ++c) {
        const size_t pb = ib + (size_t)c * JC;
        const float v = w00 * ldin(f1c, pb + i00, f32) + w01 * ldin(f1c, pb + i01, f32)
                      + w10 * ldin(f1c, pb + i10, f32) + w11 * ldin(f1c, pb + i11, f32);
        const ushort_t h = f2bfbits(v);
        oh[64 + c] = h; ol[64 + c] = f2bfbits(v - bfbits2f(h));
    }
    {
        const ushort_t h = f2bfbits(gx);
        oh[128] = h; ol[128] = f2bfbits(gx - bfbits2f(h));
    }
    {
        const ushort_t h = f2bfbits(gy);
        oh[129] = h; ol[129] = f2bfbits(gy - bfbits2f(h));
    }
    for (int c = 130; c < 160; ++c) { oh[c] = 0; ol[c] = 0; }
}

// =====================================================================
// BN+ReLU+split elementwise: fp32 NHWC 256 -> hi/lo bf16 planes
// =====================================================================
__global__ __launch_bounds__(256) void bnrelu_split_kernel(
    const float* __restrict__ x, const float2* __restrict__ st,
    ushort_t* __restrict__ hiP, ushort_t* __restrict__ loP)
{
    const int idx = blockIdx.x * 256 + threadIdx.x;   // B*JC*32
    const int px = idx >> 5;
    const int c8 = (idx & 31) << 3;
    const float4 v0 = *(const float4*)&x[(size_t)px * 256 + c8];
    const float4 v1 = *(const float4*)&x[(size_t)px * 256 + c8 + 4];
    const float vv[8] = {v0.x, v0.y, v0.z, v0.w, v1.x, v1.y, v1.z, v1.w};
    ushort_t hh[8], ll[8];
#pragma unroll
    for (int e = 0; e < 8; ++e) {
        const float2 s = st[c8 + e];
        const float f = fmaxf((vv[e] - s.x) * s.y, 0.f);
        const ushort_t h = f2bfbits(f);
        hh[e] = h; ll[e] = f2bfbits(f - bfbits2f(h));
    }
    uint4 oh, ol;
    oh.x = (unsigned)hh[0] | ((unsigned)hh[1] << 16);
    oh.y = (unsigned)hh[2] | ((unsigned)hh[3] << 16);
    oh.z = (unsigned)hh[4] | ((unsigned)hh[5] << 16);
    oh.w = (unsigned)hh[6] | ((unsigned)hh[7] << 16);
    ol.x = (unsigned)ll[0] | ((unsigned)ll[1] << 16);
    ol.y = (unsigned)ll[2] | ((unsigned)ll[3] << 16);
    ol.z = (unsigned)ll[4] | ((unsigned)ll[5] << 16);
    ol.w = (unsigned)ll[6] | ((unsigned)ll[7] << 16);
    *(uint4*)&hiP[(size_t)px * 256 + c8] = oh;
    *(uint4*)&loP[(size_t)px * 256 + c8] = ol;
}

// =====================================================================
// Kernel 3a: COARSE 3x3 conv, split-bf16 MFMA + fused BN-stat atomics.
// Row-reuse register caching (R9): per dx, load 6 row-fragments (x2
// planes) once; dy x mt inner loop does 72 MFMAs on them.
// =====================================================================
__global__ __launch_bounds__(256, 3) void conv3x3_wsplit(
    const ushort_t* __restrict__ hiP, const ushort_t* __restrict__ loP,
    const ushort_t* __restrict__ wfrag,
    float* __restrict__ out, float* __restrict__ chsum,
    int CIP, int CO, int H, int W, int tilesX)
{
    __shared__ ushort_t actH[18 * 18 * 36];   // 23328 B
    __shared__ ushort_t actL[18 * 18 * 36];   // 23328 B
    __shared__ float smS[4][2][16], smQ[4][2][16];   // 1 KB

    const int nch = CIP >> 5;
    const int tid = threadIdx.x;
    const int tile = blockIdx.x;
    const int b = blockIdx.y;
    const int cog = blockIdx.z;
    const int ty = (tile / tilesX) * 16;
    const int tx = (tile % tilesX) * 16;
    const int wv = tid >> 6;
    const int ln = tid & 63;
    const int lm = ln & 15;
    const int q8 = (ln >> 4) * 8;

    v4f acc[4][2];
#pragma unroll
    for (int i = 0; i < 4; ++i)
#pragma unroll
        for (int j = 0; j < 2; ++j) acc[i][j] = (v4f)(0.f);

    for (int ch = 0; ch < nch; ++ch) {
        const int ci0 = ch << 5;
        __syncthreads();
        for (int p = tid; p < 2592; p += 256) {
            const int pl = (p >= 1296) ? 1 : 0;
            const int r = p - pl * 1296;
            const int yy = r / 72;
            const int rem = r - yy * 72;
            const int xx = rem >> 2;
            const int cs = (rem & 3) << 3;
            const int gy = ty + yy - 1, gx = tx + xx - 1;
            uint4 val = make_uint4(0u, 0u, 0u, 0u);
            if (gy >= 0 && gy < H && gx >= 0 && gx < W) {
                const ushort_t* src = pl ? loP : hiP;
                val = *(const uint4*)&src[(((size_t)(b * H + gy)) * W + gx) * CIP + ci0 + cs];
            }
            ushort_t* dst = pl ? actL : actH;
            *(uint4*)&dst[(yy * 18 + xx) * 36 + cs] = val;
        }
        __syncthreads();

#pragma unroll
        for (int dx = 0; dx < 3; ++dx) {
            // cache 6 row-fragments (rows wv*4 .. wv*4+5 of the halo tile)
            v8s ah[6], al[6];
#pragma unroll
            for (int rr = 0; rr < 6; ++rr) {
                const int aoff = ((wv * 4 + rr) * 18 + lm + dx) * 36 + q8;
                ah[rr] = *(const v8s*)&actH[aoff];
                al[rr] = *(const v8s*)&actL[aoff];
            }
#pragma unroll
            for (int dy = 0; dy < 3; ++dy) {
                const int k = dy * 3 + dx;
                const size_t fb = (((size_t)(cog * 9 + k) * 4) * nch + ch) * 64 + ln;
                const size_t step = (size_t)nch * 64;
                const v8s bh0 = *(const v8s*)&wfrag[fb * 8];
                const v8s bl0 = *(const v8s*)&wfrag[(fb + step) * 8];
                const v8s bh1 = *(const v8s*)&wfrag[(fb + 2 * step) * 8];
                const v8s bl1 = *(const v8s*)&wfrag[(fb + 3 * step) * 8];
#pragma unroll
                for (int mt = 0; mt < 4; ++mt) {
                    const v8s a_h = ah[mt + dy];
                    const v8s a_l = al[mt + dy];
                    acc[mt][0] = __builtin_amdgcn_mfma_f32_16x16x32_bf16(a_h, bl0, acc[mt][0], 0, 0, 0);
                    acc[mt][0] = __builtin_amdgcn_mfma_f32_16x16x32_bf16(a_l, bh0, acc[mt][0], 0, 0, 0);
                    acc[mt][0] = __builtin_amdgcn_mfma_f32_16x16x32_bf16(a_h, bh0, acc[mt][0], 0, 0, 0);
                    acc[mt][1] = __builtin_amdgcn_mfma_f32_16x16x32_bf16(a_h, bl1, acc[mt][1], 0, 0, 0);
                    acc[mt][1] = __builtin_amdgcn_mfma_f32_16x16x32_bf16(a_l, bh1, acc[mt][1], 0, 0, 0);
                    acc[mt][1] = __builtin_amdgcn_mfma_f32_16x16x32_bf16(a_h, bh1, acc[mt][1], 0, 0, 0);
                }
            }
        }
    }

    // D layout: col(n=co)=ln&15, row(m=x)=(ln>>4)*4+i
#pragma unroll
    for (int mt = 0; mt < 4; ++mt) {
        const int y = ty + wv * 4 + mt;
#pragma unroll
        for (int nt = 0; nt < 2; ++nt) {
            const int co = cog * 32 + nt * 16 + lm;
#pragma unroll
            for (int i = 0; i < 4; ++i) {
                const int x = tx + ((ln >> 4) << 2) + i;
                out[(((size_t)(b * H + y)) * W + x) * CO + co] = acc[mt][nt][i];
            }
        }
    }

    // ---- fused BN-stat partial sums (per-channel sum & sumsq) ----
    float s0 = 0.f, s1 = 0.f, q0 = 0.f, q1 = 0.f;
#pragma unroll
    for (int mt = 0; mt < 4; ++mt)
#pragma unroll
        for (int i = 0; i < 4; ++i) {
            float v = acc[mt][0][i]; s0 += v; q0 += v * v;
            v = acc[mt][1][i]; s1 += v; q1 += v * v;
        }
    s0 += __shfl_xor(s0, 16); s0 += __shfl_xor(s0, 32);
    s1 += __shfl_xor(s1, 16); s1 += __shfl_xor(s1, 32);
    q0 += __shfl_xor(q0, 16); q0 += __shfl_xor(q0, 32);
    q1 += __shfl_xor(q1, 16); q1 += __shfl_xor(q1, 32);
    __syncthreads();
    if (ln < 16) {
        smS[wv][0][ln] = s0; smS[wv][1][ln] = s1;
        smQ[wv][0][ln] = q0; smQ[wv][1][ln] = q1;
    }
    __syncthreads();
    if (tid < 32) {
        const int nt = tid >> 4, l2 = tid & 15;
        float S = 0.f, Q = 0.f;
        for (int w = 0; w < 4; ++w) { S += smS[w][nt][l2]; Q += smQ[w][nt][l2]; }
        const int co = cog * 32 + nt * 16 + l2;
        atomicAdd(&chsum[2 * co], S);
        atomicAdd(&chsum[2 * co + 1], Q);
    }
}

// =====================================================================
// Kernel 3b: FINE 3x3 conv, single-bf16 MFMA + fused BN-stat atomics.
// Row-reuse register caching (R9).
// =====================================================================
template <bool BN>
__global__ __launch_bounds__(256) void conv3x3_mfma(
    const ushort_t* __restrict__ in,
    const ushort_t* __restrict__ wp,   // [9][CO][CI] bf16
    const float2* __restrict__ stats,
    ushort_t* __restrict__ out, float* __restrict__ chsum,
    int CI, int CO, int H, int W, int tilesX)
{
    __shared__ ushort_t act[18 * 18 * 40];
    __shared__ ushort_t wbuf[9 * 32 * 40];
    __shared__ float2 st[256];
    __shared__ float smS[4][2][16], smQ[4][2][16];

    const int tid = threadIdx.x;
    const int tile = blockIdx.x;
    const int b = blockIdx.y;
    const int cog = blockIdx.z;
    const int ty = (tile / tilesX) * 16;
    const int tx = (tile % tilesX) * 16;
    const int wv = tid >> 6;
    const int ln = tid & 63;
    const int lm = ln & 15;
    const int q8 = (ln >> 4) * 8;

    if (BN) for (int c = tid; c < CI; c += 256) st[c] = stats[c];

    v4f acc[4][2];
#pragma unroll
    for (int i = 0; i < 4; ++i)
#pragma unroll
        for (int j = 0; j < 2; ++j) acc[i][j] = (v4f)(0.f);

    const int nChunks = CI >> 5;
    for (int ch = 0; ch < nChunks; ++ch) {
        const int ci0 = ch << 5;
        __syncthreads();
        for (int p = tid; p < 1296; p += 256) {
            const int yy = p / 72;
            const int rem = p - yy * 72;
            const int xx = rem >> 2;
            const int cs = (rem & 3) << 3;
            const int gy = ty + yy - 1, gx = tx + xx - 1;
            uint4 val = make_uint4(0u, 0u, 0u, 0u);
            if (gy >= 0 && gy < H && gx >= 0 && gx < W) {
                const ushort_t* gp = in + (((size_t)(b * H + gy)) * W + gx) * CI + ci0 + cs;
                val = *(const uint4*)gp;
                if (BN) {
                    unsigned u[4] = {val.x, val.y, val.z, val.w};
                    unsigned o[4];
#pragma unroll
                    for (int e = 0; e < 4; ++e) {
                        float lo = bfbits2f(u[e] & 0xffffu);
                        float hi = bfbits2f(u[e] >> 16);
                        const float2 s0 = st[ci0 + cs + 2 * e];
                        const float2 s1 = st[ci0 + cs + 2 * e + 1];
                        lo = fmaxf((lo - s0.x) * s0.y, 0.f);
                        hi = fmaxf((hi - s1.x) * s1.y, 0.f);
                        o[e] = (unsigned)f2bfbits(lo) | ((unsigned)f2bfbits(hi) << 16);
                    }
                    val = make_uint4(o[0], o[1], o[2], o[3]);
                }
            }
            *(uint4*)&act[(yy * 18 + xx) * 40 + cs] = val;
        }
        for (int p = tid; p < 1152; p += 256) {
            const int k = p / 128;
            const int rem = p - k * 128;
            const int co = rem >> 2;
            const int cs = (rem & 3) << 3;
            const ushort_t* gp = wp + ((size_t)k * CO + cog * 32 + co) * CI + ci0 + cs;
            *(uint4*)&wbuf[(k * 32 + co) * 40 + cs] = *(const uint4*)gp;
        }
        __syncthreads();

#pragma unroll
        for (int dx = 0; dx < 3; ++dx) {
            v8s af[6];
#pragma unroll
            for (int rr = 0; rr < 6; ++rr)
                af[rr] = *(const v8s*)&act[((wv * 4 + rr) * 18 + lm + dx) * 40 + q8];
#pragma unroll
            for (int dy = 0; dy < 3; ++dy) {
                const int k = dy * 3 + dx;
                const v8s bf0 = *(const v8s*)&wbuf[(k * 32 + lm) * 40 + q8];
                const v8s bf1 = *(const v8s*)&wbuf[(k * 32 + 16 + lm) * 40 + q8];
#pragma unroll
                for (int mt = 0; mt < 4; ++mt) {
                    acc[mt][0] = __builtin_amdgcn_mfma_f32_16x16x32_bf16(af[mt + dy], bf0, acc[mt][0], 0, 0, 0);
                    acc[mt][1] = __builtin_amdgcn_mfma_f32_16x16x32_bf16(af[mt + dy], bf1, acc[mt][1], 0, 0, 0);
                }
            }
        }
    }

#pragma unroll
    for (int mt = 0; mt < 4; ++mt) {
        const int y = ty + wv * 4 + mt;
#pragma unroll
        for (int nt = 0; nt < 2; ++nt) {
            const int co = cog * 32 + nt * 16 + lm;
#pragma unroll
            for (int i = 0; i < 4; ++i) {
                const int x = tx + ((ln >> 4) << 2) + i;
                out[(((size_t)(b * H + y)) * W + x) * CO + co] = f2bfbits(acc[mt][nt][i]);
            }
        }
    }

    // ---- fused BN-stat partial sums ----
    float s0 = 0.f, s1 = 0.f, q0 = 0.f, q1 = 0.f;
#pragma unroll
    for (int mt = 0; mt < 4; ++mt)
#pragma unroll
        for (int i = 0; i < 4; ++i) {
            float v = acc[mt][0][i]; s0 += v; q0 += v * v;
            v = acc[mt][1][i]; s1 += v; q1 += v * v;
        }
    s0 += __shfl_xor(s0, 16); s0 += __shfl_xor(s0, 32);
    s1 += __shfl_xor(s1, 16); s1 += __shfl_xor(s1, 32);
    q0 += __shfl_xor(q0, 16); q0 += __shfl_xor(q0, 32);
    q1 += __shfl_xor(q1, 16); q1 += __shfl_xor(q1, 32);
    __syncthreads();
    if (ln < 16) {
        smS[wv][0][ln] = s0; smS[wv][1][ln] = s1;
        smQ[wv][0][ln] = q0; smQ[wv][1][ln] = q1;
    }
    __syncthreads();
    if (tid < 32) {
        const int nt = tid >> 4, l2 = tid & 15;
        float S = 0.f, Q = 0.f;
        for (int w = 0; w < 4; ++w) { S += smS[w][nt][l2]; Q += smQ[w][nt][l2]; }
        const int co = cog * 32 + nt * 16 + l2;
        atomicAdd(&chsum[2 * co], S);
        atomicAdd(&chsum[2 * co + 1], Q);
    }
}

// =====================================================================
// stats finalize: (sum, sumsq) -> (mean, rsqrt(var+eps))
// =====================================================================
__global__ void stats_finalize_kernel(const float* __restrict__ chsum,
                                      float2* __restrict__ st, int C, float inv_n)
{
    const int c = threadIdx.x;
    if (c >= C) return;
    const float mean = chsum[2 * c] * inv_n;
    const float var = chsum[2 * c + 1] * inv_n - mean * mean;
    st[c] = make_float2(mean, 1.0f / sqrtf(var + 1e-5f));
}

// =====================================================================
// Kernel 5: coarse head (fp32 NHWC): 1x1 conv 256->3 + bias + cm0
// =====================================================================
__global__ __launch_bounds__(256) void coarse_head_kernel(
    const float* __restrict__ A, const float2* __restrict__ stats,
    const void* __restrict__ w5, const void* __restrict__ b5,
    float* __restrict__ cm0, void* __restrict__ out,
    const int* __restrict__ dflag)
{
    const int f32 = *dflag;
    __shared__ float wl[3][256];
    __shared__ float bl[3];
    __shared__ float2 st[256];
    const int tid = threadIdx.x;
    for (int i = tid; i < 768; i += 256) wl[i >> 8][i & 255] = ldin(w5, i, f32);
    if (tid < 3) bl[tid] = ldin(b5, tid, f32);
    st[tid] = stats[tid];
    __syncthreads();

    const int idx = blockIdx.x * 256 + tid;
    const int b = idx >> 12, hw = idx & (JC - 1);
    float a0 = bl[0], a1 = bl[1], a2 = bl[2];
    const float* p = A + (size_t)idx * 256;
    for (int c = 0; c < 256; c += 4) {
        const float4 raw = *(const float4*)(p + c);
        const float rv[4] = {raw.x, raw.y, raw.z, raw.w};
#pragma unroll
        for (int e = 0; e < 4; ++e) {
            const int cc = c + e;
            const float v = fmaxf((rv[e] - st[cc].x) * st[cc].y, 0.f);
            a0 += v * wl[0][cc]; a1 += v * wl[1][cc]; a2 += v * wl[2][cc];
        }
    }
    const size_t base = (size_t)b * 3 * JC + hw;
    const float c0 = cm0[base] + a0;
    const float c1 = cm0[base + JC] + a1;
    const float c2 = cm0[base + 2 * JC] + a2;
    cm0[base] = c0; cm0[base + JC] = c1; cm0[base + 2 * JC] = c2;
    stout(out, base, c0, f32);
    stout(out, base + JC, c1, f32);
    stout(out, base + 2 * JC, c2, f32);
}

// =====================================================================
// Kernel 6: bilinear 2x upsample (half-pixel, edge clamp)
// =====================================================================
__global__ __launch_bounds__(256) void upsample_kernel(
    const float* __restrict__ cm, float* __restrict__ up)
{
    const int idx = blockIdx.x * 256 + threadIdx.x;
    const int ox = idx & 127, oy = (idx >> 7) & 127, bc = idx >> 14;
    const float sx = ox * 0.5f - 0.25f;
    const float sy = oy * 0.5f - 0.25f;
    const int x0 = (int)floorf(sx), y0 = (int)floorf(sy);
    const float fx = sx - x0, fy = sy - y0;
    const int cx0 = max(x0, 0), cx1 = min(x0 + 1, WC - 1);
    const int cy0 = max(y0, 0), cy1 = min(y0 + 1, HC - 1);
    const float* p = cm + (size_t)bc * JC;
    const float v = (1.f - fy) * ((1.f - fx) * p[cy0 * WC + cx0] + fx * p[cy0 * WC + cx1])
                  + fy * ((1.f - fx) * p[cy1 * WC + cx0] + fx * p[cy1 * WC + cx1]);
    up[idx] = v;
}

// =====================================================================
// Kernel 7: fine concat -> NHWC bf16 [b][y][x][64] (50 real + 14 zero)
// =====================================================================
__global__ __launch_bounds__(256) void fine_concat_nhwc(
    const void* __restrict__ f0f, const void* __restrict__ f1f,
    const float* __restrict__ up, ushort_t* __restrict__ A,
    const int* __restrict__ dflag)
{
    const int f32 = *dflag;
    const int idx = blockIdx.x * 256 + threadIdx.x;   // B*JF
    const int b = idx >> 14, hw = idx & (JF - 1);
    const size_t ib = (size_t)b * CF * JF;
    ushort_t* o = A + (size_t)idx * 64;

    for (int c = 0; c < CF; ++c)
        o[c] = f2bfbits(ldin(f0f, ib + (size_t)c * JF + hw, f32));

    const size_t ub = (size_t)b * 3 * JF + hw;
    const float gx = up[ub], gy = up[ub + JF];
    const float x = (gx + 1.f) * 64.f - 0.5f;
    const float y = (gy + 1.f) * 64.f - 0.5f;
    const float x0f = floorf(x), y0f = floorf(y);
    const float wx = x - x0f, wy = y - y0f;
    const int x0 = (int)x0f, y0 = (int)y0f;
    const int x1 = x0 + 1, y1 = y0 + 1;
    const float vx0 = (x0 >= 0 && x0 < WF) ? 1.f : 0.f;
    const float vx1 = (x1 >= 0 && x1 < WF) ? 1.f : 0.f;
    const float vy0 = (y0 >= 0 && y0 < HF) ? 1.f : 0.f;
    const float vy1 = (y1 >= 0 && y1 < HF) ? 1.f : 0.f;
    const int cx0 = min(max(x0, 0), WF - 1), cx1 = min(max(x1, 0), WF - 1);
    const int cy0 = min(max(y0, 0), HF - 1), cy1 = min(max(y1, 0), HF - 1);
    const float w00 = (1.f - wx) * (1.f - wy) * vx0 * vy0;
    const float w01 = wx * (1.f - wy) * vx1 * vy0;
    const float w10 = (1.f - wx) * wy * vx0 * vy1;
    const float w11 = wx * wy * vx1 * vy1;
    const int i00 = cy0 * WF + cx0, i01 = cy0 * WF + cx1;
    const int i10 = cy1 * WF + cx0, i11 = cy1 * WF + cx1;

    for (int c = 0; c < CF; ++c) {
        const size_t pb = ib + (size_t)c * JF;
        const float v = w00 * ldin(f1f, pb + i00, f32) + w01 * ldin(f1f, pb + i01, f32)
                      + w10 * ldin(f1f, pb + i10, f32) + w11 * ldin(f1f, pb + i11, f32);
        o[24 + c] = f2bfbits(v);
    }
    o[48] = f2bfbits(gx);
    o[49] = f2bfbits(gy);
    for (int c = 50; c < 64; ++c) o[c] = 0;
}

// =====================================================================
// Kernel 8: fine head (NHWC bf16): 1x1 conv 64->3 + bias + up -> out1
// =====================================================================
__global__ __launch_bounds__(256) void fine_head_kernel(
    const ushort_t* __restrict__ A, const float2* __restrict__ stats,
    const void* __restrict__ w5, const void* __restrict__ b5,
    const float* __restrict__ up, void* __restrict__ out,
    const int* __restrict__ dflag)
{
    const int f32 = *dflag;
    __shared__ float wl[3][64];
    __shared__ float bl[3];
    __shared__ float2 st[64];
    const int tid = threadIdx.x;
    if (tid < 192) wl[tid >> 6][tid & 63] = ldin(w5, tid, f32);
    if (tid < 3) bl[tid] = ldin(b5, tid, f32);
    if (tid < 64) st[tid] = stats[tid];
    __syncthreads();

    const int idx = blockIdx.x * 256 + tid;
    const int b = idx >> 14, hw = idx & (JF - 1);
    float a0 = bl[0], a1 = bl[1], a2 = bl[2];
    const ushort_t* p = A + (size_t)idx * 64;
    for (int c = 0; c < 64; c += 8) {
        const uint4 raw = *(const uint4*)(p + c);
        const unsigned u[4] = {raw.x, raw.y, raw.z, raw.w};
#pragma unroll
        for (int e = 0; e < 4; ++e) {
            const int c0 = c + 2 * e, c1 = c0 + 1;
            float lo = bfbits2f(u[e] & 0xffffu);
            float hi = bfbits2f(u[e] >> 16);
            lo = fmaxf((lo - st[c0].x) * st[c0].y, 0.f);
            hi = fmaxf((hi - st[c1].x) * st[c1].y, 0.f);
            a0 += lo * wl[0][c0] + hi * wl[0][c1];
            a1 += lo * wl[1][c0] + hi * wl[1][c1];
            a2 += lo * wl[2][c0] + hi * wl[2][c1];
        }
    }
    const size_t base = (size_t)b * 3 * JF + hw;
    stout(out, OUT0_ELEMS + base,          up[base] + a0, f32);
    stout(out, OUT0_ELEMS + base + JF,     up[base + JF] + a1, f32);
    stout(out, OUT0_ELEMS + base + 2 * JF, up[base + 2 * JF] + a2, f32);
}

// =====================================================================
extern "C" void kernel_launch(void* const* d_in, const int* in_sizes, int n_in,
                              void* d_out, int out_size, void* d_ws, size_t ws_size,
                              hipStream_t stream)
{
    const void* f0c = d_in[0];
    const void* f1c = d_in[1];
    const void* f0f = d_in[2];
    const void* f1f = d_in[3];
    const void* cw1 = d_in[4];
    const void* cw2 = d_in[5];
    const void* cw3 = d_in[6];
    const void* cw4 = d_in[7];
    const void* cw5 = d_in[8];
    const void* cb5 = d_in[9];
    const void* fw1 = d_in[10];
    const void* fw2 = d_in[11];
    const void* fw3 = d_in[12];
    const void* fw4 = d_in[13];
    const void* fw5 = d_in[14];
    const void* fb5 = d_in[15];

    // ---- workspace layout (same proven footprint as R8/R9) ----
    char* wsb = (char*)d_ws;
    float* bufA    = (float*)wsb;                       // 16 MiB
    float* bufB    = (float*)(wsb + 16777216);          // 16 MiB
    float* cm0     = (float*)(wsb + 33554432);          // 196,608 B
    float* up      = (float*)(wsb + 33751040);          // 786,432 B
    float* chsum   = (float*)(wsb + 34537472);          // 2,048 B
    float2* st_g   = (float2*)(wsb + 34668544);         // 2,048 B
    int* dflag     = (int*)(wsb + 34670592);            // 64 B
    ushort_t* fwp  = (ushort_t*)(wsb + 34670656);       // 294,912 B
    ushort_t* fw1p = fwp;
    ushort_t* fw2p = fwp + 36864;
    ushort_t* fw3p = fwp + 73728;
    ushort_t* fw4p = fwp + 110592;
    ushort_t* wfrag = (ushort_t*)(wsb + 34965568);      // up to 9,437,184 B

    // split activation planes: hi = bufA[0..8MB), lo = bufA[8..16MB)
    ushort_t* hiP = (ushort_t*)bufA;
    ushort_t* loP = (ushort_t*)(wsb + 8388608);

    // corr split Q/K planes in bufA's first 8 MB (dead before concat)
    ushort_t* qhi = (ushort_t*)bufA;
    ushort_t* qlo = qhi + 1048576;
    ushort_t* khi = qlo + 1048576;
    ushort_t* klo = khi + 1048576;
    float* cpart = (float*)bufB;   // 1 MB corr partials (bufB dead during corr)

    ushort_t* fF1 = (ushort_t*)bufB;   // fine ping
    ushort_t* fF2 = (ushort_t*)bufA;   // fine pong

    // 0. dtype probe
    dtype_probe_kernel<<<1, 256, 0, stream>>>((const ushort_t*)f0c, dflag);

    // fine weight repacks (bf16 [k][co][ci_pad])
    repack_w_kernel<<<(9 * 64 * 64 + 255) / 256, 256, 0, stream>>>(fw1, fw1p, 64, 50, 64, dflag);
    repack_w_kernel<<<(9 * 64 * 64 + 255) / 256, 256, 0, stream>>>(fw2, fw2p, 64, 64, 64, dflag);
    repack_w_kernel<<<(9 * 64 * 64 + 255) / 256, 256, 0, stream>>>(fw3, fw3p, 64, 64, 64, dflag);
    repack_w_kernel<<<(9 * 64 * 64 + 255) / 256, 256, 0, stream>>>(fw4, fw4p, 64, 64, 64, dflag);

    // 1. correlation: split-transpose Q/K, split-K MFMA, reduce
    split_transpose_kernel<<<dim3(B_ * 64), 256, 0, stream>>>(f0c, qhi, qlo, dflag);
    split_transpose_kernel<<<dim3(B_ * 64), 256, 0, stream>>>(f1c, khi, klo, dflag);
    corr_mfma_kernel<<<dim3(HC, B_, 4), 256, 0, stream>>>(qhi, qlo, khi, klo, cpart);
    corr_reduce_kernel<<<dim3(B_ * JC / 256), 256, 0, stream>>>(cpart, cm0);

    // 2. coarse concat -> split planes (CIP=160); overwrites q/k (dead)
    coarse_concat_split<<<dim3(B_ * JC / 256), 256, 0, stream>>>(f0c, f1c, cm0, hiP, loP, dflag);

    // 3. coarse conv stack: fragment-weight split-bf16 MFMA, fused stats
    const dim3 cgrid(16, B_, 8);
    repack_wfrag_kernel<<<(8 * 9 * 2 * 2 * 5 * 64 + 255) / 256, 256, 0, stream>>>(cw1, wfrag, 130, 5, dflag);
    hipMemsetAsync(chsum, 0, 2048, stream);
    conv3x3_wsplit<<<cgrid, 256, 0, stream>>>(hiP, loP, wfrag, bufB, chsum, 160, 256, HC, WC, 4);
    stats_finalize_kernel<<<1, 256, 0, stream>>>(chsum, st_g, 256, 1.f / 16384.f);

    bnrelu_split_kernel<<<B_ * JC * 32 / 256, 256, 0, stream>>>(bufB, st_g, hiP, loP);
    repack_wfrag_kernel<<<(8 * 9 * 2 * 2 * 8 * 64 + 255) / 256, 256, 0, stream>>>(cw2, wfrag, 256, 8, dflag);
    hipMemsetAsync(chsum, 0, 2048, stream);
    conv3x3_wsplit<<<cgrid, 256, 0, stream>>>(hiP, loP, wfrag, bufB, chsum, 256, 256, HC, WC, 4);
    stats_finalize_kernel<<<1, 256, 0, stream>>>(chsum, st_g, 256, 1.f / 16384.f);

    bnrelu_split_kernel<<<B_ * JC * 32 / 256, 256, 0, stream>>>(bufB, st_g, hiP, loP);
    repack_wfrag_kernel<<<(8 * 9 * 2 * 2 * 8 * 64 + 255) / 256, 256, 0, stream>>>(cw3, wfrag, 256, 8, dflag);
    hipMemsetAsync(chsum, 0, 2048, stream);
    conv3x3_wsplit<<<cgrid, 256, 0, stream>>>(hiP, loP, wfrag, bufB, chsum, 256, 256, HC, WC, 4);
    stats_finalize_kernel<<<1, 256, 0, stream>>>(chsum, st_g, 256, 1.f / 16384.f);

    bnrelu_split_kernel<<<B_ * JC * 32 / 256, 256, 0, stream>>>(bufB, st_g, hiP, loP);
    repack_wfrag_kernel<<<(8 * 9 * 2 * 2 * 8 * 64 + 255) / 256, 256, 0, stream>>>(cw4, wfrag, 256, 8, dflag);
    hipMemsetAsync(chsum, 0, 2048, stream);
    conv3x3_wsplit<<<cgrid, 256, 0, stream>>>(hiP, loP, wfrag, bufB, chsum, 256, 256, HC, WC, 4);
    stats_finalize_kernel<<<1, 256, 0, stream>>>(chsum, st_g, 256, 1.f / 16384.f);

    // 4. coarse head -> out0, cmatch (in place over cm0)
    coarse_head_kernel<<<dim3(B_ * JC / 256), 256, 0, stream>>>(bufB, st_g, cw5, cb5, cm0, d_out, dflag);

    // 5. upsample (cm0 now holds cmatch)
    upsample_kernel<<<dim3(B_ * 3 * JF / 256), 256, 0, stream>>>(cm0, up);

    // 6. fine concat -> fF1 (bufB region; conv4 raw dead after head)
    fine_concat_nhwc<<<dim3(B_ * JF / 256), 256, 0, stream>>>(f0f, f1f, up, fF1, dflag);

    // 7. fine conv stack (bf16 MFMA, fused stats)
    const dim3 fgrid(64, B_, 2);
    hipMemsetAsync(chsum, 0, 512, stream);
    conv3x3_mfma<false><<<fgrid, 256, 0, stream>>>(fF1, fw1p, nullptr, fF2, chsum, 64, 64, HF, WF, 8);
    stats_finalize_kernel<<<1, 256, 0, stream>>>(chsum, st_g, 64, 1.f / 65536.f);
    hipMemsetAsync(chsum, 0, 512, stream);
    conv3x3_mfma<true><<<fgrid, 256, 0, stream>>>(fF2, fw2p, st_g, fF1, chsum, 64, 64, HF, WF, 8);
    stats_finalize_kernel<<<1, 256, 0, stream>>>(chsum, st_g, 64, 1.f / 65536.f);
    hipMemsetAsync(chsum, 0, 512, stream);
    conv3x3_mfma<true><<<fgrid, 256, 0, stream>>>(fF1, fw3p, st_g, fF2, chsum, 64, 64, HF, WF, 8);
    stats_finalize_kernel<<<1, 256, 0, stream>>>(chsum, st_g, 64, 1.f / 65536.f);
    hipMemsetAsync(chsum, 0, 512, stream);
    conv3x3_mfma<true><<<fgrid, 256, 0, stream>>>(fF2, fw4p, st_g, fF1, chsum, 64, 64, HF, WF, 8);
    stats_finalize_kernel<<<1, 256, 0, stream>>>(chsum, st_g, 64, 1.f / 65536.f);

    // 8. fine head -> out1
    fine_head_kernel<<<dim3(B_ * JF / 256), 256, 0, stream>>>(fF1, st_g, fw5, fb5, up, d_out, dflag);
}